// Round 3
// baseline (473.187 us; speedup 1.0000x reference)
//
#include <hip/hip_runtime.h>
#include <hip/hip_bf16.h>
#include <math.h>

#define B_SZ 2
#define L_SZ 1024
#define DM 1024
#define DI 2048
#define NS 16
#define DTR 64
#define NCHUNK 8
#define CLEN 128

typedef unsigned short ushortT;
typedef __attribute__((ext_vector_type(8))) short short8;
typedef __attribute__((ext_vector_type(4))) float floatx4;

__device__ __forceinline__ ushortT f2bf(float f) {
  unsigned u = __float_as_uint(f);
  unsigned r = (u + 0x7fff + ((u >> 16) & 1)) >> 16;
  return (ushortT)r;
}

__device__ __forceinline__ void gl2lds16(const void* g, void* l) {
  __builtin_amdgcn_global_load_lds(
      (const __attribute__((address_space(1))) unsigned int*)g,
      (__attribute__((address_space(3))) unsigned int*)l, 16, 0, 0);
}

// ---------------- f32 -> bf16 convert (4 elems/thread) ----------------
__global__ __launch_bounds__(256) void cvt_bf16(const float* __restrict__ src,
                                                ushortT* __restrict__ dst) {
  const int i = blockIdx.x * 256 + threadIdx.x;
  float4 v = ((const float4*)src)[i];
  unsigned lo = (unsigned)f2bf(v.x) | ((unsigned)f2bf(v.y) << 16);
  unsigned hi = (unsigned)f2bf(v.z) | ((unsigned)f2bf(v.w) << 16);
  ((uint2*)dst)[i] = make_uint2(lo, hi);
}

// ---------------- f32 [R][C] -> bf16 [C][R] transpose ----------------
__global__ __launch_bounds__(256) void transpose_bf16(
    const float* __restrict__ src, ushortT* __restrict__ dst, int R, int C) {
  __shared__ float t[32][33];
  const int bx = blockIdx.x * 32;  // col base
  const int by = blockIdx.y * 32;  // row base
  const int tx = threadIdx.x, ty = threadIdx.y;  // (32,8)
#pragma unroll
  for (int j = 0; j < 4; ++j)
    t[ty + j * 8][tx] = src[(size_t)(by + ty + j * 8) * C + bx + tx];
  __syncthreads();
#pragma unroll
  for (int j = 0; j < 4; ++j)
    dst[(size_t)(bx + ty + j * 8) * R + by + tx] = f2bf(t[tx][ty + j * 8]);
}

// ---------------- bf16 MFMA GEMM: C[M][N] f32 = A[M][K] @ BT[N][K]^T ----------------
// m97-style: BK=32, global_load_lds width=16, XOR chunk swizzle, 16x16x32 MFMA.
template <int BM, int BN>
__global__ __launch_bounds__((BM / 64) * (BN / 64) * 64) void gemm_bf16(
    const ushortT* __restrict__ A, int lda,
    const ushortT* __restrict__ BT, int ldb,
    float* __restrict__ C, int ldc, int K) {
  constexpr int NW = (BM / 64) * (BN / 64);
  constexpr int NT = NW * 64;
  __shared__ __align__(16) char smem[(BM + BN) * 64];
  char* As = smem;
  char* Bs = smem + BM * 64;
  const int tid = threadIdx.x;
  const int lane = tid & 63;
  const int quad = lane >> 4;
  const int l16 = lane & 15;
  const int wid = tid >> 6;
  const int wm = wid % (BM / 64);
  const int wn = wid / (BM / 64);
  const int m0 = blockIdx.y * BM;
  const int n0 = blockIdx.x * BN;

  floatx4 acc[4][4] = {};

  for (int k0 = 0; k0 < K; k0 += 32) {
    // stage A tile: BM rows x 64B, chunk-swizzled
    for (int i = tid; i < BM * 4; i += NT) {
      const int r = i >> 2, c = i & 3;
      const int cg = c ^ (r & 3);
      const char* g = (const char*)(A + (size_t)(m0 + r) * lda + k0) + cg * 16;
      gl2lds16(g, As + (size_t)(i - lane) * 16);
    }
    // stage B tile: BN rows x 64B
    for (int i = tid; i < BN * 4; i += NT) {
      const int r = i >> 2, c = i & 3;
      const int cg = c ^ (r & 3);
      const char* g = (const char*)(BT + (size_t)(n0 + r) * ldb + k0) + cg * 16;
      gl2lds16(g, Bs + (size_t)(i - lane) * 16);
    }
    __syncthreads();

    short8 afr[4], bfr[4];
#pragma unroll
    for (int i = 0; i < 4; ++i) {
      const int r = wm * 64 + i * 16 + l16;
      afr[i] = *(const short8*)(As + r * 64 + ((quad ^ (r & 3)) * 16));
    }
#pragma unroll
    for (int j = 0; j < 4; ++j) {
      const int r = wn * 64 + j * 16 + l16;
      bfr[j] = *(const short8*)(Bs + r * 64 + ((quad ^ (r & 3)) * 16));
    }
#pragma unroll
    for (int i = 0; i < 4; ++i)
#pragma unroll
      for (int j = 0; j < 4; ++j)
        acc[i][j] = __builtin_amdgcn_mfma_f32_16x16x32_bf16(afr[i], bfr[j],
                                                            acc[i][j], 0, 0, 0);
    __syncthreads();
  }
  // epilogue: C/D layout col=lane&15, row=quad*4+reg
#pragma unroll
  for (int i = 0; i < 4; ++i)
#pragma unroll
    for (int j = 0; j < 4; ++j)
#pragma unroll
      for (int r = 0; r < 4; ++r) {
        const int m = m0 + wm * 64 + i * 16 + quad * 4 + r;
        const int n = n0 + wn * 64 + j * 16 + l16;
        C[(size_t)m * ldc + n] = acc[i][j][r];
      }
}

// ------------- causal depthwise conv (k=4) + silu -> xc f32 -------------
__global__ __launch_bounds__(256) void conv_silu(
    const float* __restrict__ xz, const float* __restrict__ kern,
    const float* __restrict__ bias, float* __restrict__ xc) {
  const int d = blockIdx.y * 256 + threadIdx.x;
  const int row = blockIdx.x;
  const int l = row & (L_SZ - 1);
  float acc = bias[d];
#pragma unroll
  for (int i = 0; i < 4; ++i) {
    const int li = l - 3 + i;
    if (li >= 0) acc = fmaf(xz[(size_t)(row - 3 + i) * 4096 + d], kern[i * DI + d], acc);
  }
  xc[(size_t)row * DI + d] = acc / (1.f + __expf(-acc));
}

// ------------- x_dbl = xc @ Wx : (2048 x 96), K=2048 -------------
// 8 independent accumulators + float4 A-loads: breaks the serial fma chain.
__global__ __launch_bounds__(768) void gemm_xdbl(
    const float* __restrict__ xc, const float* __restrict__ Wx,
    float* __restrict__ xdbl) {
  const int col = threadIdx.x;                       // 0..95
  const int row = blockIdx.x * 8 + threadIdx.y;      // 0..2047
  const float* __restrict__ arow = xc + (size_t)row * DI;
  const float* __restrict__ wcol = Wx + col;
  float a0 = 0.f, a1 = 0.f, a2 = 0.f, a3 = 0.f;
  float a4 = 0.f, a5 = 0.f, a6 = 0.f, a7 = 0.f;
  for (int k = 0; k < DI; k += 8) {
    const float4 v0 = *(const float4*)&arow[k];
    const float4 v1 = *(const float4*)&arow[k + 4];
    const float w0 = wcol[(size_t)(k + 0) * 96];
    const float w1 = wcol[(size_t)(k + 1) * 96];
    const float w2 = wcol[(size_t)(k + 2) * 96];
    const float w3 = wcol[(size_t)(k + 3) * 96];
    const float w4 = wcol[(size_t)(k + 4) * 96];
    const float w5 = wcol[(size_t)(k + 5) * 96];
    const float w6 = wcol[(size_t)(k + 6) * 96];
    const float w7 = wcol[(size_t)(k + 7) * 96];
    a0 = fmaf(v0.x, w0, a0);
    a1 = fmaf(v0.y, w1, a1);
    a2 = fmaf(v0.z, w2, a2);
    a3 = fmaf(v0.w, w3, a3);
    a4 = fmaf(v1.x, w4, a4);
    a5 = fmaf(v1.y, w5, a5);
    a6 = fmaf(v1.z, w6, a6);
    a7 = fmaf(v1.w, w7, a7);
  }
  const float s = ((a0 + a4) + (a1 + a5)) + ((a2 + a6) + (a3 + a7));
  xdbl[(size_t)row * 96 + col] = s;
}

// ------------- delta = softplus(dt @ Wdt + dt_bias) -------------
__global__ __launch_bounds__(256) void gemm_delta(
    const float* __restrict__ xdbl, const float* __restrict__ Wdt,
    const float* __restrict__ dt_bias, float* __restrict__ delta) {
  const int col = blockIdx.x * 256 + threadIdx.x;
  const int row = blockIdx.y;
  const float* __restrict__ dt = xdbl + (size_t)row * 96;
  float acc = dt_bias[col];
#pragma unroll
  for (int k = 0; k < DTR; ++k) acc = fmaf(dt[k], Wdt[(size_t)k * DI + col], acc);
  delta[(size_t)row * DI + col] = (acc > 20.f) ? acc : log1pf(__expf(acc));
}

// ------------- scan phase 1: per-chunk transition (prod dA, local final state) -------------
// blocks: b(1) | chunk(3) | dtile(3); 256 threads = contiguous d.
__global__ __launch_bounds__(256) void scan_phase1(
    const float* __restrict__ delta, const float* __restrict__ xc,
    const float* __restrict__ xdbl, const float* __restrict__ A_log,
    float* __restrict__ aprod, float* __restrict__ sfin) {
  const int bx = blockIdx.x;
  const int b = bx >> 6;
  const int c = (bx >> 3) & 7;
  const int d = (bx & 7) * 256 + threadIdx.x;
  const int row0 = b * L_SZ + c * CLEN;

  __shared__ float Bsh[CLEN][16];
  for (int i = threadIdx.x; i < CLEN * 16; i += 256) {
    const int r = i >> 4, n = i & 15;
    Bsh[r][n] = xdbl[(size_t)(row0 + r) * 96 + 64 + n];
  }

  float Av[16];
#pragma unroll
  for (int n = 0; n < 16; ++n) Av[n] = -__expf(A_log[d * 16 + n]);
  float x[16] = {}, P[16];
#pragma unroll
  for (int n = 0; n < 16; ++n) P[n] = 1.f;

  __syncthreads();

  const float* dp = delta + (size_t)row0 * DI + d;
  const float* up = xc + (size_t)row0 * DI + d;
  float dlt = dp[0], u = up[0];
  for (int l = 0; l < CLEN; ++l) {
    float dn = 0.f, un = 0.f;
    if (l + 1 < CLEN) { dn = dp[(size_t)(l + 1) * DI]; un = up[(size_t)(l + 1) * DI]; }
    const float t = dlt * u;
#pragma unroll
    for (int n = 0; n < 16; ++n) {
      const float dA = __expf(dlt * Av[n]);
      P[n] *= dA;
      x[n] = fmaf(dA, x[n], t * Bsh[l][n]);
    }
    dlt = dn; u = un;
  }
  const size_t sb = (((size_t)(b * NCHUNK + c) * DI) + d) * 16;
#pragma unroll
  for (int n = 0; n < 16; ++n) { aprod[sb + n] = P[n]; sfin[sb + n] = x[n]; }
}

// ------------- scan phase 2: sequential chunk combine; sfin becomes xinit -------------
__global__ __launch_bounds__(256) void scan_phase2(
    const float* __restrict__ aprod, float* __restrict__ sfin) {
  const int t = blockIdx.x * 256 + threadIdx.x;  // (b, d, n) flat
  const int b = t >> 15;
  const int rem = t & 32767;
  float x = 0.f;
#pragma unroll
  for (int c = 0; c < NCHUNK; ++c) {
    const size_t idx = ((size_t)(b * NCHUNK + c) << 15) + rem;
    const float P = aprod[idx];
    const float S = sfin[idx];
    sfin[idx] = x;           // xinit for chunk c
    x = fmaf(P, x, S);
  }
}

// ------------- scan phase 3: rescan w/ init state + y + skip + gate -> bf16 y in xz x-half -------------
__global__ __launch_bounds__(256) void scan_phase3(
    const float* __restrict__ delta, const float* __restrict__ xc,
    const float* __restrict__ xdbl, const float* __restrict__ A_log,
    const float* __restrict__ Dskip, const float* __restrict__ xinit,
    float* __restrict__ xz) {
  const int bx = blockIdx.x;
  const int b = bx >> 6;
  const int c = (bx >> 3) & 7;
  const int d = (bx & 7) * 256 + threadIdx.x;
  const int row0 = b * L_SZ + c * CLEN;

  __shared__ float Bsh[CLEN][16], Csh[CLEN][16];
  for (int i = threadIdx.x; i < CLEN * 32; i += 256) {
    const int r = i >> 5, q = i & 31;
    const float v = xdbl[(size_t)(row0 + r) * 96 + 64 + q];
    if (q < 16) Bsh[r][q] = v; else Csh[r][q - 16] = v;
  }

  float Av[16];
#pragma unroll
  for (int n = 0; n < 16; ++n) Av[n] = -__expf(A_log[d * 16 + n]);
  const float Dsk = Dskip[d];
  const size_t sb = (((size_t)(b * NCHUNK + c) * DI) + d) * 16;
  float x[16];
#pragma unroll
  for (int n = 0; n < 16; ++n) x[n] = xinit[sb + n];

  __syncthreads();

  const float* dp = delta + (size_t)row0 * DI + d;
  const float* up = xc + (size_t)row0 * DI + d;
  ushortT* yb = (ushortT*)xz;
  float dlt = dp[0], u = up[0];
  for (int l = 0; l < CLEN; ++l) {
    float dn = 0.f, un = 0.f;
    if (l + 1 < CLEN) { dn = dp[(size_t)(l + 1) * DI]; un = up[(size_t)(l + 1) * DI]; }
    const float t = dlt * u;
    float y = 0.f;
#pragma unroll
    for (int n = 0; n < 16; ++n) {
      const float dA = __expf(dlt * Av[n]);
      x[n] = fmaf(dA, x[n], t * Bsh[l][n]);
      y = fmaf(x[n], Csh[l][n], y);
    }
    const size_t row = (size_t)(row0 + l);
    const float z = xz[row * 4096 + DI + d];
    const float g = (y + u * Dsk) * (z / (1.f + __expf(-z)));
    yb[row * 8192 + d] = f2bf(g);
    dlt = dn; u = un;
  }
}

extern "C" void kernel_launch(void* const* d_in, const int* in_sizes, int n_in,
                              void* d_out, int out_size, void* d_ws, size_t ws_size,
                              hipStream_t stream) {
  const float* hidden  = (const float*)d_in[0];
  const float* Win     = (const float*)d_in[1];
  const float* Wx      = (const float*)d_in[2];
  const float* Wdt     = (const float*)d_in[3];
  const float* dt_bias = (const float*)d_in[4];
  const float* Wout    = (const float*)d_in[5];
  const float* dwk     = (const float*)d_in[6];
  const float* dwb     = (const float*)d_in[7];
  const float* A_log   = (const float*)d_in[8];
  const float* Dskip   = (const float*)d_in[9];

  // ws (64 MB): xz 32MB | shared16 (WinT -> delta -> WoutT) 16MB | xc 16MB
  char* ws = (char*)d_ws;
  float* xz       = (float*)ws;
  float* shared16 = (float*)(ws + (32u << 20));
  float* xc       = (float*)(ws + (48u << 20));
  // d_out (8 MB) doubles as scratch: hid_bf16 [0,4M) -> stats [0,4M); xdbl [4M,4.75M)
  char* dob = (char*)d_out;
  ushortT* hidb = (ushortT*)dob;
  float* xdbl   = (float*)(dob + (4u << 20));
  float* aprod  = (float*)dob;
  float* sfin   = (float*)(dob + (2u << 20));

  // 1. hidden -> bf16 (into d_out)
  cvt_bf16<<<dim3(B_SZ * L_SZ * DM / 1024), 256, 0, stream>>>(hidden, hidb);
  // 2. Win (1024x4096) -> WinT bf16 (4096x1024) in shared16
  transpose_bf16<<<dim3(4096 / 32, 1024 / 32), dim3(32, 8), 0, stream>>>(
      Win, (ushortT*)shared16, DM, 2 * DI);
  // 3. GEMM1: xz = hidden @ Win  (M=2048, N=4096, K=1024)
  gemm_bf16<128, 128><<<dim3(4096 / 128, 2048 / 128), 256, 0, stream>>>(
      hidb, DM, (ushortT*)shared16, DM, xz, 2 * DI, DM);
  // 4. depthwise conv + silu -> xc
  conv_silu<<<dim3(B_SZ * L_SZ, DI / 256), 256, 0, stream>>>(xz, dwk, dwb, xc);
  // 5. x_dbl = xc @ Wx (into d_out scratch)
  gemm_xdbl<<<dim3(B_SZ * L_SZ / 8), dim3(96, 8), 0, stream>>>(xc, Wx, xdbl);
  // 6. delta = softplus(dt @ Wdt + bias) -> shared16 (WinT dead)
  gemm_delta<<<dim3(DI / 256, B_SZ * L_SZ), 256, 0, stream>>>(xdbl, Wdt, dt_bias, shared16);
  // 7-9. chunked selective scan; y (gated, bf16) -> xz x-half
  scan_phase1<<<dim3(B_SZ * NCHUNK * (DI / 256)), 256, 0, stream>>>(
      shared16, xc, xdbl, A_log, aprod, sfin);
  scan_phase2<<<dim3(B_SZ * DI * NS / 256), 256, 0, stream>>>(aprod, sfin);
  scan_phase3<<<dim3(B_SZ * NCHUNK * (DI / 256)), 256, 0, stream>>>(
      shared16, xc, xdbl, A_log, Dskip, sfin, xz);
  // 10. Wout (2048x1024) -> WoutT bf16 (1024x2048) in shared16 (delta dead)
  transpose_bf16<<<dim3(1024 / 32, 2048 / 32), dim3(32, 8), 0, stream>>>(
      Wout, (ushortT*)shared16, DI, DM);
  // 11. GEMM4: out = y @ Wout  (M=2048, N=1024, K=2048); A = bf16 y, lda=8192
  gemm_bf16<128, 64><<<dim3(1024 / 64, 2048 / 128), 128, 0, stream>>>(
      (ushortT*)xz, 4 * DI, (ushortT*)shared16, DI, (float*)d_out, DM, DI);
}

// Round 4
// 453.590 us; speedup vs baseline: 1.0432x; 1.0432x over previous
//
#include <hip/hip_runtime.h>
#include <hip/hip_bf16.h>
#include <math.h>

#define B_SZ 2
#define L_SZ 1024
#define DM 1024
#define DI 2048
#define NS 16
#define DTR 64
#define NCHUNK 8
#define CLEN 128

typedef unsigned short ushortT;
typedef __attribute__((ext_vector_type(8))) short short8;
typedef __attribute__((ext_vector_type(4))) float floatx4;

__device__ __forceinline__ ushortT f2bf(float f) {
  unsigned u = __float_as_uint(f);
  unsigned r = (u + 0x7fff + ((u >> 16) & 1)) >> 16;
  return (ushortT)r;
}

__device__ __forceinline__ void gl2lds16(const void* g, void* l) {
  __builtin_amdgcn_global_load_lds(
      (const __attribute__((address_space(1))) unsigned int*)g,
      (__attribute__((address_space(3))) unsigned int*)l, 16, 0, 0);
}

// ---------------- f32 -> bf16 convert (4 elems/thread) ----------------
__global__ __launch_bounds__(256) void cvt_bf16(const float* __restrict__ src,
                                                ushortT* __restrict__ dst) {
  const int i = blockIdx.x * 256 + threadIdx.x;
  float4 v = ((const float4*)src)[i];
  unsigned lo = (unsigned)f2bf(v.x) | ((unsigned)f2bf(v.y) << 16);
  unsigned hi = (unsigned)f2bf(v.z) | ((unsigned)f2bf(v.w) << 16);
  ((uint2*)dst)[i] = make_uint2(lo, hi);
}

// ---------------- zero fill (float4 per thread) ----------------
__global__ __launch_bounds__(256) void zero_f32(float* __restrict__ p) {
  const int i = blockIdx.x * 256 + threadIdx.x;
  ((float4*)p)[i] = make_float4(0.f, 0.f, 0.f, 0.f);
}

// ---------------- f32 [R][C] -> bf16 [C][R] transpose ----------------
__global__ __launch_bounds__(256) void transpose_bf16(
    const float* __restrict__ src, ushortT* __restrict__ dst, int R, int C) {
  __shared__ float t[32][33];
  const int bx = blockIdx.x * 32;  // col base
  const int by = blockIdx.y * 32;  // row base
  const int tx = threadIdx.x, ty = threadIdx.y;  // (32,8)
#pragma unroll
  for (int j = 0; j < 4; ++j)
    t[ty + j * 8][tx] = src[(size_t)(by + ty + j * 8) * C + bx + tx];
  __syncthreads();
#pragma unroll
  for (int j = 0; j < 4; ++j)
    dst[(size_t)(bx + ty + j * 8) * R + by + tx] = f2bf(t[tx][ty + j * 8]);
}

// ---------------- bf16 MFMA GEMM: C[M][N] f32 = A[M][K] @ BT[N][K]^T ----------------
// m97-style: BK=32, global_load_lds width=16, XOR chunk swizzle, 16x16x32 MFMA.
template <int BM, int BN>
__global__ __launch_bounds__((BM / 64) * (BN / 64) * 64) void gemm_bf16(
    const ushortT* __restrict__ A, int lda,
    const ushortT* __restrict__ BT, int ldb,
    float* __restrict__ C, int ldc, int K) {
  constexpr int NW = (BM / 64) * (BN / 64);
  constexpr int NT = NW * 64;
  __shared__ __align__(16) char smem[(BM + BN) * 64];
  char* As = smem;
  char* Bs = smem + BM * 64;
  const int tid = threadIdx.x;
  const int lane = tid & 63;
  const int quad = lane >> 4;
  const int l16 = lane & 15;
  const int wid = tid >> 6;
  const int wm = wid % (BM / 64);
  const int wn = wid / (BM / 64);
  const int m0 = blockIdx.y * BM;
  const int n0 = blockIdx.x * BN;

  floatx4 acc[4][4] = {};

  for (int k0 = 0; k0 < K; k0 += 32) {
    // stage A tile: BM rows x 64B, chunk-swizzled
    for (int i = tid; i < BM * 4; i += NT) {
      const int r = i >> 2, c = i & 3;
      const int cg = c ^ (r & 3);
      const char* g = (const char*)(A + (size_t)(m0 + r) * lda + k0) + cg * 16;
      gl2lds16(g, As + (size_t)(i - lane) * 16);
    }
    // stage B tile: BN rows x 64B
    for (int i = tid; i < BN * 4; i += NT) {
      const int r = i >> 2, c = i & 3;
      const int cg = c ^ (r & 3);
      const char* g = (const char*)(BT + (size_t)(n0 + r) * ldb + k0) + cg * 16;
      gl2lds16(g, Bs + (size_t)(i - lane) * 16);
    }
    __syncthreads();

    short8 afr[4], bfr[4];
#pragma unroll
    for (int i = 0; i < 4; ++i) {
      const int r = wm * 64 + i * 16 + l16;
      afr[i] = *(const short8*)(As + r * 64 + ((quad ^ (r & 3)) * 16));
    }
#pragma unroll
    for (int j = 0; j < 4; ++j) {
      const int r = wn * 64 + j * 16 + l16;
      bfr[j] = *(const short8*)(Bs + r * 64 + ((quad ^ (r & 3)) * 16));
    }
#pragma unroll
    for (int i = 0; i < 4; ++i)
#pragma unroll
      for (int j = 0; j < 4; ++j)
        acc[i][j] = __builtin_amdgcn_mfma_f32_16x16x32_bf16(afr[i], bfr[j],
                                                            acc[i][j], 0, 0, 0);
    __syncthreads();
  }
  // epilogue: C/D layout col=lane&15, row=quad*4+reg
#pragma unroll
  for (int i = 0; i < 4; ++i)
#pragma unroll
    for (int j = 0; j < 4; ++j)
#pragma unroll
      for (int r = 0; r < 4; ++r) {
        const int m = m0 + wm * 64 + i * 16 + quad * 4 + r;
        const int n = n0 + wn * 64 + j * 16 + l16;
        C[(size_t)m * ldc + n] = acc[i][j][r];
      }
}

// ------------- causal depthwise conv (k=4) + silu -> xc f32 -------------
__global__ __launch_bounds__(256) void conv_silu(
    const float* __restrict__ xz, const float* __restrict__ kern,
    const float* __restrict__ bias, float* __restrict__ xc) {
  const int d = blockIdx.y * 256 + threadIdx.x;
  const int row = blockIdx.x;
  const int l = row & (L_SZ - 1);
  float acc = bias[d];
#pragma unroll
  for (int i = 0; i < 4; ++i) {
    const int li = l - 3 + i;
    if (li >= 0) acc = fmaf(xz[(size_t)(row - 3 + i) * 4096 + d], kern[i * DI + d], acc);
  }
  xc[(size_t)row * DI + d] = acc / (1.f + __expf(-acc));
}

// ------------- x_dbl = xc @ Wx : (2048 x 96), K=2048 -------------
// K-split: grid (row-tile 16 rows) x (K-tile 128). Wx K-slab staged in LDS.
// 384 threads = 96 cols x 4 k-subsegments of 32. Partials combined by atomicAdd.
__global__ __launch_bounds__(384) void gemm_xdbl_split(
    const float* __restrict__ xc, const float* __restrict__ Wx,
    float* __restrict__ xdbl) {
  __shared__ float WxL[128 * 96];  // 48 KB
  const int bx = blockIdx.x;
  const int rt = bx >> 4;          // row tile 0..127
  const int kt = bx & 15;          // k tile 0..15
  const int tid = threadIdx.x;
  const int col = tid % 96;
  const int yy = tid / 96;         // 0..3
  const int r0 = rt * 16;

  // stage Wx[kt*128 .. +128)[0..96) -> LDS, coalesced
  for (int i = tid; i < 128 * 96; i += 384) WxL[i] = Wx[kt * (128 * 96) + i];
  __syncthreads();

  const int k0 = yy * 32;  // local k base within tile
  const float* __restrict__ xbase = xc + (size_t)r0 * DI + kt * 128 + k0;

  float acc[16];
#pragma unroll
  for (int r = 0; r < 16; ++r) acc[r] = 0.f;

#pragma unroll
  for (int r4 = 0; r4 < 4; ++r4) {
#pragma unroll
    for (int g = 0; g < 4; ++g) {
      float w[8];
#pragma unroll
      for (int j = 0; j < 8; ++j) w[j] = WxL[(k0 + g * 8 + j) * 96 + col];
#pragma unroll
      for (int rr = 0; rr < 4; ++rr) {
        const int r = r4 * 4 + rr;
        const float* xr = xbase + (size_t)r * DI + g * 8;
        const float4 x0 = *(const float4*)xr;
        const float4 x1 = *(const float4*)(xr + 4);
        float a = acc[r];
        a = fmaf(x0.x, w[0], a);
        a = fmaf(x0.y, w[1], a);
        a = fmaf(x0.z, w[2], a);
        a = fmaf(x0.w, w[3], a);
        a = fmaf(x1.x, w[4], a);
        a = fmaf(x1.y, w[5], a);
        a = fmaf(x1.z, w[6], a);
        a = fmaf(x1.w, w[7], a);
        acc[r] = a;
      }
    }
  }
  // thread-local k-subsegment done; combine across (yy, kt) via atomics
#pragma unroll
  for (int r = 0; r < 16; ++r)
    atomicAdd(&xdbl[(size_t)(r0 + r) * 96 + col], acc[r]);
}

// ------------- delta = softplus(dt @ Wdt + dt_bias) -------------
__global__ __launch_bounds__(256) void gemm_delta(
    const float* __restrict__ xdbl, const float* __restrict__ Wdt,
    const float* __restrict__ dt_bias, float* __restrict__ delta) {
  const int col = blockIdx.x * 256 + threadIdx.x;
  const int row = blockIdx.y;
  const float* __restrict__ dt = xdbl + (size_t)row * 96;
  float acc = dt_bias[col];
#pragma unroll
  for (int k = 0; k < DTR; ++k) acc = fmaf(dt[k], Wdt[(size_t)k * DI + col], acc);
  delta[(size_t)row * DI + col] = (acc > 20.f) ? acc : log1pf(__expf(acc));
}

// ------------- scan phase 1: per-chunk transition (prod dA, local final state) -------------
// blocks: b(1) | chunk(3) | dtile(3); 256 threads = contiguous d.
__global__ __launch_bounds__(256) void scan_phase1(
    const float* __restrict__ delta, const float* __restrict__ xc,
    const float* __restrict__ xdbl, const float* __restrict__ A_log,
    float* __restrict__ aprod, float* __restrict__ sfin) {
  const int bx = blockIdx.x;
  const int b = bx >> 6;
  const int c = (bx >> 3) & 7;
  const int d = (bx & 7) * 256 + threadIdx.x;
  const int row0 = b * L_SZ + c * CLEN;

  __shared__ float Bsh[CLEN][16];
  for (int i = threadIdx.x; i < CLEN * 16; i += 256) {
    const int r = i >> 4, n = i & 15;
    Bsh[r][n] = xdbl[(size_t)(row0 + r) * 96 + 64 + n];
  }

  float Av[16];
#pragma unroll
  for (int n = 0; n < 16; ++n) Av[n] = -__expf(A_log[d * 16 + n]);
  float x[16] = {}, P[16];
#pragma unroll
  for (int n = 0; n < 16; ++n) P[n] = 1.f;

  __syncthreads();

  const float* dp = delta + (size_t)row0 * DI + d;
  const float* up = xc + (size_t)row0 * DI + d;
  float dlt = dp[0], u = up[0];
  for (int l = 0; l < CLEN; ++l) {
    float dn = 0.f, un = 0.f;
    if (l + 1 < CLEN) { dn = dp[(size_t)(l + 1) * DI]; un = up[(size_t)(l + 1) * DI]; }
    const float t = dlt * u;
#pragma unroll
    for (int n = 0; n < 16; ++n) {
      const float dA = __expf(dlt * Av[n]);
      P[n] *= dA;
      x[n] = fmaf(dA, x[n], t * Bsh[l][n]);
    }
    dlt = dn; u = un;
  }
  const size_t sb = (((size_t)(b * NCHUNK + c) * DI) + d) * 16;
#pragma unroll
  for (int n = 0; n < 16; ++n) { aprod[sb + n] = P[n]; sfin[sb + n] = x[n]; }
}

// ------------- scan phase 2: sequential chunk combine; sfin becomes xinit -------------
__global__ __launch_bounds__(256) void scan_phase2(
    const float* __restrict__ aprod, float* __restrict__ sfin) {
  const int t = blockIdx.x * 256 + threadIdx.x;  // (b, d, n) flat
  const int b = t >> 15;
  const int rem = t & 32767;
  float x = 0.f;
#pragma unroll
  for (int c = 0; c < NCHUNK; ++c) {
    const size_t idx = ((size_t)(b * NCHUNK + c) << 15) + rem;
    const float P = aprod[idx];
    const float S = sfin[idx];
    sfin[idx] = x;           // xinit for chunk c
    x = fmaf(P, x, S);
  }
}

// ------------- scan phase 3: rescan w/ init state + y + skip + gate -> bf16 y in xz x-half -------------
__global__ __launch_bounds__(256) void scan_phase3(
    const float* __restrict__ delta, const float* __restrict__ xc,
    const float* __restrict__ xdbl, const float* __restrict__ A_log,
    const float* __restrict__ Dskip, const float* __restrict__ xinit,
    float* __restrict__ xz) {
  const int bx = blockIdx.x;
  const int b = bx >> 6;
  const int c = (bx >> 3) & 7;
  const int d = (bx & 7) * 256 + threadIdx.x;
  const int row0 = b * L_SZ + c * CLEN;

  __shared__ float Bsh[CLEN][16], Csh[CLEN][16];
  for (int i = threadIdx.x; i < CLEN * 32; i += 256) {
    const int r = i >> 5, q = i & 31;
    const float v = xdbl[(size_t)(row0 + r) * 96 + 64 + q];
    if (q < 16) Bsh[r][q] = v; else Csh[r][q - 16] = v;
  }

  float Av[16];
#pragma unroll
  for (int n = 0; n < 16; ++n) Av[n] = -__expf(A_log[d * 16 + n]);
  const float Dsk = Dskip[d];
  const size_t sb = (((size_t)(b * NCHUNK + c) * DI) + d) * 16;
  float x[16];
#pragma unroll
  for (int n = 0; n < 16; ++n) x[n] = xinit[sb + n];

  __syncthreads();

  const float* dp = delta + (size_t)row0 * DI + d;
  const float* up = xc + (size_t)row0 * DI + d;
  ushortT* yb = (ushortT*)xz;
  float dlt = dp[0], u = up[0];
  for (int l = 0; l < CLEN; ++l) {
    float dn = 0.f, un = 0.f;
    if (l + 1 < CLEN) { dn = dp[(size_t)(l + 1) * DI]; un = up[(size_t)(l + 1) * DI]; }
    const float t = dlt * u;
    float y = 0.f;
#pragma unroll
    for (int n = 0; n < 16; ++n) {
      const float dA = __expf(dlt * Av[n]);
      x[n] = fmaf(dA, x[n], t * Bsh[l][n]);
      y = fmaf(x[n], Csh[l][n], y);
    }
    const size_t row = (size_t)(row0 + l);
    const float z = xz[row * 4096 + DI + d];
    const float g = (y + u * Dsk) * (z / (1.f + __expf(-z)));
    yb[row * 8192 + d] = f2bf(g);
    dlt = dn; u = un;
  }
}

extern "C" void kernel_launch(void* const* d_in, const int* in_sizes, int n_in,
                              void* d_out, int out_size, void* d_ws, size_t ws_size,
                              hipStream_t stream) {
  const float* hidden  = (const float*)d_in[0];
  const float* Win     = (const float*)d_in[1];
  const float* Wx      = (const float*)d_in[2];
  const float* Wdt     = (const float*)d_in[3];
  const float* dt_bias = (const float*)d_in[4];
  const float* Wout    = (const float*)d_in[5];
  const float* dwk     = (const float*)d_in[6];
  const float* dwb     = (const float*)d_in[7];
  const float* A_log   = (const float*)d_in[8];
  const float* Dskip   = (const float*)d_in[9];

  // ws (64 MB): xz 32MB | shared16 (WinT -> delta -> WoutT) 16MB | xc 16MB
  char* ws = (char*)d_ws;
  float* xz       = (float*)ws;
  float* shared16 = (float*)(ws + (32u << 20));
  float* xc       = (float*)(ws + (48u << 20));
  // d_out (8 MB) doubles as scratch: hid_bf16 [0,4M) -> stats [0,4M); xdbl [4M,4.75M)
  char* dob = (char*)d_out;
  ushortT* hidb = (ushortT*)dob;
  float* xdbl   = (float*)(dob + (4u << 20));
  float* aprod  = (float*)dob;
  float* sfin   = (float*)(dob + (2u << 20));

  // 1. hidden -> bf16 (into d_out)
  cvt_bf16<<<dim3(B_SZ * L_SZ * DM / 1024), 256, 0, stream>>>(hidden, hidb);
  // 2. Win (1024x4096) -> WinT bf16 (4096x1024) in shared16
  transpose_bf16<<<dim3(4096 / 32, 1024 / 32), dim3(32, 8), 0, stream>>>(
      Win, (ushortT*)shared16, DM, 2 * DI);
  // 3. GEMM1: xz = hidden @ Win  (M=2048, N=4096, K=1024)
  gemm_bf16<128, 128><<<dim3(4096 / 128, 2048 / 128), 256, 0, stream>>>(
      hidb, DM, (ushortT*)shared16, DM, xz, 2 * DI, DM);
  // 4. depthwise conv + silu -> xc
  conv_silu<<<dim3(B_SZ * L_SZ, DI / 256), 256, 0, stream>>>(xz, dwk, dwb, xc);
  // 5. x_dbl = xc @ Wx (into d_out scratch), K-split + atomics
  zero_f32<<<dim3(B_SZ * L_SZ * 96 / 1024), 256, 0, stream>>>(xdbl);
  gemm_xdbl_split<<<dim3(128 * 16), 384, 0, stream>>>(xc, Wx, xdbl);
  // 6. delta = softplus(dt @ Wdt + bias) -> shared16 (WinT dead)
  gemm_delta<<<dim3(DI / 256, B_SZ * L_SZ), 256, 0, stream>>>(xdbl, Wdt, dt_bias, shared16);
  // 7-9. chunked selective scan; y (gated, bf16) -> xz x-half
  scan_phase1<<<dim3(B_SZ * NCHUNK * (DI / 256)), 256, 0, stream>>>(
      shared16, xc, xdbl, A_log, aprod, sfin);
  scan_phase2<<<dim3(B_SZ * DI * NS / 256), 256, 0, stream>>>(aprod, sfin);
  scan_phase3<<<dim3(B_SZ * NCHUNK * (DI / 256)), 256, 0, stream>>>(
      shared16, xc, xdbl, A_log, Dskip, sfin, xz);
  // 10. Wout (2048x1024) -> WoutT bf16 (1024x2048) in shared16 (delta dead)
  transpose_bf16<<<dim3(1024 / 32, 2048 / 32), dim3(32, 8), 0, stream>>>(
      Wout, (ushortT*)shared16, DI, DM);
  // 11. GEMM4: out = y @ Wout  (M=2048, N=1024, K=2048); A = bf16 y, lda=8192
  gemm_bf16<128, 64><<<dim3(1024 / 64, 2048 / 128), 128, 0, stream>>>(
      (ushortT*)xz, 4 * DI, (ushortT*)shared16, DI, (float*)d_out, DM, DI);
}

// Round 5
// 417.231 us; speedup vs baseline: 1.1341x; 1.0871x over previous
//
#include <hip/hip_runtime.h>
#include <hip/hip_bf16.h>
#include <math.h>

#define B_SZ 2
#define L_SZ 1024
#define DM 1024
#define DI 2048
#define NS 16
#define DTR 64
#define NCHUNK 8
#define CLEN 128

typedef unsigned short ushortT;
typedef __attribute__((ext_vector_type(8))) short short8;
typedef __attribute__((ext_vector_type(4))) float floatx4;

__device__ __forceinline__ ushortT f2bf(float f) {
  unsigned u = __float_as_uint(f);
  unsigned r = (u + 0x7fff + ((u >> 16) & 1)) >> 16;
  return (ushortT)r;
}

__device__ __forceinline__ void gl2lds16(const void* g, void* l) {
  __builtin_amdgcn_global_load_lds(
      (const __attribute__((address_space(1))) unsigned int*)g,
      (__attribute__((address_space(3))) unsigned int*)l, 16, 0, 0);
}

// ---------------- f32 -> bf16 convert (4 elems/thread) ----------------
__global__ __launch_bounds__(256) void cvt_bf16(const float* __restrict__ src,
                                                ushortT* __restrict__ dst) {
  const int i = blockIdx.x * 256 + threadIdx.x;
  float4 v = ((const float4*)src)[i];
  unsigned lo = (unsigned)f2bf(v.x) | ((unsigned)f2bf(v.y) << 16);
  unsigned hi = (unsigned)f2bf(v.z) | ((unsigned)f2bf(v.w) << 16);
  ((uint2*)dst)[i] = make_uint2(lo, hi);
}

// ---------------- zero fill (float4 per thread) ----------------
__global__ __launch_bounds__(256) void zero_f32(float* __restrict__ p) {
  const int i = blockIdx.x * 256 + threadIdx.x;
  ((float4*)p)[i] = make_float4(0.f, 0.f, 0.f, 0.f);
}

// ---------------- f32 [R][C] -> bf16 [C][R] transpose ----------------
__global__ __launch_bounds__(256) void transpose_bf16(
    const float* __restrict__ src, ushortT* __restrict__ dst, int R, int C) {
  __shared__ float t[32][33];
  const int bx = blockIdx.x * 32;  // col base
  const int by = blockIdx.y * 32;  // row base
  const int tx = threadIdx.x, ty = threadIdx.y;  // (32,8)
#pragma unroll
  for (int j = 0; j < 4; ++j)
    t[ty + j * 8][tx] = src[(size_t)(by + ty + j * 8) * C + bx + tx];
  __syncthreads();
#pragma unroll
  for (int j = 0; j < 4; ++j)
    dst[(size_t)(bx + ty + j * 8) * R + by + tx] = f2bf(t[tx][ty + j * 8]);
}

// ---------------- bf16 MFMA GEMM: C[M][N] f32 = A[M][K] @ BT[N][K]^T ----------------
// m97-style: BK=32, global_load_lds width=16, XOR chunk swizzle, 16x16x32 MFMA.
template <int BM, int BN>
__global__ __launch_bounds__((BM / 64) * (BN / 64) * 64) void gemm_bf16(
    const ushortT* __restrict__ A, int lda,
    const ushortT* __restrict__ BT, int ldb,
    float* __restrict__ C, int ldc, int K) {
  constexpr int NW = (BM / 64) * (BN / 64);
  constexpr int NT = NW * 64;
  __shared__ __align__(16) char smem[(BM + BN) * 64];
  char* As = smem;
  char* Bs = smem + BM * 64;
  const int tid = threadIdx.x;
  const int lane = tid & 63;
  const int quad = lane >> 4;
  const int l16 = lane & 15;
  const int wid = tid >> 6;
  const int wm = wid % (BM / 64);
  const int wn = wid / (BM / 64);
  const int m0 = blockIdx.y * BM;
  const int n0 = blockIdx.x * BN;

  floatx4 acc[4][4] = {};

  for (int k0 = 0; k0 < K; k0 += 32) {
    // stage A tile: BM rows x 64B, chunk-swizzled
    for (int i = tid; i < BM * 4; i += NT) {
      const int r = i >> 2, c = i & 3;
      const int cg = c ^ (r & 3);
      const char* g = (const char*)(A + (size_t)(m0 + r) * lda + k0) + cg * 16;
      gl2lds16(g, As + (size_t)(i - lane) * 16);
    }
    // stage B tile: BN rows x 64B
    for (int i = tid; i < BN * 4; i += NT) {
      const int r = i >> 2, c = i & 3;
      const int cg = c ^ (r & 3);
      const char* g = (const char*)(BT + (size_t)(n0 + r) * ldb + k0) + cg * 16;
      gl2lds16(g, Bs + (size_t)(i - lane) * 16);
    }
    __syncthreads();

    short8 afr[4], bfr[4];
#pragma unroll
    for (int i = 0; i < 4; ++i) {
      const int r = wm * 64 + i * 16 + l16;
      afr[i] = *(const short8*)(As + r * 64 + ((quad ^ (r & 3)) * 16));
    }
#pragma unroll
    for (int j = 0; j < 4; ++j) {
      const int r = wn * 64 + j * 16 + l16;
      bfr[j] = *(const short8*)(Bs + r * 64 + ((quad ^ (r & 3)) * 16));
    }
#pragma unroll
    for (int i = 0; i < 4; ++i)
#pragma unroll
      for (int j = 0; j < 4; ++j)
        acc[i][j] = __builtin_amdgcn_mfma_f32_16x16x32_bf16(afr[i], bfr[j],
                                                            acc[i][j], 0, 0, 0);
    __syncthreads();
  }
  // epilogue: C/D layout col=lane&15, row=quad*4+reg
#pragma unroll
  for (int i = 0; i < 4; ++i)
#pragma unroll
    for (int j = 0; j < 4; ++j)
#pragma unroll
      for (int r = 0; r < 4; ++r) {
        const int m = m0 + wm * 64 + i * 16 + quad * 4 + r;
        const int n = n0 + wn * 64 + j * 16 + l16;
        C[(size_t)m * ldc + n] = acc[i][j][r];
      }
}

// ------------- causal depthwise conv (k=4) + silu -> xc f32 -------------
__global__ __launch_bounds__(256) void conv_silu(
    const float* __restrict__ xz, const float* __restrict__ kern,
    const float* __restrict__ bias, float* __restrict__ xc) {
  const int d = blockIdx.y * 256 + threadIdx.x;
  const int row = blockIdx.x;
  const int l = row & (L_SZ - 1);
  float acc = bias[d];
#pragma unroll
  for (int i = 0; i < 4; ++i) {
    const int li = l - 3 + i;
    if (li >= 0) acc = fmaf(xz[(size_t)(row - 3 + i) * 4096 + d], kern[i * DI + d], acc);
  }
  xc[(size_t)row * DI + d] = acc / (1.f + __expf(-acc));
}

// ------------- x_dbl = xc @ Wx : (2048 x 96), K=2048 -------------
// K-split: grid (row-tile 16 rows) x (K-tile 128). Wx K-slab staged in LDS.
// 384 threads = 96 cols x 4 k-subsegments of 32. Partials combined by atomicAdd.
__global__ __launch_bounds__(384) void gemm_xdbl_split(
    const float* __restrict__ xc, const float* __restrict__ Wx,
    float* __restrict__ xdbl) {
  __shared__ float WxL[128 * 96];  // 48 KB
  const int bx = blockIdx.x;
  const int rt = bx >> 4;          // row tile 0..127
  const int kt = bx & 15;          // k tile 0..15
  const int tid = threadIdx.x;
  const int col = tid % 96;
  const int yy = tid / 96;         // 0..3
  const int r0 = rt * 16;

  // stage Wx[kt*128 .. +128)[0..96) -> LDS, coalesced
  for (int i = tid; i < 128 * 96; i += 384) WxL[i] = Wx[kt * (128 * 96) + i];
  __syncthreads();

  const int k0 = yy * 32;  // local k base within tile
  const float* __restrict__ xbase = xc + (size_t)r0 * DI + kt * 128 + k0;

  float acc[16];
#pragma unroll
  for (int r = 0; r < 16; ++r) acc[r] = 0.f;

#pragma unroll
  for (int r4 = 0; r4 < 4; ++r4) {
#pragma unroll
    for (int g = 0; g < 4; ++g) {
      float w[8];
#pragma unroll
      for (int j = 0; j < 8; ++j) w[j] = WxL[(k0 + g * 8 + j) * 96 + col];
#pragma unroll
      for (int rr = 0; rr < 4; ++rr) {
        const int r = r4 * 4 + rr;
        const float* xr = xbase + (size_t)r * DI + g * 8;
        const float4 x0 = *(const float4*)xr;
        const float4 x1 = *(const float4*)(xr + 4);
        float a = acc[r];
        a = fmaf(x0.x, w[0], a);
        a = fmaf(x0.y, w[1], a);
        a = fmaf(x0.z, w[2], a);
        a = fmaf(x0.w, w[3], a);
        a = fmaf(x1.x, w[4], a);
        a = fmaf(x1.y, w[5], a);
        a = fmaf(x1.z, w[6], a);
        a = fmaf(x1.w, w[7], a);
        acc[r] = a;
      }
    }
  }
  // thread-local k-subsegment done; combine across (yy, kt) via atomics
#pragma unroll
  for (int r = 0; r < 16; ++r)
    atomicAdd(&xdbl[(size_t)(r0 + r) * 96 + col], acc[r]);
}

// ------------- delta = softplus(dt @ Wdt + dt_bias) -------------
// Row-tiled 16x: dt tile in LDS (broadcast reads), 8-wide Wdt register batches,
// 16 independent accumulators. Wdt L2 traffic 1 GB -> 64 MB.
__global__ __launch_bounds__(256) void gemm_delta(
    const float* __restrict__ xdbl, const float* __restrict__ Wdt,
    const float* __restrict__ dt_bias, float* __restrict__ delta) {
  __shared__ float dtL[16][64];
  const int col = blockIdx.x * 256 + threadIdx.x;
  const int row0 = blockIdx.y * 16;
  for (int i = threadIdx.x; i < 16 * 64; i += 256) {
    const int r = i >> 6, k = i & 63;
    dtL[r][k] = xdbl[(size_t)(row0 + r) * 96 + k];
  }
  __syncthreads();
  const float bias = dt_bias[col];
  float acc[16];
#pragma unroll
  for (int r = 0; r < 16; ++r) acc[r] = bias;
  for (int k8 = 0; k8 < 64; k8 += 8) {
    float w[8];
#pragma unroll
    for (int j = 0; j < 8; ++j) w[j] = Wdt[(size_t)(k8 + j) * DI + col];
#pragma unroll
    for (int r = 0; r < 16; ++r) {
      float a = acc[r];
#pragma unroll
      for (int j = 0; j < 8; ++j) a = fmaf(dtL[r][k8 + j], w[j], a);
      acc[r] = a;
    }
  }
#pragma unroll
  for (int r = 0; r < 16; ++r) {
    const float a = acc[r];
    delta[(size_t)(row0 + r) * DI + col] = (a > 20.f) ? a : log1pf(__expf(a));
  }
}

// ------------- scan phase 1: per-chunk transition (prod dA, local final state) -------------
// blocks: b(1) | chunk(3) | dtile(3); 256 threads = contiguous d.
__global__ __launch_bounds__(256) void scan_phase1(
    const float* __restrict__ delta, const float* __restrict__ xc,
    const float* __restrict__ xdbl, const float* __restrict__ A_log,
    float* __restrict__ aprod, float* __restrict__ sfin) {
  const int bx = blockIdx.x;
  const int b = bx >> 6;
  const int c = (bx >> 3) & 7;
  const int d = (bx & 7) * 256 + threadIdx.x;
  const int row0 = b * L_SZ + c * CLEN;

  __shared__ float Bsh[CLEN][16];
  for (int i = threadIdx.x; i < CLEN * 16; i += 256) {
    const int r = i >> 4, n = i & 15;
    Bsh[r][n] = xdbl[(size_t)(row0 + r) * 96 + 64 + n];
  }

  float Av[16];
#pragma unroll
  for (int n = 0; n < 16; ++n) Av[n] = -__expf(A_log[d * 16 + n]);
  float x[16] = {}, P[16];
#pragma unroll
  for (int n = 0; n < 16; ++n) P[n] = 1.f;

  __syncthreads();

  const float* dp = delta + (size_t)row0 * DI + d;
  const float* up = xc + (size_t)row0 * DI + d;
  float dlt = dp[0], u = up[0];
  for (int l = 0; l < CLEN; ++l) {
    float dn = 0.f, un = 0.f;
    if (l + 1 < CLEN) { dn = dp[(size_t)(l + 1) * DI]; un = up[(size_t)(l + 1) * DI]; }
    const float t = dlt * u;
#pragma unroll
    for (int n = 0; n < 16; ++n) {
      const float dA = __expf(dlt * Av[n]);
      P[n] *= dA;
      x[n] = fmaf(dA, x[n], t * Bsh[l][n]);
    }
    dlt = dn; u = un;
  }
  const size_t sb = (((size_t)(b * NCHUNK + c) * DI) + d) * 16;
#pragma unroll
  for (int n = 0; n < 16; ++n) { aprod[sb + n] = P[n]; sfin[sb + n] = x[n]; }
}

// ------------- scan phase 2: sequential chunk combine; sfin becomes xinit -------------
__global__ __launch_bounds__(256) void scan_phase2(
    const float* __restrict__ aprod, float* __restrict__ sfin) {
  const int t = blockIdx.x * 256 + threadIdx.x;  // (b, d, n) flat
  const int b = t >> 15;
  const int rem = t & 32767;
  float x = 0.f;
#pragma unroll
  for (int c = 0; c < NCHUNK; ++c) {
    const size_t idx = ((size_t)(b * NCHUNK + c) << 15) + rem;
    const float P = aprod[idx];
    const float S = sfin[idx];
    sfin[idx] = x;           // xinit for chunk c
    x = fmaf(P, x, S);
  }
}

// ------------- scan phase 3: rescan w/ init state + y + skip + gate -> bf16 y in xz x-half -------------
__global__ __launch_bounds__(256) void scan_phase3(
    const float* __restrict__ delta, const float* __restrict__ xc,
    const float* __restrict__ xdbl, const float* __restrict__ A_log,
    const float* __restrict__ Dskip, const float* __restrict__ xinit,
    float* __restrict__ xz) {
  const int bx = blockIdx.x;
  const int b = bx >> 6;
  const int c = (bx >> 3) & 7;
  const int d = (bx & 7) * 256 + threadIdx.x;
  const int row0 = b * L_SZ + c * CLEN;

  __shared__ float Bsh[CLEN][16], Csh[CLEN][16];
  for (int i = threadIdx.x; i < CLEN * 32; i += 256) {
    const int r = i >> 5, q = i & 31;
    const float v = xdbl[(size_t)(row0 + r) * 96 + 64 + q];
    if (q < 16) Bsh[r][q] = v; else Csh[r][q - 16] = v;
  }

  float Av[16];
#pragma unroll
  for (int n = 0; n < 16; ++n) Av[n] = -__expf(A_log[d * 16 + n]);
  const float Dsk = Dskip[d];
  const size_t sb = (((size_t)(b * NCHUNK + c) * DI) + d) * 16;
  float x[16];
#pragma unroll
  for (int n = 0; n < 16; ++n) x[n] = xinit[sb + n];

  __syncthreads();

  const float* dp = delta + (size_t)row0 * DI + d;
  const float* up = xc + (size_t)row0 * DI + d;
  ushortT* yb = (ushortT*)xz;
  float dlt = dp[0], u = up[0];
  for (int l = 0; l < CLEN; ++l) {
    float dn = 0.f, un = 0.f;
    if (l + 1 < CLEN) { dn = dp[(size_t)(l + 1) * DI]; un = up[(size_t)(l + 1) * DI]; }
    const float t = dlt * u;
    float y = 0.f;
#pragma unroll
    for (int n = 0; n < 16; ++n) {
      const float dA = __expf(dlt * Av[n]);
      x[n] = fmaf(dA, x[n], t * Bsh[l][n]);
      y = fmaf(x[n], Csh[l][n], y);
    }
    const size_t row = (size_t)(row0 + l);
    const float z = xz[row * 4096 + DI + d];
    const float g = (y + u * Dsk) * (z / (1.f + __expf(-z)));
    yb[row * 8192 + d] = f2bf(g);
    dlt = dn; u = un;
  }
}

extern "C" void kernel_launch(void* const* d_in, const int* in_sizes, int n_in,
                              void* d_out, int out_size, void* d_ws, size_t ws_size,
                              hipStream_t stream) {
  const float* hidden  = (const float*)d_in[0];
  const float* Win     = (const float*)d_in[1];
  const float* Wx      = (const float*)d_in[2];
  const float* Wdt     = (const float*)d_in[3];
  const float* dt_bias = (const float*)d_in[4];
  const float* Wout    = (const float*)d_in[5];
  const float* dwk     = (const float*)d_in[6];
  const float* dwb     = (const float*)d_in[7];
  const float* A_log   = (const float*)d_in[8];
  const float* Dskip   = (const float*)d_in[9];

  // ws (64 MB): xz 32MB | shared16 (WinT -> delta -> WoutT) 16MB | xc 16MB
  char* ws = (char*)d_ws;
  float* xz       = (float*)ws;
  float* shared16 = (float*)(ws + (32u << 20));
  float* xc       = (float*)(ws + (48u << 20));
  // d_out (8 MB) doubles as scratch: hid_bf16 [0,4M) -> stats [0,4M); xdbl [4M,4.75M)
  char* dob = (char*)d_out;
  ushortT* hidb = (ushortT*)dob;
  float* xdbl   = (float*)(dob + (4u << 20));
  float* aprod  = (float*)dob;
  float* sfin   = (float*)(dob + (2u << 20));

  // 1. hidden -> bf16 (into d_out)
  cvt_bf16<<<dim3(B_SZ * L_SZ * DM / 1024), 256, 0, stream>>>(hidden, hidb);
  // 2. Win (1024x4096) -> WinT bf16 (4096x1024) in shared16
  transpose_bf16<<<dim3(4096 / 32, 1024 / 32), dim3(32, 8), 0, stream>>>(
      Win, (ushortT*)shared16, DM, 2 * DI);
  // 3. GEMM1: xz = hidden @ Win  (M=2048, N=4096, K=1024)
  gemm_bf16<128, 128><<<dim3(4096 / 128, 2048 / 128), 256, 0, stream>>>(
      hidb, DM, (ushortT*)shared16, DM, xz, 2 * DI, DM);
  // 4. depthwise conv + silu -> xc
  conv_silu<<<dim3(B_SZ * L_SZ, DI / 256), 256, 0, stream>>>(xz, dwk, dwb, xc);
  // 5. x_dbl = xc @ Wx (into d_out scratch), K-split + atomics
  zero_f32<<<dim3(B_SZ * L_SZ * 96 / 1024), 256, 0, stream>>>(xdbl);
  gemm_xdbl_split<<<dim3(128 * 16), 384, 0, stream>>>(xc, Wx, xdbl);
  // 6. delta = softplus(dt @ Wdt + bias) -> shared16 (WinT dead)
  gemm_delta<<<dim3(DI / 256, B_SZ * L_SZ / 16), 256, 0, stream>>>(
      xdbl, Wdt, dt_bias, shared16);
  // 7-9. chunked selective scan; y (gated, bf16) -> xz x-half
  scan_phase1<<<dim3(B_SZ * NCHUNK * (DI / 256)), 256, 0, stream>>>(
      shared16, xc, xdbl, A_log, aprod, sfin);
  scan_phase2<<<dim3(B_SZ * DI * NS / 256), 256, 0, stream>>>(aprod, sfin);
  scan_phase3<<<dim3(B_SZ * NCHUNK * (DI / 256)), 256, 0, stream>>>(
      shared16, xc, xdbl, A_log, Dskip, sfin, xz);
  // 10. Wout (2048x1024) -> WoutT bf16 (1024x2048) in shared16 (delta dead)
  transpose_bf16<<<dim3(1024 / 32, 2048 / 32), dim3(32, 8), 0, stream>>>(
      Wout, (ushortT*)shared16, DI, DM);
  // 11. GEMM4: out = y @ Wout  (M=2048, N=1024, K=2048); A = bf16 y, lda=8192
  gemm_bf16<128, 64><<<dim3(1024 / 64, 2048 / 128), 128, 0, stream>>>(
      (ushortT*)xz, 4 * DI, (ushortT*)shared16, DI, (float*)d_out, DM, DI);
}

// Round 6
// 352.433 us; speedup vs baseline: 1.3426x; 1.1839x over previous
//
#include <hip/hip_runtime.h>
#include <hip/hip_bf16.h>
#include <math.h>

#define B_SZ 2
#define L_SZ 1024
#define DM 1024
#define DI 2048
#define NS 16
#define DTR 64
#define NCHUNK 16
#define CLEN 64

typedef unsigned short ushortT;
typedef __attribute__((ext_vector_type(8))) short short8;
typedef __attribute__((ext_vector_type(4))) float floatx4;

__device__ __forceinline__ ushortT f2bf(float f) {
  unsigned u = __float_as_uint(f);
  unsigned r = (u + 0x7fff + ((u >> 16) & 1)) >> 16;
  return (ushortT)r;
}

__device__ __forceinline__ void gl2lds16(const void* g, void* l) {
  __builtin_amdgcn_global_load_lds(
      (const __attribute__((address_space(1))) unsigned int*)g,
      (__attribute__((address_space(3))) unsigned int*)l, 16, 0, 0);
}

// Scan-state stash lives in the dead strided region of xz: floats [1024,2048)
// of each 4096-float row (y-bf16 uses [0,1024), z uses [2048,4096)).
// i in [0, 2M): aprod at i, sfin at i + 1M.
__device__ __forceinline__ unsigned stash_addr(unsigned i) {
  return (i >> 10) * 4096 + 1024 + (i & 1023);
}

// ---------------- f32 -> bf16 convert (4 elems/thread) ----------------
__global__ __launch_bounds__(256) void cvt_bf16(const float* __restrict__ src,
                                                ushortT* __restrict__ dst) {
  const int i = blockIdx.x * 256 + threadIdx.x;
  float4 v = ((const float4*)src)[i];
  unsigned lo = (unsigned)f2bf(v.x) | ((unsigned)f2bf(v.y) << 16);
  unsigned hi = (unsigned)f2bf(v.z) | ((unsigned)f2bf(v.w) << 16);
  ((uint2*)dst)[i] = make_uint2(lo, hi);
}

// ---------------- zero fill (float4 per thread) ----------------
__global__ __launch_bounds__(256) void zero_f32(float* __restrict__ p) {
  const int i = blockIdx.x * 256 + threadIdx.x;
  ((float4*)p)[i] = make_float4(0.f, 0.f, 0.f, 0.f);
}

// ---------------- f32 [R][C] -> bf16 [C][R] transpose ----------------
__global__ __launch_bounds__(256) void transpose_bf16(
    const float* __restrict__ src, ushortT* __restrict__ dst, int R, int C) {
  __shared__ float t[32][33];
  const int bx = blockIdx.x * 32;  // col base
  const int by = blockIdx.y * 32;  // row base
  const int tx = threadIdx.x, ty = threadIdx.y;  // (32,8)
#pragma unroll
  for (int j = 0; j < 4; ++j)
    t[ty + j * 8][tx] = src[(size_t)(by + ty + j * 8) * C + bx + tx];
  __syncthreads();
#pragma unroll
  for (int j = 0; j < 4; ++j)
    dst[(size_t)(bx + ty + j * 8) * R + by + tx] = f2bf(t[tx][ty + j * 8]);
}

// ---------------- bf16 MFMA GEMM: C[M][N] f32 = A[M][K] @ BT[N][K]^T ----------------
// m97-style: BK=32, global_load_lds width=16, XOR chunk swizzle, 16x16x32 MFMA.
template <int BM, int BN>
__global__ __launch_bounds__((BM / 64) * (BN / 64) * 64) void gemm_bf16(
    const ushortT* __restrict__ A, int lda,
    const ushortT* __restrict__ BT, int ldb,
    float* __restrict__ C, int ldc, int K) {
  constexpr int NW = (BM / 64) * (BN / 64);
  constexpr int NT = NW * 64;
  __shared__ __align__(16) char smem[(BM + BN) * 64];
  char* As = smem;
  char* Bs = smem + BM * 64;
  const int tid = threadIdx.x;
  const int lane = tid & 63;
  const int quad = lane >> 4;
  const int l16 = lane & 15;
  const int wid = tid >> 6;
  const int wm = wid % (BM / 64);
  const int wn = wid / (BM / 64);
  const int m0 = blockIdx.y * BM;
  const int n0 = blockIdx.x * BN;

  floatx4 acc[4][4] = {};

  for (int k0 = 0; k0 < K; k0 += 32) {
    // stage A tile: BM rows x 64B, chunk-swizzled
    for (int i = tid; i < BM * 4; i += NT) {
      const int r = i >> 2, c = i & 3;
      const int cg = c ^ (r & 3);
      const char* g = (const char*)(A + (size_t)(m0 + r) * lda + k0) + cg * 16;
      gl2lds16(g, As + (size_t)(i - lane) * 16);
    }
    // stage B tile: BN rows x 64B
    for (int i = tid; i < BN * 4; i += NT) {
      const int r = i >> 2, c = i & 3;
      const int cg = c ^ (r & 3);
      const char* g = (const char*)(BT + (size_t)(n0 + r) * ldb + k0) + cg * 16;
      gl2lds16(g, Bs + (size_t)(i - lane) * 16);
    }
    __syncthreads();

    short8 afr[4], bfr[4];
#pragma unroll
    for (int i = 0; i < 4; ++i) {
      const int r = wm * 64 + i * 16 + l16;
      afr[i] = *(const short8*)(As + r * 64 + ((quad ^ (r & 3)) * 16));
    }
#pragma unroll
    for (int j = 0; j < 4; ++j) {
      const int r = wn * 64 + j * 16 + l16;
      bfr[j] = *(const short8*)(Bs + r * 64 + ((quad ^ (r & 3)) * 16));
    }
#pragma unroll
    for (int i = 0; i < 4; ++i)
#pragma unroll
      for (int j = 0; j < 4; ++j)
        acc[i][j] = __builtin_amdgcn_mfma_f32_16x16x32_bf16(afr[i], bfr[j],
                                                            acc[i][j], 0, 0, 0);
    __syncthreads();
  }
  // epilogue: C/D layout col=lane&15, row=quad*4+reg
#pragma unroll
  for (int i = 0; i < 4; ++i)
#pragma unroll
    for (int j = 0; j < 4; ++j)
#pragma unroll
      for (int r = 0; r < 4; ++r) {
        const int m = m0 + wm * 64 + i * 16 + quad * 4 + r;
        const int n = n0 + wn * 64 + j * 16 + l16;
        C[(size_t)m * ldc + n] = acc[i][j][r];
      }
}

// ------------- causal depthwise conv (k=4) + silu -> xc f32 -------------
__global__ __launch_bounds__(256) void conv_silu(
    const float* __restrict__ xz, const float* __restrict__ kern,
    const float* __restrict__ bias, float* __restrict__ xc) {
  const int d = blockIdx.y * 256 + threadIdx.x;
  const int row = blockIdx.x;
  const int l = row & (L_SZ - 1);
  float acc = bias[d];
#pragma unroll
  for (int i = 0; i < 4; ++i) {
    const int li = l - 3 + i;
    if (li >= 0) acc = fmaf(xz[(size_t)(row - 3 + i) * 4096 + d], kern[i * DI + d], acc);
  }
  xc[(size_t)row * DI + d] = acc / (1.f + __expf(-acc));
}

// ------------- x_dbl = xc @ Wx : (2048 x 96), K=2048 -------------
// K-split: grid (row-tile 16 rows) x (K-tile 128). Wx K-slab staged in LDS.
// 384 threads = 96 cols x 4 k-subsegments of 32. Partials combined by atomicAdd.
__global__ __launch_bounds__(384) void gemm_xdbl_split(
    const float* __restrict__ xc, const float* __restrict__ Wx,
    float* __restrict__ xdbl) {
  __shared__ float WxL[128 * 96];  // 48 KB
  const int bx = blockIdx.x;
  const int rt = bx >> 4;          // row tile 0..127
  const int kt = bx & 15;          // k tile 0..15
  const int tid = threadIdx.x;
  const int col = tid % 96;
  const int yy = tid / 96;         // 0..3
  const int r0 = rt * 16;

  // stage Wx[kt*128 .. +128)[0..96) -> LDS, coalesced
  for (int i = tid; i < 128 * 96; i += 384) WxL[i] = Wx[kt * (128 * 96) + i];
  __syncthreads();

  const int k0 = yy * 32;  // local k base within tile
  const float* __restrict__ xbase = xc + (size_t)r0 * DI + kt * 128 + k0;

  float acc[16];
#pragma unroll
  for (int r = 0; r < 16; ++r) acc[r] = 0.f;

#pragma unroll
  for (int r4 = 0; r4 < 4; ++r4) {
#pragma unroll
    for (int g = 0; g < 4; ++g) {
      float w[8];
#pragma unroll
      for (int j = 0; j < 8; ++j) w[j] = WxL[(k0 + g * 8 + j) * 96 + col];
#pragma unroll
      for (int rr = 0; rr < 4; ++rr) {
        const int r = r4 * 4 + rr;
        const float* xr = xbase + (size_t)r * DI + g * 8;
        const float4 x0 = *(const float4*)xr;
        const float4 x1 = *(const float4*)(xr + 4);
        float a = acc[r];
        a = fmaf(x0.x, w[0], a);
        a = fmaf(x0.y, w[1], a);
        a = fmaf(x0.z, w[2], a);
        a = fmaf(x0.w, w[3], a);
        a = fmaf(x1.x, w[4], a);
        a = fmaf(x1.y, w[5], a);
        a = fmaf(x1.z, w[6], a);
        a = fmaf(x1.w, w[7], a);
        acc[r] = a;
      }
    }
  }
  // thread-local k-subsegment done; combine across (yy, kt) via atomics
#pragma unroll
  for (int r = 0; r < 16; ++r)
    atomicAdd(&xdbl[(size_t)(r0 + r) * 96 + col], acc[r]);
}

// ------------- delta = softplus(dt @ Wdt + dt_bias) -------------
// Row-tiled 16x: dt tile in LDS (broadcast reads), 8-wide Wdt register batches,
// 16 independent accumulators.
__global__ __launch_bounds__(256) void gemm_delta(
    const float* __restrict__ xdbl, const float* __restrict__ Wdt,
    const float* __restrict__ dt_bias, float* __restrict__ delta) {
  __shared__ float dtL[16][64];
  const int col = blockIdx.x * 256 + threadIdx.x;
  const int row0 = blockIdx.y * 16;
  for (int i = threadIdx.x; i < 16 * 64; i += 256) {
    const int r = i >> 6, k = i & 63;
    dtL[r][k] = xdbl[(size_t)(row0 + r) * 96 + k];
  }
  __syncthreads();
  const float bias = dt_bias[col];
  float acc[16];
#pragma unroll
  for (int r = 0; r < 16; ++r) acc[r] = bias;
  for (int k8 = 0; k8 < 64; k8 += 8) {
    float w[8];
#pragma unroll
    for (int j = 0; j < 8; ++j) w[j] = Wdt[(size_t)(k8 + j) * DI + col];
#pragma unroll
    for (int r = 0; r < 16; ++r) {
      float a = acc[r];
#pragma unroll
      for (int j = 0; j < 8; ++j) a = fmaf(dtL[r][k8 + j], w[j], a);
      acc[r] = a;
    }
  }
#pragma unroll
  for (int r = 0; r < 16; ++r) {
    const float a = acc[r];
    delta[(size_t)(row0 + r) * DI + col] = (a > 20.f) ? a : log1pf(__expf(a));
  }
}

// ------------- scan phase 1: per-chunk transition -------------
// 1024 blocks: b(1)|chunk(4)|dtile(5). 256 thr = 64 d x 4 n-quads (4 states each).
// 4-step batched prefetch of delta/u. States -> xz stash (aprod, sfin).
__global__ __launch_bounds__(256) void scan_phase1(
    const float* __restrict__ delta, const float* __restrict__ xc,
    const float* __restrict__ xdbl, const float* __restrict__ A_log,
    float* __restrict__ xz) {
  const int bx = blockIdx.x;
  const int b = bx >> 9;
  const int c = (bx >> 5) & 15;
  const int dt = bx & 31;
  const int tid = threadIdx.x;
  const int dl = tid >> 2, nq = tid & 3;
  const int d = dt * 64 + dl;
  const int row0 = b * L_SZ + c * CLEN;

  __shared__ float Bsh[CLEN][16];
  for (int i = tid; i < CLEN * 16; i += 256)
    Bsh[i >> 4][i & 15] = xdbl[(size_t)(row0 + (i >> 4)) * 96 + 64 + (i & 15)];

  float Av[4];
#pragma unroll
  for (int j = 0; j < 4; ++j) Av[j] = -__expf(A_log[d * 16 + nq * 4 + j]);
  float x[4] = {}, P[4] = {1.f, 1.f, 1.f, 1.f};
  __syncthreads();

  const float* dp = delta + (size_t)row0 * DI + d;
  const float* up = xc + (size_t)row0 * DI + d;
  float dB[4], uB[4];
#pragma unroll
  for (int j = 0; j < 4; ++j) { dB[j] = dp[(size_t)j * DI]; uB[j] = up[(size_t)j * DI]; }
  for (int l0 = 0; l0 < CLEN; l0 += 4) {
    float dN[4] = {}, uN[4] = {};
    if (l0 + 4 < CLEN) {
#pragma unroll
      for (int j = 0; j < 4; ++j) {
        dN[j] = dp[(size_t)(l0 + 4 + j) * DI];
        uN[j] = up[(size_t)(l0 + 4 + j) * DI];
      }
    }
#pragma unroll
    for (int jj = 0; jj < 4; ++jj) {
      const float dlt = dB[jj];
      const float t = dlt * uB[jj];
      const float* bb = &Bsh[l0 + jj][nq * 4];
#pragma unroll
      for (int n = 0; n < 4; ++n) {
        const float dA = __expf(dlt * Av[n]);
        P[n] *= dA;
        x[n] = fmaf(dA, x[n], t * bb[n]);
      }
    }
#pragma unroll
    for (int j = 0; j < 4; ++j) { dB[j] = dN[j]; uB[j] = uN[j]; }
  }
  const unsigned sb = ((unsigned)((b * NCHUNK + c) * DI + d)) * 16 + nq * 4;
  *(float4*)&xz[stash_addr(sb)] = make_float4(P[0], P[1], P[2], P[3]);
  *(float4*)&xz[stash_addr((1u << 20) + sb)] = make_float4(x[0], x[1], x[2], x[3]);
}

// ------------- scan phase 2: sequential chunk combine; sfin becomes xinit -------------
__global__ __launch_bounds__(256) void scan_phase2(float* __restrict__ xz) {
  const int t = blockIdx.x * 256 + threadIdx.x;  // (b, d, n) flat: 65536
  const int b = t >> 15;
  const int rem = t & 32767;
  float x = 0.f;
#pragma unroll
  for (int c = 0; c < NCHUNK; ++c) {
    const unsigned i = ((unsigned)(b * NCHUNK + c) << 15) + rem;
    float* Pr = &xz[stash_addr(i)];
    float* Sr = &xz[stash_addr((1u << 20) + i)];
    const float P = *Pr, S = *Sr;
    *Sr = x;  // xinit for chunk c
    x = fmaf(P, x, S);
  }
}

// ------------- scan phase 3: rescan w/ init + y + skip + gate -> bf16 y -------------
__global__ __launch_bounds__(256) void scan_phase3(
    const float* __restrict__ delta, const float* __restrict__ xc,
    const float* __restrict__ xdbl, const float* __restrict__ A_log,
    const float* __restrict__ Dskip, float* __restrict__ xz) {
  const int bx = blockIdx.x;
  const int b = bx >> 9;
  const int c = (bx >> 5) & 15;
  const int dt = bx & 31;
  const int tid = threadIdx.x;
  const int dl = tid >> 2, nq = tid & 3;
  const int d = dt * 64 + dl;
  const int row0 = b * L_SZ + c * CLEN;

  __shared__ float Bsh[CLEN][16], Csh[CLEN][16];
  for (int i = tid; i < CLEN * 32; i += 256) {
    const int r = i >> 5, q = i & 31;
    const float v = xdbl[(size_t)(row0 + r) * 96 + 64 + q];
    if (q < 16) Bsh[r][q] = v; else Csh[r][q - 16] = v;
  }

  float Av[4];
#pragma unroll
  for (int j = 0; j < 4; ++j) Av[j] = -__expf(A_log[d * 16 + nq * 4 + j]);
  const float Dsk = Dskip[d];
  const unsigned sb = ((unsigned)((b * NCHUNK + c) * DI + d)) * 16 + nq * 4;
  const float4 xi = *(const float4*)&xz[stash_addr((1u << 20) + sb)];
  float x[4] = {xi.x, xi.y, xi.z, xi.w};
  __syncthreads();

  const float* dp = delta + (size_t)row0 * DI + d;
  const float* up = xc + (size_t)row0 * DI + d;
  const float* zp = xz + (size_t)row0 * 4096 + DI + d;
  ushortT* yb = (ushortT*)xz;

  float dB[4], uB[4], zB[4];
#pragma unroll
  for (int j = 0; j < 4; ++j) {
    dB[j] = dp[(size_t)j * DI];
    uB[j] = up[(size_t)j * DI];
    zB[j] = zp[(size_t)j * 4096];
  }
  for (int l0 = 0; l0 < CLEN; l0 += 4) {
    float dN[4] = {}, uN[4] = {}, zN[4] = {};
    if (l0 + 4 < CLEN) {
#pragma unroll
      for (int j = 0; j < 4; ++j) {
        dN[j] = dp[(size_t)(l0 + 4 + j) * DI];
        uN[j] = up[(size_t)(l0 + 4 + j) * DI];
        zN[j] = zp[(size_t)(l0 + 4 + j) * 4096];
      }
    }
#pragma unroll
    for (int jj = 0; jj < 4; ++jj) {
      const float dlt = dB[jj];
      const float u = uB[jj];
      const float t = dlt * u;
      const float* bb = &Bsh[l0 + jj][nq * 4];
      const float* cc = &Csh[l0 + jj][nq * 4];
      float y = 0.f;
#pragma unroll
      for (int n = 0; n < 4; ++n) {
        const float dA = __expf(dlt * Av[n]);
        x[n] = fmaf(dA, x[n], t * bb[n]);
        y = fmaf(x[n], cc[n], y);
      }
      y += __shfl_xor(y, 1);
      y += __shfl_xor(y, 2);
      if (nq == 0) {
        const float z = zB[jj];
        const float g = (y + u * Dsk) * (z / (1.f + __expf(-z)));
        yb[(size_t)(row0 + l0 + jj) * 8192 + d] = f2bf(g);
      }
    }
#pragma unroll
    for (int j = 0; j < 4; ++j) { dB[j] = dN[j]; uB[j] = uN[j]; zB[j] = zN[j]; }
  }
}

extern "C" void kernel_launch(void* const* d_in, const int* in_sizes, int n_in,
                              void* d_out, int out_size, void* d_ws, size_t ws_size,
                              hipStream_t stream) {
  const float* hidden  = (const float*)d_in[0];
  const float* Win     = (const float*)d_in[1];
  const float* Wx      = (const float*)d_in[2];
  const float* Wdt     = (const float*)d_in[3];
  const float* dt_bias = (const float*)d_in[4];
  const float* Wout    = (const float*)d_in[5];
  const float* dwk     = (const float*)d_in[6];
  const float* dwb     = (const float*)d_in[7];
  const float* A_log   = (const float*)d_in[8];
  const float* Dskip   = (const float*)d_in[9];

  // ws (64 MB): xz 32MB | shared16 (WinT -> delta -> WoutT) 16MB | xc 16MB
  // xz per-row float layout: [0,1024) y-bf16 | [1024,2048) scan stash | [2048,4096) z
  char* ws = (char*)d_ws;
  float* xz       = (float*)ws;
  float* shared16 = (float*)(ws + (32u << 20));
  float* xc       = (float*)(ws + (48u << 20));
  // d_out (8 MB) doubles as scratch: hid_bf16 [0,4M); xdbl [4M,4.75M)
  char* dob = (char*)d_out;
  ushortT* hidb = (ushortT*)dob;
  float* xdbl   = (float*)(dob + (4u << 20));

  // 1. hidden -> bf16 (into d_out)
  cvt_bf16<<<dim3(B_SZ * L_SZ * DM / 1024), 256, 0, stream>>>(hidden, hidb);
  // 2. Win (1024x4096) -> WinT bf16 (4096x1024) in shared16
  transpose_bf16<<<dim3(4096 / 32, 1024 / 32), dim3(32, 8), 0, stream>>>(
      Win, (ushortT*)shared16, DM, 2 * DI);
  // 3. GEMM1: xz = hidden @ Win  (M=2048, N=4096, K=1024)
  gemm_bf16<128, 128><<<dim3(4096 / 128, 2048 / 128), 256, 0, stream>>>(
      hidb, DM, (ushortT*)shared16, DM, xz, 2 * DI, DM);
  // 4. depthwise conv + silu -> xc
  conv_silu<<<dim3(B_SZ * L_SZ, DI / 256), 256, 0, stream>>>(xz, dwk, dwb, xc);
  // 5. x_dbl = xc @ Wx (into d_out scratch), K-split + atomics
  zero_f32<<<dim3(B_SZ * L_SZ * 96 / 1024), 256, 0, stream>>>(xdbl);
  gemm_xdbl_split<<<dim3(128 * 16), 384, 0, stream>>>(xc, Wx, xdbl);
  // 6. delta = softplus(dt @ Wdt + bias) -> shared16 (WinT dead)
  gemm_delta<<<dim3(DI / 256, B_SZ * L_SZ / 16), 256, 0, stream>>>(
      xdbl, Wdt, dt_bias, shared16);
  // 7-9. chunked selective scan (states in xz stash); y (gated, bf16) -> xz
  scan_phase1<<<dim3(B_SZ * NCHUNK * (DI / 64)), 256, 0, stream>>>(
      shared16, xc, xdbl, A_log, xz);
  scan_phase2<<<dim3(B_SZ * DI * NS / 256), 256, 0, stream>>>(xz);
  scan_phase3<<<dim3(B_SZ * NCHUNK * (DI / 64)), 256, 0, stream>>>(
      shared16, xc, xdbl, A_log, Dskip, xz);
  // 10. Wout (2048x1024) -> WoutT bf16 (1024x2048) in shared16 (delta dead)
  transpose_bf16<<<dim3(1024 / 32, 2048 / 32), dim3(32, 8), 0, stream>>>(
      Wout, (ushortT*)shared16, DI, DM);
  // 11. GEMM4: out = y @ Wout  (M=2048, N=1024, K=2048); A = bf16 y, lda=8192
  gemm_bf16<128, 64><<<dim3(1024 / 64, 2048 / 128), 128, 0, stream>>>(
      (ushortT*)xz, 4 * DI, (ushortT*)shared16, DI, (float*)d_out, DM, DI);
}

// Round 7
// 338.560 us; speedup vs baseline: 1.3976x; 1.0410x over previous
//
#include <hip/hip_runtime.h>
#include <hip/hip_bf16.h>
#include <math.h>

#define B_SZ 2
#define L_SZ 1024
#define DM 1024
#define DI 2048
#define NS 16
#define DTR 64
#define NCHUNK 16
#define CLEN 64
#define XDLD 128  // padded x_dbl leading dim

typedef unsigned short ushortT;
typedef __attribute__((ext_vector_type(8))) short short8;
typedef __attribute__((ext_vector_type(4))) float floatx4;

__device__ __forceinline__ ushortT f2bf(float f) {
  unsigned u = __float_as_uint(f);
  unsigned r = (u + 0x7fff + ((u >> 16) & 1)) >> 16;
  return (ushortT)r;
}

__device__ __forceinline__ void gl2lds16(const void* g, void* l) {
  __builtin_amdgcn_global_load_lds(
      (const __attribute__((address_space(1))) unsigned int*)g,
      (__attribute__((address_space(3))) unsigned int*)l, 16, 0, 0);
}

// Scan-state stash lives in the dead strided region of xz: floats [1024,2048)
// of each 4096-float row. i in [0, 2M): aprod at i, sfin at i + 1M.
__device__ __forceinline__ unsigned stash_addr(unsigned i) {
  return (i >> 10) * 4096 + 1024 + (i & 1023);
}

// ---------------- f32 -> bf16 convert (4 elems/thread) ----------------
__global__ __launch_bounds__(256) void cvt_bf16(const float* __restrict__ src,
                                                ushortT* __restrict__ dst) {
  const int i = blockIdx.x * 256 + threadIdx.x;
  float4 v = ((const float4*)src)[i];
  unsigned lo = (unsigned)f2bf(v.x) | ((unsigned)f2bf(v.y) << 16);
  unsigned hi = (unsigned)f2bf(v.z) | ((unsigned)f2bf(v.w) << 16);
  ((uint2*)dst)[i] = make_uint2(lo, hi);
}

// ---------------- f32 [R][C] -> bf16 [C][R] transpose ----------------
__global__ __launch_bounds__(256) void transpose_bf16(
    const float* __restrict__ src, ushortT* __restrict__ dst, int R, int C) {
  __shared__ float t[32][33];
  const int bx = blockIdx.x * 32;  // col base
  const int by = blockIdx.y * 32;  // row base
  const int tx = threadIdx.x, ty = threadIdx.y;  // (32,8)
#pragma unroll
  for (int j = 0; j < 4; ++j)
    t[ty + j * 8][tx] = src[(size_t)(by + ty + j * 8) * C + bx + tx];
  __syncthreads();
#pragma unroll
  for (int j = 0; j < 4; ++j)
    dst[(size_t)(bx + ty + j * 8) * R + by + tx] = f2bf(t[tx][ty + j * 8]);
}

// ---------------- Wx (2048x96) -> WxT bf16 (128x2048), rows 96..127 zero ----------------
__global__ __launch_bounds__(256) void wx_pad_t(const float* __restrict__ Wx,
                                                ushortT* __restrict__ WxT) {
  const int k = blockIdx.x * 256 + threadIdx.x;  // 0..2047
  const int n = blockIdx.y;                      // 0..127
  WxT[(size_t)n * DI + k] = (n < 96) ? f2bf(Wx[(size_t)k * 96 + n]) : (ushortT)0;
}

// ---------------- bf16 MFMA GEMM: C[M][N] f32 = A[M][K] @ BT[N][K]^T ----------------
// m97-style: BK=32, global_load_lds width=16, XOR chunk swizzle, 16x16x32 MFMA.
template <int BM, int BN>
__global__ __launch_bounds__((BM / 64) * (BN / 64) * 64) void gemm_bf16(
    const ushortT* __restrict__ A, int lda,
    const ushortT* __restrict__ BT, int ldb,
    float* __restrict__ C, int ldc, int K) {
  constexpr int NW = (BM / 64) * (BN / 64);
  constexpr int NT = NW * 64;
  __shared__ __align__(16) char smem[(BM + BN) * 64];
  char* As = smem;
  char* Bs = smem + BM * 64;
  const int tid = threadIdx.x;
  const int lane = tid & 63;
  const int quad = lane >> 4;
  const int l16 = lane & 15;
  const int wid = tid >> 6;
  const int wm = wid % (BM / 64);
  const int wn = wid / (BM / 64);
  const int m0 = blockIdx.y * BM;
  const int n0 = blockIdx.x * BN;

  floatx4 acc[4][4] = {};

  for (int k0 = 0; k0 < K; k0 += 32) {
    for (int i = tid; i < BM * 4; i += NT) {
      const int r = i >> 2, c = i & 3;
      const int cg = c ^ (r & 3);
      const char* g = (const char*)(A + (size_t)(m0 + r) * lda + k0) + cg * 16;
      gl2lds16(g, As + (size_t)(i - lane) * 16);
    }
    for (int i = tid; i < BN * 4; i += NT) {
      const int r = i >> 2, c = i & 3;
      const int cg = c ^ (r & 3);
      const char* g = (const char*)(BT + (size_t)(n0 + r) * ldb + k0) + cg * 16;
      gl2lds16(g, Bs + (size_t)(i - lane) * 16);
    }
    __syncthreads();

    short8 afr[4], bfr[4];
#pragma unroll
    for (int i = 0; i < 4; ++i) {
      const int r = wm * 64 + i * 16 + l16;
      afr[i] = *(const short8*)(As + r * 64 + ((quad ^ (r & 3)) * 16));
    }
#pragma unroll
    for (int j = 0; j < 4; ++j) {
      const int r = wn * 64 + j * 16 + l16;
      bfr[j] = *(const short8*)(Bs + r * 64 + ((quad ^ (r & 3)) * 16));
    }
#pragma unroll
    for (int i = 0; i < 4; ++i)
#pragma unroll
      for (int j = 0; j < 4; ++j)
        acc[i][j] = __builtin_amdgcn_mfma_f32_16x16x32_bf16(afr[i], bfr[j],
                                                            acc[i][j], 0, 0, 0);
    __syncthreads();
  }
#pragma unroll
  for (int i = 0; i < 4; ++i)
#pragma unroll
    for (int j = 0; j < 4; ++j)
#pragma unroll
      for (int r = 0; r < 4; ++r) {
        const int m = m0 + wm * 64 + i * 16 + quad * 4 + r;
        const int n = n0 + wn * 64 + j * 16 + l16;
        C[(size_t)m * ldc + n] = acc[i][j][r];
      }
}

// ------------- x_dbl = xc @ Wx (padded N=128) via MFMA -------------
// BM=64, BN=128, BK=32, 4 waves (2 wm x 2 wn). A staged f32 (XOR mod-8 chunk
// swizzle) and converted f32->bf16 in-register; B = WxT bf16 (m97 swizzle).
__global__ __launch_bounds__(256) void gemm_xdbl_mfma(
    const float* __restrict__ xc, const ushortT* __restrict__ WxT,
    float* __restrict__ xdbl) {
  __shared__ __align__(16) char smem[64 * 128 + 128 * 64];
  char* As = smem;             // [64 r][128 B f32]
  char* Bs = smem + 64 * 128;  // [128 r][64 B bf16]
  const int tid = threadIdx.x;
  const int lane = tid & 63;
  const int quad = lane >> 4;
  const int l16 = lane & 15;
  const int wid = tid >> 6;
  const int wm = wid & 1;
  const int wn = wid >> 1;
  const int m0 = blockIdx.x * 64;

  floatx4 acc[2][4] = {};

  for (int k0 = 0; k0 < DI; k0 += 32) {
    for (int i = tid; i < 64 * 8; i += 256) {
      const int r = i >> 3, c = i & 7;
      const int cg = c ^ (r & 7);
      gl2lds16(xc + (size_t)(m0 + r) * DI + k0 + cg * 4, As + (i - lane) * 16);
    }
    for (int i = tid; i < 128 * 4; i += 256) {
      const int r = i >> 2, c = i & 3;
      const int cg = c ^ (r & 3);
      gl2lds16(WxT + (size_t)r * DI + k0 + cg * 8, Bs + (i - lane) * 16);
    }
    __syncthreads();

    short8 afr[2], bfr[4];
#pragma unroll
    for (int i = 0; i < 2; ++i) {
      const int m = wm * 32 + i * 16 + l16;
      const float4 x0 = *(const float4*)(As + m * 128 + (((quad * 2 + 0) ^ (m & 7)) * 16));
      const float4 x1 = *(const float4*)(As + m * 128 + (((quad * 2 + 1) ^ (m & 7)) * 16));
      short8 f;
      f[0] = (short)f2bf(x0.x); f[1] = (short)f2bf(x0.y);
      f[2] = (short)f2bf(x0.z); f[3] = (short)f2bf(x0.w);
      f[4] = (short)f2bf(x1.x); f[5] = (short)f2bf(x1.y);
      f[6] = (short)f2bf(x1.z); f[7] = (short)f2bf(x1.w);
      afr[i] = f;
    }
#pragma unroll
    for (int j = 0; j < 4; ++j) {
      const int n = wn * 64 + j * 16 + l16;
      bfr[j] = *(const short8*)(Bs + n * 64 + ((quad ^ (n & 3)) * 16));
    }
#pragma unroll
    for (int i = 0; i < 2; ++i)
#pragma unroll
      for (int j = 0; j < 4; ++j)
        acc[i][j] = __builtin_amdgcn_mfma_f32_16x16x32_bf16(afr[i], bfr[j],
                                                            acc[i][j], 0, 0, 0);
    __syncthreads();
  }
#pragma unroll
  for (int i = 0; i < 2; ++i)
#pragma unroll
    for (int j = 0; j < 4; ++j)
#pragma unroll
      for (int r = 0; r < 4; ++r) {
        const int m = m0 + wm * 32 + i * 16 + quad * 4 + r;
        const int n = wn * 64 + j * 16 + l16;
        xdbl[(size_t)m * XDLD + n] = acc[i][j][r];
      }
}

// ------------- causal depthwise conv (k=4) + silu -> xc f32 -------------
__global__ __launch_bounds__(256) void conv_silu(
    const float* __restrict__ xz, const float* __restrict__ kern,
    const float* __restrict__ bias, float* __restrict__ xc) {
  const int d = blockIdx.y * 256 + threadIdx.x;
  const int row = blockIdx.x;
  const int l = row & (L_SZ - 1);
  float acc = bias[d];
#pragma unroll
  for (int i = 0; i < 4; ++i) {
    const int li = l - 3 + i;
    if (li >= 0) acc = fmaf(xz[(size_t)(row - 3 + i) * 4096 + d], kern[i * DI + d], acc);
  }
  xc[(size_t)row * DI + d] = acc / (1.f + __expf(-acc));
}

// ------------- delta = softplus(dt @ Wdt + dt_bias) -------------
__global__ __launch_bounds__(256) void gemm_delta(
    const float* __restrict__ xdbl, const float* __restrict__ Wdt,
    const float* __restrict__ dt_bias, float* __restrict__ delta) {
  __shared__ float dtL[16][64];
  const int col = blockIdx.x * 256 + threadIdx.x;
  const int row0 = blockIdx.y * 16;
  for (int i = threadIdx.x; i < 16 * 64; i += 256) {
    const int r = i >> 6, k = i & 63;
    dtL[r][k] = xdbl[(size_t)(row0 + r) * XDLD + k];
  }
  __syncthreads();
  const float bias = dt_bias[col];
  float acc[16];
#pragma unroll
  for (int r = 0; r < 16; ++r) acc[r] = bias;
  for (int k8 = 0; k8 < 64; k8 += 8) {
    float w[8];
#pragma unroll
    for (int j = 0; j < 8; ++j) w[j] = Wdt[(size_t)(k8 + j) * DI + col];
#pragma unroll
    for (int r = 0; r < 16; ++r) {
      float a = acc[r];
#pragma unroll
      for (int j = 0; j < 8; ++j) a = fmaf(dtL[r][k8 + j], w[j], a);
      acc[r] = a;
    }
  }
#pragma unroll
  for (int r = 0; r < 16; ++r) {
    const float a = acc[r];
    delta[(size_t)(row0 + r) * DI + col] = (a > 20.f) ? a : log1pf(__expf(a));
  }
}

// ------------- scan phase 1: per-chunk transition -------------
__global__ __launch_bounds__(256) void scan_phase1(
    const float* __restrict__ delta, const float* __restrict__ xc,
    const float* __restrict__ xdbl, const float* __restrict__ A_log,
    float* __restrict__ xz) {
  const int bx = blockIdx.x;
  const int b = bx >> 9;
  const int c = (bx >> 5) & 15;
  const int dt = bx & 31;
  const int tid = threadIdx.x;
  const int dl = tid >> 2, nq = tid & 3;
  const int d = dt * 64 + dl;
  const int row0 = b * L_SZ + c * CLEN;

  __shared__ float Bsh[CLEN][16];
  for (int i = tid; i < CLEN * 16; i += 256)
    Bsh[i >> 4][i & 15] = xdbl[(size_t)(row0 + (i >> 4)) * XDLD + 64 + (i & 15)];

  float Av[4];
#pragma unroll
  for (int j = 0; j < 4; ++j) Av[j] = -__expf(A_log[d * 16 + nq * 4 + j]);
  float x[4] = {}, P[4] = {1.f, 1.f, 1.f, 1.f};
  __syncthreads();

  const float* dp = delta + (size_t)row0 * DI + d;
  const float* up = xc + (size_t)row0 * DI + d;
  float dB[4], uB[4];
#pragma unroll
  for (int j = 0; j < 4; ++j) { dB[j] = dp[(size_t)j * DI]; uB[j] = up[(size_t)j * DI]; }
  for (int l0 = 0; l0 < CLEN; l0 += 4) {
    float dN[4] = {}, uN[4] = {};
    if (l0 + 4 < CLEN) {
#pragma unroll
      for (int j = 0; j < 4; ++j) {
        dN[j] = dp[(size_t)(l0 + 4 + j) * DI];
        uN[j] = up[(size_t)(l0 + 4 + j) * DI];
      }
    }
#pragma unroll
    for (int jj = 0; jj < 4; ++jj) {
      const float dlt = dB[jj];
      const float t = dlt * uB[jj];
      const float* bb = &Bsh[l0 + jj][nq * 4];
#pragma unroll
      for (int n = 0; n < 4; ++n) {
        const float dA = __expf(dlt * Av[n]);
        P[n] *= dA;
        x[n] = fmaf(dA, x[n], t * bb[n]);
      }
    }
#pragma unroll
    for (int j = 0; j < 4; ++j) { dB[j] = dN[j]; uB[j] = uN[j]; }
  }
  const unsigned sb = ((unsigned)((b * NCHUNK + c) * DI + d)) * 16 + nq * 4;
  *(float4*)&xz[stash_addr(sb)] = make_float4(P[0], P[1], P[2], P[3]);
  *(float4*)&xz[stash_addr((1u << 20) + sb)] = make_float4(x[0], x[1], x[2], x[3]);
}

// ------------- scan phase 2: sequential chunk combine -------------
__global__ __launch_bounds__(256) void scan_phase2(float* __restrict__ xz) {
  const int t = blockIdx.x * 256 + threadIdx.x;
  const int b = t >> 15;
  const int rem = t & 32767;
  float x = 0.f;
#pragma unroll
  for (int c = 0; c < NCHUNK; ++c) {
    const unsigned i = ((unsigned)(b * NCHUNK + c) << 15) + rem;
    float* Pr = &xz[stash_addr(i)];
    float* Sr = &xz[stash_addr((1u << 20) + i)];
    const float P = *Pr, S = *Sr;
    *Sr = x;
    x = fmaf(P, x, S);
  }
}

// ------------- scan phase 3: rescan w/ init + y + skip + gate -> bf16 y -------------
__global__ __launch_bounds__(256) void scan_phase3(
    const float* __restrict__ delta, const float* __restrict__ xc,
    const float* __restrict__ xdbl, const float* __restrict__ A_log,
    const float* __restrict__ Dskip, float* __restrict__ xz) {
  const int bx = blockIdx.x;
  const int b = bx >> 9;
  const int c = (bx >> 5) & 15;
  const int dt = bx & 31;
  const int tid = threadIdx.x;
  const int dl = tid >> 2, nq = tid & 3;
  const int d = dt * 64 + dl;
  const int row0 = b * L_SZ + c * CLEN;

  __shared__ float Bsh[CLEN][16], Csh[CLEN][16];
  for (int i = tid; i < CLEN * 32; i += 256) {
    const int r = i >> 5, q = i & 31;
    const float v = xdbl[(size_t)(row0 + r) * XDLD + 64 + q];
    if (q < 16) Bsh[r][q] = v; else Csh[r][q - 16] = v;
  }

  float Av[4];
#pragma unroll
  for (int j = 0; j < 4; ++j) Av[j] = -__expf(A_log[d * 16 + nq * 4 + j]);
  const float Dsk = Dskip[d];
  const unsigned sb = ((unsigned)((b * NCHUNK + c) * DI + d)) * 16 + nq * 4;
  const float4 xi = *(const float4*)&xz[stash_addr((1u << 20) + sb)];
  float x[4] = {xi.x, xi.y, xi.z, xi.w};
  __syncthreads();

  const float* dp = delta + (size_t)row0 * DI + d;
  const float* up = xc + (size_t)row0 * DI + d;
  const float* zp = xz + (size_t)row0 * 4096 + DI + d;
  ushortT* yb = (ushortT*)xz;

  float dB[4], uB[4], zB[4];
#pragma unroll
  for (int j = 0; j < 4; ++j) {
    dB[j] = dp[(size_t)j * DI];
    uB[j] = up[(size_t)j * DI];
    zB[j] = zp[(size_t)j * 4096];
  }
  for (int l0 = 0; l0 < CLEN; l0 += 4) {
    float dN[4] = {}, uN[4] = {}, zN[4] = {};
    if (l0 + 4 < CLEN) {
#pragma unroll
      for (int j = 0; j < 4; ++j) {
        dN[j] = dp[(size_t)(l0 + 4 + j) * DI];
        uN[j] = up[(size_t)(l0 + 4 + j) * DI];
        zN[j] = zp[(size_t)(l0 + 4 + j) * 4096];
      }
    }
#pragma unroll
    for (int jj = 0; jj < 4; ++jj) {
      const float dlt = dB[jj];
      const float u = uB[jj];
      const float t = dlt * u;
      const float* bb = &Bsh[l0 + jj][nq * 4];
      const float* cc = &Csh[l0 + jj][nq * 4];
      float y = 0.f;
#pragma unroll
      for (int n = 0; n < 4; ++n) {
        const float dA = __expf(dlt * Av[n]);
        x[n] = fmaf(dA, x[n], t * bb[n]);
        y = fmaf(x[n], cc[n], y);
      }
      y += __shfl_xor(y, 1);
      y += __shfl_xor(y, 2);
      if (nq == 0) {
        const float z = zB[jj];
        const float g = (y + u * Dsk) * (z / (1.f + __expf(-z)));
        yb[(size_t)(row0 + l0 + jj) * 8192 + d] = f2bf(g);
      }
    }
#pragma unroll
    for (int j = 0; j < 4; ++j) { dB[j] = dN[j]; uB[j] = uN[j]; zB[j] = zN[j]; }
  }
}

extern "C" void kernel_launch(void* const* d_in, const int* in_sizes, int n_in,
                              void* d_out, int out_size, void* d_ws, size_t ws_size,
                              hipStream_t stream) {
  const float* hidden  = (const float*)d_in[0];
  const float* Win     = (const float*)d_in[1];
  const float* Wx      = (const float*)d_in[2];
  const float* Wdt     = (const float*)d_in[3];
  const float* dt_bias = (const float*)d_in[4];
  const float* Wout    = (const float*)d_in[5];
  const float* dwk     = (const float*)d_in[6];
  const float* dwb     = (const float*)d_in[7];
  const float* A_log   = (const float*)d_in[8];
  const float* Dskip   = (const float*)d_in[9];

  // ws (64 MB): xz 32MB | shared16 (WinT -> delta -> WoutT) 16MB | xc 16MB
  // xz per-row float layout: [0,1024) y-bf16 | [1024,2048) scan stash | [2048,4096) z
  char* ws = (char*)d_ws;
  float* xz       = (float*)ws;
  float* shared16 = (float*)(ws + (32u << 20));
  float* xc       = (float*)(ws + (48u << 20));
  // d_out (8 MB) scratch: hidb [0,4M) (dead after GEMM1); xdbl128 [4M,5M); WxT [5M,5.5M)
  char* dob = (char*)d_out;
  ushortT* hidb = (ushortT*)dob;
  float* xdbl   = (float*)(dob + (4u << 20));
  ushortT* WxT  = (ushortT*)(dob + (5u << 20));

  // 1. hidden -> bf16
  cvt_bf16<<<dim3(B_SZ * L_SZ * DM / 1024), 256, 0, stream>>>(hidden, hidb);
  // 2. Win (1024x4096) -> WinT bf16 (4096x1024) in shared16
  transpose_bf16<<<dim3(4096 / 32, 1024 / 32), dim3(32, 8), 0, stream>>>(
      Win, (ushortT*)shared16, DM, 2 * DI);
  // 3. Wx -> WxT bf16 padded (128 x 2048)
  wx_pad_t<<<dim3(DI / 256, 128), 256, 0, stream>>>(Wx, WxT);
  // 4. GEMM1: xz = hidden @ Win  (M=2048, N=4096, K=1024)
  gemm_bf16<128, 128><<<dim3(4096 / 128, 2048 / 128), 256, 0, stream>>>(
      hidb, DM, (ushortT*)shared16, DM, xz, 2 * DI, DM);
  // 5. depthwise conv + silu -> xc f32
  conv_silu<<<dim3(B_SZ * L_SZ, DI / 256), 256, 0, stream>>>(xz, dwk, dwb, xc);
  // 6. x_dbl = xc @ Wx via MFMA (padded N=128) -> xdbl128
  gemm_xdbl_mfma<<<dim3(B_SZ * L_SZ / 64), 256, 0, stream>>>(xc, WxT, xdbl);
  // 7. delta = softplus(dt @ Wdt + bias) -> shared16 (WinT dead)
  gemm_delta<<<dim3(DI / 256, B_SZ * L_SZ / 16), 256, 0, stream>>>(
      xdbl, Wdt, dt_bias, shared16);
  // 8-10. chunked selective scan (states in xz stash); y (gated, bf16) -> xz
  scan_phase1<<<dim3(B_SZ * NCHUNK * (DI / 64)), 256, 0, stream>>>(
      shared16, xc, xdbl, A_log, xz);
  scan_phase2<<<dim3(B_SZ * DI * NS / 256), 256, 0, stream>>>(xz);
  scan_phase3<<<dim3(B_SZ * NCHUNK * (DI / 64)), 256, 0, stream>>>(
      shared16, xc, xdbl, A_log, Dskip, xz);
  // 11. Wout (2048x1024) -> WoutT bf16 (1024x2048) in shared16 (delta dead)
  transpose_bf16<<<dim3(1024 / 32, 2048 / 32), dim3(32, 8), 0, stream>>>(
      Wout, (ushortT*)shared16, DI, DM);
  // 12. GEMM4: out = y @ Wout  (M=2048, N=1024, K=2048); A = bf16 y, lda=8192
  gemm_bf16<128, 64><<<dim3(1024 / 64, 2048 / 128), 128, 0, stream>>>(
      (ushortT*)xz, 4 * DI, (ushortT*)shared16, DI, (float*)d_out, DM, DI);
}

// Round 8
// 298.305 us; speedup vs baseline: 1.5862x; 1.1349x over previous
//
#include <hip/hip_runtime.h>
#include <hip/hip_bf16.h>
#include <math.h>

#define B_SZ 2
#define L_SZ 1024
#define DM 1024
#define DI 2048
#define NS 16
#define DTR 64
#define NCHUNK 16
#define CLEN 64
#define XDLD 128  // padded x_dbl leading dim
#define KSPLIT 8

typedef unsigned short ushortT;
typedef __attribute__((ext_vector_type(8))) short short8;
typedef __attribute__((ext_vector_type(4))) float floatx4;

__device__ __forceinline__ ushortT f2bf(float f) {
  unsigned u = __float_as_uint(f);
  unsigned r = (u + 0x7fff + ((u >> 16) & 1)) >> 16;
  return (ushortT)r;
}

__device__ __forceinline__ void gl2lds16(const void* g, void* l) {
  __builtin_amdgcn_global_load_lds(
      (const __attribute__((address_space(1))) unsigned int*)g,
      (__attribute__((address_space(3))) unsigned int*)l, 16, 0, 0);
}

// Scan-state stash lives in the dead strided region of xz: floats [1024,2048)
// of each 4096-float row. i in [0, 2M): aprod at i, sfin at i + 1M.
__device__ __forceinline__ unsigned stash_addr(unsigned i) {
  return (i >> 10) * 4096 + 1024 + (i & 1023);
}

// ---------------- f32 -> bf16 convert (4 elems/thread) ----------------
__global__ __launch_bounds__(256) void cvt_bf16(const float* __restrict__ src,
                                                ushortT* __restrict__ dst) {
  const int i = blockIdx.x * 256 + threadIdx.x;
  float4 v = ((const float4*)src)[i];
  unsigned lo = (unsigned)f2bf(v.x) | ((unsigned)f2bf(v.y) << 16);
  unsigned hi = (unsigned)f2bf(v.z) | ((unsigned)f2bf(v.w) << 16);
  ((uint2*)dst)[i] = make_uint2(lo, hi);
}

// ---------------- f32 [R][C] -> bf16 [C][R] transpose ----------------
__global__ __launch_bounds__(256) void transpose_bf16(
    const float* __restrict__ src, ushortT* __restrict__ dst, int R, int C) {
  __shared__ float t[32][33];
  const int bx = blockIdx.x * 32;  // col base
  const int by = blockIdx.y * 32;  // row base
  const int tx = threadIdx.x, ty = threadIdx.y;  // (32,8)
#pragma unroll
  for (int j = 0; j < 4; ++j)
    t[ty + j * 8][tx] = src[(size_t)(by + ty + j * 8) * C + bx + tx];
  __syncthreads();
#pragma unroll
  for (int j = 0; j < 4; ++j)
    dst[(size_t)(bx + ty + j * 8) * R + by + tx] = f2bf(t[tx][ty + j * 8]);
}

// ---------------- Wx (2048x96) -> WxT bf16 (128x2048), rows 96..127 zero ----------------
__global__ __launch_bounds__(256) void wx_pad_t(const float* __restrict__ Wx,
                                                ushortT* __restrict__ WxT) {
  const int k = blockIdx.x * 256 + threadIdx.x;  // 0..2047
  const int n = blockIdx.y;                      // 0..127
  WxT[(size_t)n * DI + k] = (n < 96) ? f2bf(Wx[(size_t)k * 96 + n]) : (ushortT)0;
}

// ---------------- bf16 MFMA GEMM: C[M][N] f32 = A[M][K] @ BT[N][K]^T ----------------
// m97-style: BK=32, global_load_lds width=16, XOR chunk swizzle, 16x16x32 MFMA.
template <int BM, int BN>
__global__ __launch_bounds__((BM / 64) * (BN / 64) * 64) void gemm_bf16(
    const ushortT* __restrict__ A, int lda,
    const ushortT* __restrict__ BT, int ldb,
    float* __restrict__ C, int ldc, int K) {
  constexpr int NW = (BM / 64) * (BN / 64);
  constexpr int NT = NW * 64;
  __shared__ __align__(16) char smem[(BM + BN) * 64];
  char* As = smem;
  char* Bs = smem + BM * 64;
  const int tid = threadIdx.x;
  const int lane = tid & 63;
  const int quad = lane >> 4;
  const int l16 = lane & 15;
  const int wid = tid >> 6;
  const int wm = wid % (BM / 64);
  const int wn = wid / (BM / 64);
  const int m0 = blockIdx.y * BM;
  const int n0 = blockIdx.x * BN;

  floatx4 acc[4][4] = {};

  for (int k0 = 0; k0 < K; k0 += 32) {
    for (int i = tid; i < BM * 4; i += NT) {
      const int r = i >> 2, c = i & 3;
      const int cg = c ^ (r & 3);
      const char* g = (const char*)(A + (size_t)(m0 + r) * lda + k0) + cg * 16;
      gl2lds16(g, As + (size_t)(i - lane) * 16);
    }
    for (int i = tid; i < BN * 4; i += NT) {
      const int r = i >> 2, c = i & 3;
      const int cg = c ^ (r & 3);
      const char* g = (const char*)(BT + (size_t)(n0 + r) * ldb + k0) + cg * 16;
      gl2lds16(g, Bs + (size_t)(i - lane) * 16);
    }
    __syncthreads();

    short8 afr[4], bfr[4];
#pragma unroll
    for (int i = 0; i < 4; ++i) {
      const int r = wm * 64 + i * 16 + l16;
      afr[i] = *(const short8*)(As + r * 64 + ((quad ^ (r & 3)) * 16));
    }
#pragma unroll
    for (int j = 0; j < 4; ++j) {
      const int r = wn * 64 + j * 16 + l16;
      bfr[j] = *(const short8*)(Bs + r * 64 + ((quad ^ (r & 3)) * 16));
    }
#pragma unroll
    for (int i = 0; i < 4; ++i)
#pragma unroll
      for (int j = 0; j < 4; ++j)
        acc[i][j] = __builtin_amdgcn_mfma_f32_16x16x32_bf16(afr[i], bfr[j],
                                                            acc[i][j], 0, 0, 0);
    __syncthreads();
  }
#pragma unroll
  for (int i = 0; i < 4; ++i)
#pragma unroll
    for (int j = 0; j < 4; ++j)
#pragma unroll
      for (int r = 0; r < 4; ++r) {
        const int m = m0 + wm * 64 + i * 16 + quad * 4 + r;
        const int n = n0 + wn * 64 + j * 16 + l16;
        C[(size_t)m * ldc + n] = acc[i][j][r];
      }
}

// ------------- x_dbl partials: xc @ Wx (padded N=128), K-split via MFMA -------------
// grid (32 m-tiles, 8 k-slices). BM=64, BN=128, per-slice K=256 (8 x BK=32).
// A staged f32 (XOR mod-8 swizzle), converted f32->bf16 in-register.
__global__ __launch_bounds__(256) void gemm_xdbl_mfma(
    const float* __restrict__ xc, const ushortT* __restrict__ WxT,
    float* __restrict__ part) {
  __shared__ __align__(16) char smem[64 * 128 + 128 * 64];
  char* As = smem;             // [64 r][128 B f32]
  char* Bs = smem + 64 * 128;  // [128 r][64 B bf16]
  const int tid = threadIdx.x;
  const int lane = tid & 63;
  const int quad = lane >> 4;
  const int l16 = lane & 15;
  const int wid = tid >> 6;
  const int wm = wid & 1;
  const int wn = wid >> 1;
  const int m0 = blockIdx.x * 64;
  const int kbase = blockIdx.y * (DI / KSPLIT);

  floatx4 acc[2][4] = {};

  for (int kk = 0; kk < DI / KSPLIT; kk += 32) {
    const int k0 = kbase + kk;
    for (int i = tid; i < 64 * 8; i += 256) {
      const int r = i >> 3, c = i & 7;
      const int cg = c ^ (r & 7);
      gl2lds16(xc + (size_t)(m0 + r) * DI + k0 + cg * 4, As + (i - lane) * 16);
    }
    for (int i = tid; i < 128 * 4; i += 256) {
      const int r = i >> 2, c = i & 3;
      const int cg = c ^ (r & 3);
      gl2lds16(WxT + (size_t)r * DI + k0 + cg * 8, Bs + (i - lane) * 16);
    }
    __syncthreads();

    short8 afr[2], bfr[4];
#pragma unroll
    for (int i = 0; i < 2; ++i) {
      const int m = wm * 32 + i * 16 + l16;
      const float4 x0 = *(const float4*)(As + m * 128 + (((quad * 2 + 0) ^ (m & 7)) * 16));
      const float4 x1 = *(const float4*)(As + m * 128 + (((quad * 2 + 1) ^ (m & 7)) * 16));
      short8 f;
      f[0] = (short)f2bf(x0.x); f[1] = (short)f2bf(x0.y);
      f[2] = (short)f2bf(x0.z); f[3] = (short)f2bf(x0.w);
      f[4] = (short)f2bf(x1.x); f[5] = (short)f2bf(x1.y);
      f[6] = (short)f2bf(x1.z); f[7] = (short)f2bf(x1.w);
      afr[i] = f;
    }
#pragma unroll
    for (int j = 0; j < 4; ++j) {
      const int n = wn * 64 + j * 16 + l16;
      bfr[j] = *(const short8*)(Bs + n * 64 + ((quad ^ (n & 3)) * 16));
    }
#pragma unroll
    for (int i = 0; i < 2; ++i)
#pragma unroll
      for (int j = 0; j < 4; ++j)
        acc[i][j] = __builtin_amdgcn_mfma_f32_16x16x32_bf16(afr[i], bfr[j],
                                                            acc[i][j], 0, 0, 0);
    __syncthreads();
  }
  float* out = part + (size_t)blockIdx.y * (B_SZ * L_SZ * XDLD);
#pragma unroll
  for (int i = 0; i < 2; ++i)
#pragma unroll
    for (int j = 0; j < 4; ++j)
#pragma unroll
      for (int r = 0; r < 4; ++r) {
        const int m = m0 + wm * 32 + i * 16 + quad * 4 + r;
        const int n = wn * 64 + j * 16 + l16;
        out[(size_t)m * XDLD + n] = acc[i][j][r];
      }
}

// ------------- xdbl = sum of KSPLIT partials (float4 per thread) -------------
__global__ __launch_bounds__(256) void xdbl_reduce(const float* __restrict__ part,
                                                   float* __restrict__ xdbl) {
  const int i = blockIdx.x * 256 + threadIdx.x;  // float4 index, [0, 65536)
  float4 a = ((const float4*)part)[i];
#pragma unroll
  for (int s = 1; s < KSPLIT; ++s) {
    const float4 b = ((const float4*)part)[(size_t)s * (B_SZ * L_SZ * XDLD / 4) + i];
    a.x += b.x; a.y += b.y; a.z += b.z; a.w += b.w;
  }
  ((float4*)xdbl)[i] = a;
}

// ------------- causal depthwise conv (k=4) + silu -> xc f32 -------------
__global__ __launch_bounds__(256) void conv_silu(
    const float* __restrict__ xz, const float* __restrict__ kern,
    const float* __restrict__ bias, float* __restrict__ xc) {
  const int d = blockIdx.y * 256 + threadIdx.x;
  const int row = blockIdx.x;
  const int l = row & (L_SZ - 1);
  float acc = bias[d];
#pragma unroll
  for (int i = 0; i < 4; ++i) {
    const int li = l - 3 + i;
    if (li >= 0) acc = fmaf(xz[(size_t)(row - 3 + i) * 4096 + d], kern[i * DI + d], acc);
  }
  xc[(size_t)row * DI + d] = acc / (1.f + __expf(-acc));
}

// ------------- delta = softplus(dt @ Wdt + dt_bias) -------------
__global__ __launch_bounds__(256) void gemm_delta(
    const float* __restrict__ xdbl, const float* __restrict__ Wdt,
    const float* __restrict__ dt_bias, float* __restrict__ delta) {
  __shared__ float dtL[16][64];
  const int col = blockIdx.x * 256 + threadIdx.x;
  const int row0 = blockIdx.y * 16;
  for (int i = threadIdx.x; i < 16 * 64; i += 256) {
    const int r = i >> 6, k = i & 63;
    dtL[r][k] = xdbl[(size_t)(row0 + r) * XDLD + k];
  }
  __syncthreads();
  const float bias = dt_bias[col];
  float acc[16];
#pragma unroll
  for (int r = 0; r < 16; ++r) acc[r] = bias;
  for (int k8 = 0; k8 < 64; k8 += 8) {
    float w[8];
#pragma unroll
    for (int j = 0; j < 8; ++j) w[j] = Wdt[(size_t)(k8 + j) * DI + col];
#pragma unroll
    for (int r = 0; r < 16; ++r) {
      float a = acc[r];
#pragma unroll
      for (int j = 0; j < 8; ++j) a = fmaf(dtL[r][k8 + j], w[j], a);
      acc[r] = a;
    }
  }
#pragma unroll
  for (int r = 0; r < 16; ++r) {
    const float a = acc[r];
    delta[(size_t)(row0 + r) * DI + col] = (a > 20.f) ? a : log1pf(__expf(a));
  }
}

// ------------- scan phase 1: per-chunk transition -------------
__global__ __launch_bounds__(256) void scan_phase1(
    const float* __restrict__ delta, const float* __restrict__ xc,
    const float* __restrict__ xdbl, const float* __restrict__ A_log,
    float* __restrict__ xz) {
  const int bx = blockIdx.x;
  const int b = bx >> 9;
  const int c = (bx >> 5) & 15;
  const int dt = bx & 31;
  const int tid = threadIdx.x;
  const int dl = tid >> 2, nq = tid & 3;
  const int d = dt * 64 + dl;
  const int row0 = b * L_SZ + c * CLEN;

  __shared__ float Bsh[CLEN][16];
  for (int i = tid; i < CLEN * 16; i += 256)
    Bsh[i >> 4][i & 15] = xdbl[(size_t)(row0 + (i >> 4)) * XDLD + 64 + (i & 15)];

  float Av[4];
#pragma unroll
  for (int j = 0; j < 4; ++j) Av[j] = -__expf(A_log[d * 16 + nq * 4 + j]);
  float x[4] = {}, P[4] = {1.f, 1.f, 1.f, 1.f};
  __syncthreads();

  const float* dp = delta + (size_t)row0 * DI + d;
  const float* up = xc + (size_t)row0 * DI + d;
  float dB[4], uB[4];
#pragma unroll
  for (int j = 0; j < 4; ++j) { dB[j] = dp[(size_t)j * DI]; uB[j] = up[(size_t)j * DI]; }
  for (int l0 = 0; l0 < CLEN; l0 += 4) {
    float dN[4] = {}, uN[4] = {};
    if (l0 + 4 < CLEN) {
#pragma unroll
      for (int j = 0; j < 4; ++j) {
        dN[j] = dp[(size_t)(l0 + 4 + j) * DI];
        uN[j] = up[(size_t)(l0 + 4 + j) * DI];
      }
    }
#pragma unroll
    for (int jj = 0; jj < 4; ++jj) {
      const float dlt = dB[jj];
      const float t = dlt * uB[jj];
      const float* bb = &Bsh[l0 + jj][nq * 4];
#pragma unroll
      for (int n = 0; n < 4; ++n) {
        const float dA = __expf(dlt * Av[n]);
        P[n] *= dA;
        x[n] = fmaf(dA, x[n], t * bb[n]);
      }
    }
#pragma unroll
    for (int j = 0; j < 4; ++j) { dB[j] = dN[j]; uB[j] = uN[j]; }
  }
  const unsigned sb = ((unsigned)((b * NCHUNK + c) * DI + d)) * 16 + nq * 4;
  *(float4*)&xz[stash_addr(sb)] = make_float4(P[0], P[1], P[2], P[3]);
  *(float4*)&xz[stash_addr((1u << 20) + sb)] = make_float4(x[0], x[1], x[2], x[3]);
}

// ------------- scan phase 2: sequential chunk combine -------------
__global__ __launch_bounds__(256) void scan_phase2(float* __restrict__ xz) {
  const int t = blockIdx.x * 256 + threadIdx.x;
  const int b = t >> 15;
  const int rem = t & 32767;
  float x = 0.f;
#pragma unroll
  for (int c = 0; c < NCHUNK; ++c) {
    const unsigned i = ((unsigned)(b * NCHUNK + c) << 15) + rem;
    float* Pr = &xz[stash_addr(i)];
    float* Sr = &xz[stash_addr((1u << 20) + i)];
    const float P = *Pr, S = *Sr;
    *Sr = x;
    x = fmaf(P, x, S);
  }
}

// ------------- scan phase 3: rescan w/ init + y + skip + gate -> bf16 y -------------
__global__ __launch_bounds__(256) void scan_phase3(
    const float* __restrict__ delta, const float* __restrict__ xc,
    const float* __restrict__ xdbl, const float* __restrict__ A_log,
    const float* __restrict__ Dskip, float* __restrict__ xz) {
  const int bx = blockIdx.x;
  const int b = bx >> 9;
  const int c = (bx >> 5) & 15;
  const int dt = bx & 31;
  const int tid = threadIdx.x;
  const int dl = tid >> 2, nq = tid & 3;
  const int d = dt * 64 + dl;
  const int row0 = b * L_SZ + c * CLEN;

  __shared__ float Bsh[CLEN][16], Csh[CLEN][16];
  for (int i = tid; i < CLEN * 32; i += 256) {
    const int r = i >> 5, q = i & 31;
    const float v = xdbl[(size_t)(row0 + r) * XDLD + 64 + q];
    if (q < 16) Bsh[r][q] = v; else Csh[r][q - 16] = v;
  }

  float Av[4];
#pragma unroll
  for (int j = 0; j < 4; ++j) Av[j] = -__expf(A_log[d * 16 + nq * 4 + j]);
  const float Dsk = Dskip[d];
  const unsigned sb = ((unsigned)((b * NCHUNK + c) * DI + d)) * 16 + nq * 4;
  const float4 xi = *(const float4*)&xz[stash_addr((1u << 20) + sb)];
  float x[4] = {xi.x, xi.y, xi.z, xi.w};
  __syncthreads();

  const float* dp = delta + (size_t)row0 * DI + d;
  const float* up = xc + (size_t)row0 * DI + d;
  const float* zp = xz + (size_t)row0 * 4096 + DI + d;
  ushortT* yb = (ushortT*)xz;

  float dB[4], uB[4], zB[4];
#pragma unroll
  for (int j = 0; j < 4; ++j) {
    dB[j] = dp[(size_t)j * DI];
    uB[j] = up[(size_t)j * DI];
    zB[j] = zp[(size_t)j * 4096];
  }
  for (int l0 = 0; l0 < CLEN; l0 += 4) {
    float dN[4] = {}, uN[4] = {}, zN[4] = {};
    if (l0 + 4 < CLEN) {
#pragma unroll
      for (int j = 0; j < 4; ++j) {
        dN[j] = dp[(size_t)(l0 + 4 + j) * DI];
        uN[j] = up[(size_t)(l0 + 4 + j) * DI];
        zN[j] = zp[(size_t)(l0 + 4 + j) * 4096];
      }
    }
#pragma unroll
    for (int jj = 0; jj < 4; ++jj) {
      const float dlt = dB[jj];
      const float u = uB[jj];
      const float t = dlt * u;
      const float* bb = &Bsh[l0 + jj][nq * 4];
      const float* cc = &Csh[l0 + jj][nq * 4];
      float y = 0.f;
#pragma unroll
      for (int n = 0; n < 4; ++n) {
        const float dA = __expf(dlt * Av[n]);
        x[n] = fmaf(dA, x[n], t * bb[n]);
        y = fmaf(x[n], cc[n], y);
      }
      y += __shfl_xor(y, 1);
      y += __shfl_xor(y, 2);
      if (nq == 0) {
        const float z = zB[jj];
        const float g = (y + u * Dsk) * (z / (1.f + __expf(-z)));
        yb[(size_t)(row0 + l0 + jj) * 8192 + d] = f2bf(g);
      }
    }
#pragma unroll
    for (int j = 0; j < 4; ++j) { dB[j] = dN[j]; uB[j] = uN[j]; zB[j] = zN[j]; }
  }
}

extern "C" void kernel_launch(void* const* d_in, const int* in_sizes, int n_in,
                              void* d_out, int out_size, void* d_ws, size_t ws_size,
                              hipStream_t stream) {
  const float* hidden  = (const float*)d_in[0];
  const float* Win     = (const float*)d_in[1];
  const float* Wx      = (const float*)d_in[2];
  const float* Wdt     = (const float*)d_in[3];
  const float* dt_bias = (const float*)d_in[4];
  const float* Wout    = (const float*)d_in[5];
  const float* dwk     = (const float*)d_in[6];
  const float* dwb     = (const float*)d_in[7];
  const float* A_log   = (const float*)d_in[8];
  const float* Dskip   = (const float*)d_in[9];

  // ws (64 MB): xz 32MB | shared16 (WinT -> xdbl partials -> delta -> WoutT) 16MB | xc 16MB
  // xz per-row float layout: [0,1024) y-bf16 | [1024,2048) scan stash | [2048,4096) z
  char* ws = (char*)d_ws;
  float* xz       = (float*)ws;
  float* shared16 = (float*)(ws + (32u << 20));
  float* xc       = (float*)(ws + (48u << 20));
  // d_out (8 MB) scratch: hidb [0,4M) (dead after GEMM1); xdbl128 [4M,5M); WxT [5M,5.5M)
  char* dob = (char*)d_out;
  ushortT* hidb = (ushortT*)dob;
  float* xdbl   = (float*)(dob + (4u << 20));
  ushortT* WxT  = (ushortT*)(dob + (5u << 20));

  // 1. hidden -> bf16
  cvt_bf16<<<dim3(B_SZ * L_SZ * DM / 1024), 256, 0, stream>>>(hidden, hidb);
  // 2. Win (1024x4096) -> WinT bf16 (4096x1024) in shared16
  transpose_bf16<<<dim3(4096 / 32, 1024 / 32), dim3(32, 8), 0, stream>>>(
      Win, (ushortT*)shared16, DM, 2 * DI);
  // 3. Wx -> WxT bf16 padded (128 x 2048)
  wx_pad_t<<<dim3(DI / 256, 128), 256, 0, stream>>>(Wx, WxT);
  // 4. GEMM1: xz = hidden @ Win  (M=2048, N=4096, K=1024)
  gemm_bf16<128, 128><<<dim3(4096 / 128, 2048 / 128), 256, 0, stream>>>(
      hidb, DM, (ushortT*)shared16, DM, xz, 2 * DI, DM);
  // 5. depthwise conv + silu -> xc f32
  conv_silu<<<dim3(B_SZ * L_SZ, DI / 256), 256, 0, stream>>>(xz, dwk, dwb, xc);
  // 6. x_dbl partials (K-split 8) -> shared16 [0,8M) (WinT dead), then reduce
  gemm_xdbl_mfma<<<dim3(B_SZ * L_SZ / 64, KSPLIT), 256, 0, stream>>>(
      xc, WxT, shared16);
  xdbl_reduce<<<dim3(B_SZ * L_SZ * XDLD / 1024), 256, 0, stream>>>(shared16, xdbl);
  // 7. delta = softplus(dt @ Wdt + bias) -> shared16 (partials dead)
  gemm_delta<<<dim3(DI / 256, B_SZ * L_SZ / 16), 256, 0, stream>>>(
      xdbl, Wdt, dt_bias, shared16);
  // 8-10. chunked selective scan (states in xz stash); y (gated, bf16) -> xz
  scan_phase1<<<dim3(B_SZ * NCHUNK * (DI / 64)), 256, 0, stream>>>(
      shared16, xc, xdbl, A_log, xz);
  scan_phase2<<<dim3(B_SZ * DI * NS / 256), 256, 0, stream>>>(xz);
  scan_phase3<<<dim3(B_SZ * NCHUNK * (DI / 64)), 256, 0, stream>>>(
      shared16, xc, xdbl, A_log, Dskip, xz);
  // 11. Wout (2048x1024) -> WoutT bf16 (1024x2048) in shared16 (delta dead)
  transpose_bf16<<<dim3(1024 / 32, 2048 / 32), dim3(32, 8), 0, stream>>>(
      Wout, (ushortT*)shared16, DI, DM);
  // 12. GEMM4: out = y @ Wout  (M=2048, N=1024, K=2048); A = bf16 y, lda=8192
  gemm_bf16<128, 64><<<dim3(1024 / 64, 2048 / 128), 128, 0, stream>>>(
      (ushortT*)xz, 4 * DI, (ushortT*)shared16, DI, (float*)d_out, DM, DI);
}

// Round 9
// 291.976 us; speedup vs baseline: 1.6206x; 1.0217x over previous
//
#include <hip/hip_runtime.h>
#include <hip/hip_bf16.h>
#include <math.h>

#define B_SZ 2
#define L_SZ 1024
#define DM 1024
#define DI 2048
#define NS 16
#define DTR 64
#define NCHUNK 16
#define CLEN 64
#define XDLD 128  // padded x_dbl leading dim
#define KSPLIT 8

typedef unsigned short ushortT;
typedef __attribute__((ext_vector_type(8))) short short8;
typedef __attribute__((ext_vector_type(4))) float floatx4;

__device__ __forceinline__ ushortT f2bf(float f) {
  unsigned u = __float_as_uint(f);
  unsigned r = (u + 0x7fff + ((u >> 16) & 1)) >> 16;
  return (ushortT)r;
}

__device__ __forceinline__ void gl2lds16(const void* g, void* l) {
  __builtin_amdgcn_global_load_lds(
      (const __attribute__((address_space(1))) unsigned int*)g,
      (__attribute__((address_space(3))) unsigned int*)l, 16, 0, 0);
}

// Scan-state stash lives in the dead strided region of xz: floats [1024,2048)
// of each 4096-float row. i in [0, 2M): aprod at i, sfin at i + 1M.
__device__ __forceinline__ unsigned stash_addr(unsigned i) {
  return (i >> 10) * 4096 + 1024 + (i & 1023);
}

// ---------------- f32 -> bf16 convert (4 elems/thread) ----------------
__global__ __launch_bounds__(256) void cvt_bf16(const float* __restrict__ src,
                                                ushortT* __restrict__ dst) {
  const int i = blockIdx.x * 256 + threadIdx.x;
  float4 v = ((const float4*)src)[i];
  unsigned lo = (unsigned)f2bf(v.x) | ((unsigned)f2bf(v.y) << 16);
  unsigned hi = (unsigned)f2bf(v.z) | ((unsigned)f2bf(v.w) << 16);
  ((uint2*)dst)[i] = make_uint2(lo, hi);
}

// ---------------- f32 [R][C] -> bf16 [C][R] transpose ----------------
__global__ __launch_bounds__(256) void transpose_bf16(
    const float* __restrict__ src, ushortT* __restrict__ dst, int R, int C) {
  __shared__ float t[32][33];
  const int bx = blockIdx.x * 32;  // col base
  const int by = blockIdx.y * 32;  // row base
  const int tx = threadIdx.x, ty = threadIdx.y;  // (32,8)
#pragma unroll
  for (int j = 0; j < 4; ++j)
    t[ty + j * 8][tx] = src[(size_t)(by + ty + j * 8) * C + bx + tx];
  __syncthreads();
#pragma unroll
  for (int j = 0; j < 4; ++j)
    dst[(size_t)(bx + ty + j * 8) * R + by + tx] = f2bf(t[tx][ty + j * 8]);
}

// ---------------- Wx (2048x96) -> WxT bf16 (128x2048), rows 96..127 zero ----------------
__global__ __launch_bounds__(256) void wx_pad_t(const float* __restrict__ Wx,
                                                ushortT* __restrict__ WxT) {
  const int k = blockIdx.x * 256 + threadIdx.x;  // 0..2047
  const int n = blockIdx.y;                      // 0..127
  WxT[(size_t)n * DI + k] = (n < 96) ? f2bf(Wx[(size_t)k * 96 + n]) : (ushortT)0;
}

// ---------------- bf16 MFMA GEMM: C[M][N] f32 = A[M][K] @ BT[N][K]^T ----------------
// m97-style: BK=32, global_load_lds width=16, XOR chunk swizzle, 16x16x32 MFMA.
template <int BM, int BN>
__global__ __launch_bounds__((BM / 64) * (BN / 64) * 64) void gemm_bf16(
    const ushortT* __restrict__ A, int lda,
    const ushortT* __restrict__ BT, int ldb,
    float* __restrict__ C, int ldc, int K) {
  constexpr int NW = (BM / 64) * (BN / 64);
  constexpr int NT = NW * 64;
  __shared__ __align__(16) char smem[(BM + BN) * 64];
  char* As = smem;
  char* Bs = smem + BM * 64;
  const int tid = threadIdx.x;
  const int lane = tid & 63;
  const int quad = lane >> 4;
  const int l16 = lane & 15;
  const int wid = tid >> 6;
  const int wm = wid % (BM / 64);
  const int wn = wid / (BM / 64);
  const int m0 = blockIdx.y * BM;
  const int n0 = blockIdx.x * BN;

  floatx4 acc[4][4] = {};

  for (int k0 = 0; k0 < K; k0 += 32) {
    for (int i = tid; i < BM * 4; i += NT) {
      const int r = i >> 2, c = i & 3;
      const int cg = c ^ (r & 3);
      const char* g = (const char*)(A + (size_t)(m0 + r) * lda + k0) + cg * 16;
      gl2lds16(g, As + (size_t)(i - lane) * 16);
    }
    for (int i = tid; i < BN * 4; i += NT) {
      const int r = i >> 2, c = i & 3;
      const int cg = c ^ (r & 3);
      const char* g = (const char*)(BT + (size_t)(n0 + r) * ldb + k0) + cg * 16;
      gl2lds16(g, Bs + (size_t)(i - lane) * 16);
    }
    __syncthreads();

    short8 afr[4], bfr[4];
#pragma unroll
    for (int i = 0; i < 4; ++i) {
      const int r = wm * 64 + i * 16 + l16;
      afr[i] = *(const short8*)(As + r * 64 + ((quad ^ (r & 3)) * 16));
    }
#pragma unroll
    for (int j = 0; j < 4; ++j) {
      const int r = wn * 64 + j * 16 + l16;
      bfr[j] = *(const short8*)(Bs + r * 64 + ((quad ^ (r & 3)) * 16));
    }
#pragma unroll
    for (int i = 0; i < 4; ++i)
#pragma unroll
      for (int j = 0; j < 4; ++j)
        acc[i][j] = __builtin_amdgcn_mfma_f32_16x16x32_bf16(afr[i], bfr[j],
                                                            acc[i][j], 0, 0, 0);
    __syncthreads();
  }
#pragma unroll
  for (int i = 0; i < 4; ++i)
#pragma unroll
    for (int j = 0; j < 4; ++j)
#pragma unroll
      for (int r = 0; r < 4; ++r) {
        const int m = m0 + wm * 64 + i * 16 + quad * 4 + r;
        const int n = n0 + wn * 64 + j * 16 + l16;
        C[(size_t)m * ldc + n] = acc[i][j][r];
      }
}

// ---------------- GEMM4 kernel: 64x64 tile, 2 waves, 512 blocks (2/CU) ----------------
// Small tiles trade FLOP/B for cross-block barrier overlap (m114 lesson).
__global__ __launch_bounds__(128) void gemm_out64(
    const ushortT* __restrict__ A, int lda,
    const ushortT* __restrict__ BT, int ldb,
    float* __restrict__ C, int ldc, int K) {
  __shared__ __align__(16) char smem[128 * 64];
  char* As = smem;             // 64 rows x 64 B
  char* Bs = smem + 64 * 64;   // 64 rows x 64 B
  const int tid = threadIdx.x;
  const int lane = tid & 63;
  const int quad = lane >> 4;
  const int l16 = lane & 15;
  const int wm = tid >> 6;  // 0/1: 32-row half
  const int m0 = blockIdx.y * 64;
  const int n0 = blockIdx.x * 64;

  floatx4 acc[2][4] = {};

  for (int k0 = 0; k0 < K; k0 += 32) {
    for (int i = tid; i < 256; i += 128) {
      const int r = i >> 2, c = i & 3;
      const int cg = c ^ (r & 3);
      gl2lds16(A + (size_t)(m0 + r) * lda + k0 + cg * 8, As + (i - lane) * 16);
    }
    for (int i = tid; i < 256; i += 128) {
      const int r = i >> 2, c = i & 3;
      const int cg = c ^ (r & 3);
      gl2lds16(BT + (size_t)(n0 + r) * ldb + k0 + cg * 8, Bs + (i - lane) * 16);
    }
    __syncthreads();

    short8 afr[2], bfr[4];
#pragma unroll
    for (int i = 0; i < 2; ++i) {
      const int m = wm * 32 + i * 16 + l16;
      afr[i] = *(const short8*)(As + m * 64 + ((quad ^ (m & 3)) * 16));
    }
#pragma unroll
    for (int j = 0; j < 4; ++j) {
      const int n = j * 16 + l16;
      bfr[j] = *(const short8*)(Bs + n * 64 + ((quad ^ (n & 3)) * 16));
    }
#pragma unroll
    for (int i = 0; i < 2; ++i)
#pragma unroll
      for (int j = 0; j < 4; ++j)
        acc[i][j] = __builtin_amdgcn_mfma_f32_16x16x32_bf16(afr[i], bfr[j],
                                                            acc[i][j], 0, 0, 0);
    __syncthreads();
  }
#pragma unroll
  for (int i = 0; i < 2; ++i)
#pragma unroll
    for (int j = 0; j < 4; ++j)
#pragma unroll
      for (int r = 0; r < 4; ++r) {
        const int m = m0 + wm * 32 + i * 16 + quad * 4 + r;
        const int n = n0 + j * 16 + l16;
        C[(size_t)m * ldc + n] = acc[i][j][r];
      }
}

// ------------- x_dbl partials: xc @ Wx (padded N=128), K-split via MFMA -------------
__global__ __launch_bounds__(256) void gemm_xdbl_mfma(
    const float* __restrict__ xc, const ushortT* __restrict__ WxT,
    float* __restrict__ part) {
  __shared__ __align__(16) char smem[64 * 128 + 128 * 64];
  char* As = smem;             // [64 r][128 B f32]
  char* Bs = smem + 64 * 128;  // [128 r][64 B bf16]
  const int tid = threadIdx.x;
  const int lane = tid & 63;
  const int quad = lane >> 4;
  const int l16 = lane & 15;
  const int wid = tid >> 6;
  const int wm = wid & 1;
  const int wn = wid >> 1;
  const int m0 = blockIdx.x * 64;
  const int kbase = blockIdx.y * (DI / KSPLIT);

  floatx4 acc[2][4] = {};

  for (int kk = 0; kk < DI / KSPLIT; kk += 32) {
    const int k0 = kbase + kk;
    for (int i = tid; i < 64 * 8; i += 256) {
      const int r = i >> 3, c = i & 7;
      const int cg = c ^ (r & 7);
      gl2lds16(xc + (size_t)(m0 + r) * DI + k0 + cg * 4, As + (i - lane) * 16);
    }
    for (int i = tid; i < 128 * 4; i += 256) {
      const int r = i >> 2, c = i & 3;
      const int cg = c ^ (r & 3);
      gl2lds16(WxT + (size_t)r * DI + k0 + cg * 8, Bs + (i - lane) * 16);
    }
    __syncthreads();

    short8 afr[2], bfr[4];
#pragma unroll
    for (int i = 0; i < 2; ++i) {
      const int m = wm * 32 + i * 16 + l16;
      const float4 x0 = *(const float4*)(As + m * 128 + (((quad * 2 + 0) ^ (m & 7)) * 16));
      const float4 x1 = *(const float4*)(As + m * 128 + (((quad * 2 + 1) ^ (m & 7)) * 16));
      short8 f;
      f[0] = (short)f2bf(x0.x); f[1] = (short)f2bf(x0.y);
      f[2] = (short)f2bf(x0.z); f[3] = (short)f2bf(x0.w);
      f[4] = (short)f2bf(x1.x); f[5] = (short)f2bf(x1.y);
      f[6] = (short)f2bf(x1.z); f[7] = (short)f2bf(x1.w);
      afr[i] = f;
    }
#pragma unroll
    for (int j = 0; j < 4; ++j) {
      const int n = wn * 64 + j * 16 + l16;
      bfr[j] = *(const short8*)(Bs + n * 64 + ((quad ^ (n & 3)) * 16));
    }
#pragma unroll
    for (int i = 0; i < 2; ++i)
#pragma unroll
      for (int j = 0; j < 4; ++j)
        acc[i][j] = __builtin_amdgcn_mfma_f32_16x16x32_bf16(afr[i], bfr[j],
                                                            acc[i][j], 0, 0, 0);
    __syncthreads();
  }
  float* out = part + (size_t)blockIdx.y * (B_SZ * L_SZ * XDLD);
#pragma unroll
  for (int i = 0; i < 2; ++i)
#pragma unroll
    for (int j = 0; j < 4; ++j)
#pragma unroll
      for (int r = 0; r < 4; ++r) {
        const int m = m0 + wm * 32 + i * 16 + quad * 4 + r;
        const int n = wn * 64 + j * 16 + l16;
        out[(size_t)m * XDLD + n] = acc[i][j][r];
      }
}

// ------------- xdbl = sum of KSPLIT partials (float4 per thread) -------------
__global__ __launch_bounds__(256) void xdbl_reduce(const float* __restrict__ part,
                                                   float* __restrict__ xdbl) {
  const int i = blockIdx.x * 256 + threadIdx.x;  // float4 index, [0, 65536)
  float4 a = ((const float4*)part)[i];
#pragma unroll
  for (int s = 1; s < KSPLIT; ++s) {
    const float4 b = ((const float4*)part)[(size_t)s * (B_SZ * L_SZ * XDLD / 4) + i];
    a.x += b.x; a.y += b.y; a.z += b.z; a.w += b.w;
  }
  ((float4*)xdbl)[i] = a;
}

// ------------- causal depthwise conv (k=4) + silu -> xc f32 -------------
__global__ __launch_bounds__(256) void conv_silu(
    const float* __restrict__ xz, const float* __restrict__ kern,
    const float* __restrict__ bias, float* __restrict__ xc) {
  const int d = blockIdx.y * 256 + threadIdx.x;
  const int row = blockIdx.x;
  const int l = row & (L_SZ - 1);
  float acc = bias[d];
#pragma unroll
  for (int i = 0; i < 4; ++i) {
    const int li = l - 3 + i;
    if (li >= 0) acc = fmaf(xz[(size_t)(row - 3 + i) * 4096 + d], kern[i * DI + d], acc);
  }
  xc[(size_t)row * DI + d] = acc / (1.f + __expf(-acc));
}

// ------------- delta = softplus(dt @ Wdt + dt_bias) -------------
__global__ __launch_bounds__(256) void gemm_delta(
    const float* __restrict__ xdbl, const float* __restrict__ Wdt,
    const float* __restrict__ dt_bias, float* __restrict__ delta) {
  __shared__ float dtL[16][64];
  const int col = blockIdx.x * 256 + threadIdx.x;
  const int row0 = blockIdx.y * 16;
  for (int i = threadIdx.x; i < 16 * 64; i += 256) {
    const int r = i >> 6, k = i & 63;
    dtL[r][k] = xdbl[(size_t)(row0 + r) * XDLD + k];
  }
  __syncthreads();
  const float bias = dt_bias[col];
  float acc[16];
#pragma unroll
  for (int r = 0; r < 16; ++r) acc[r] = bias;
  for (int k8 = 0; k8 < 64; k8 += 8) {
    float w[8];
#pragma unroll
    for (int j = 0; j < 8; ++j) w[j] = Wdt[(size_t)(k8 + j) * DI + col];
#pragma unroll
    for (int r = 0; r < 16; ++r) {
      float a = acc[r];
#pragma unroll
      for (int j = 0; j < 8; ++j) a = fmaf(dtL[r][k8 + j], w[j], a);
      acc[r] = a;
    }
  }
#pragma unroll
  for (int r = 0; r < 16; ++r) {
    const float a = acc[r];
    delta[(size_t)(row0 + r) * DI + col] = (a > 20.f) ? a : log1pf(__expf(a));
  }
}

// ------------- scan phase 1: per-chunk transition -------------
__global__ __launch_bounds__(256) void scan_phase1(
    const float* __restrict__ delta, const float* __restrict__ xc,
    const float* __restrict__ xdbl, const float* __restrict__ A_log,
    float* __restrict__ xz) {
  const int bx = blockIdx.x;
  const int b = bx >> 9;
  const int c = (bx >> 5) & 15;
  const int dt = bx & 31;
  const int tid = threadIdx.x;
  const int dl = tid >> 2, nq = tid & 3;
  const int d = dt * 64 + dl;
  const int row0 = b * L_SZ + c * CLEN;

  __shared__ float Bsh[CLEN][16];
  for (int i = tid; i < CLEN * 16; i += 256)
    Bsh[i >> 4][i & 15] = xdbl[(size_t)(row0 + (i >> 4)) * XDLD + 64 + (i & 15)];

  float Av[4];
#pragma unroll
  for (int j = 0; j < 4; ++j) Av[j] = -__expf(A_log[d * 16 + nq * 4 + j]);
  float x[4] = {}, P[4] = {1.f, 1.f, 1.f, 1.f};
  __syncthreads();

  const float* dp = delta + (size_t)row0 * DI + d;
  const float* up = xc + (size_t)row0 * DI + d;
  float dB[4], uB[4];
#pragma unroll
  for (int j = 0; j < 4; ++j) { dB[j] = dp[(size_t)j * DI]; uB[j] = up[(size_t)j * DI]; }
  for (int l0 = 0; l0 < CLEN; l0 += 4) {
    float dN[4] = {}, uN[4] = {};
    if (l0 + 4 < CLEN) {
#pragma unroll
      for (int j = 0; j < 4; ++j) {
        dN[j] = dp[(size_t)(l0 + 4 + j) * DI];
        uN[j] = up[(size_t)(l0 + 4 + j) * DI];
      }
    }
#pragma unroll
    for (int jj = 0; jj < 4; ++jj) {
      const float dlt = dB[jj];
      const float t = dlt * uB[jj];
      const float* bb = &Bsh[l0 + jj][nq * 4];
#pragma unroll
      for (int n = 0; n < 4; ++n) {
        const float dA = __expf(dlt * Av[n]);
        P[n] *= dA;
        x[n] = fmaf(dA, x[n], t * bb[n]);
      }
    }
#pragma unroll
    for (int j = 0; j < 4; ++j) { dB[j] = dN[j]; uB[j] = uN[j]; }
  }
  const unsigned sb = ((unsigned)((b * NCHUNK + c) * DI + d)) * 16 + nq * 4;
  *(float4*)&xz[stash_addr(sb)] = make_float4(P[0], P[1], P[2], P[3]);
  *(float4*)&xz[stash_addr((1u << 20) + sb)] = make_float4(x[0], x[1], x[2], x[3]);
}

// ------------- scan phase 2: sequential chunk combine -------------
__global__ __launch_bounds__(256) void scan_phase2(float* __restrict__ xz) {
  const int t = blockIdx.x * 256 + threadIdx.x;
  const int b = t >> 15;
  const int rem = t & 32767;
  float x = 0.f;
#pragma unroll
  for (int c = 0; c < NCHUNK; ++c) {
    const unsigned i = ((unsigned)(b * NCHUNK + c) << 15) + rem;
    float* Pr = &xz[stash_addr(i)];
    float* Sr = &xz[stash_addr((1u << 20) + i)];
    const float P = *Pr, S = *Sr;
    *Sr = x;
    x = fmaf(P, x, S);
  }
}

// ------------- scan phase 3: rescan w/ init + y + skip + gate -> bf16 y -------------
__global__ __launch_bounds__(256) void scan_phase3(
    const float* __restrict__ delta, const float* __restrict__ xc,
    const float* __restrict__ xdbl, const float* __restrict__ A_log,
    const float* __restrict__ Dskip, float* __restrict__ xz) {
  const int bx = blockIdx.x;
  const int b = bx >> 9;
  const int c = (bx >> 5) & 15;
  const int dt = bx & 31;
  const int tid = threadIdx.x;
  const int dl = tid >> 2, nq = tid & 3;
  const int d = dt * 64 + dl;
  const int row0 = b * L_SZ + c * CLEN;

  __shared__ float Bsh[CLEN][16], Csh[CLEN][16];
  for (int i = tid; i < CLEN * 32; i += 256) {
    const int r = i >> 5, q = i & 31;
    const float v = xdbl[(size_t)(row0 + r) * XDLD + 64 + q];
    if (q < 16) Bsh[r][q] = v; else Csh[r][q - 16] = v;
  }

  float Av[4];
#pragma unroll
  for (int j = 0; j < 4; ++j) Av[j] = -__expf(A_log[d * 16 + nq * 4 + j]);
  const float Dsk = Dskip[d];
  const unsigned sb = ((unsigned)((b * NCHUNK + c) * DI + d)) * 16 + nq * 4;
  const float4 xi = *(const float4*)&xz[stash_addr((1u << 20) + sb)];
  float x[4] = {xi.x, xi.y, xi.z, xi.w};
  __syncthreads();

  const float* dp = delta + (size_t)row0 * DI + d;
  const float* up = xc + (size_t)row0 * DI + d;
  const float* zp = xz + (size_t)row0 * 4096 + DI + d;
  ushortT* yb = (ushortT*)xz;

  float dB[4], uB[4], zB[4];
#pragma unroll
  for (int j = 0; j < 4; ++j) {
    dB[j] = dp[(size_t)j * DI];
    uB[j] = up[(size_t)j * DI];
    zB[j] = zp[(size_t)j * 4096];
  }
  for (int l0 = 0; l0 < CLEN; l0 += 4) {
    float dN[4] = {}, uN[4] = {}, zN[4] = {};
    if (l0 + 4 < CLEN) {
#pragma unroll
      for (int j = 0; j < 4; ++j) {
        dN[j] = dp[(size_t)(l0 + 4 + j) * DI];
        uN[j] = up[(size_t)(l0 + 4 + j) * DI];
        zN[j] = zp[(size_t)(l0 + 4 + j) * 4096];
      }
    }
#pragma unroll
    for (int jj = 0; jj < 4; ++jj) {
      const float dlt = dB[jj];
      const float u = uB[jj];
      const float t = dlt * u;
      const float* bb = &Bsh[l0 + jj][nq * 4];
      const float* cc = &Csh[l0 + jj][nq * 4];
      float y = 0.f;
#pragma unroll
      for (int n = 0; n < 4; ++n) {
        const float dA = __expf(dlt * Av[n]);
        x[n] = fmaf(dA, x[n], t * bb[n]);
        y = fmaf(x[n], cc[n], y);
      }
      y += __shfl_xor(y, 1);
      y += __shfl_xor(y, 2);
      if (nq == 0) {
        const float z = zB[jj];
        const float g = (y + u * Dsk) * (z / (1.f + __expf(-z)));
        yb[(size_t)(row0 + l0 + jj) * 8192 + d] = f2bf(g);
      }
    }
#pragma unroll
    for (int j = 0; j < 4; ++j) { dB[j] = dN[j]; uB[j] = uN[j]; zB[j] = zN[j]; }
  }
}

extern "C" void kernel_launch(void* const* d_in, const int* in_sizes, int n_in,
                              void* d_out, int out_size, void* d_ws, size_t ws_size,
                              hipStream_t stream) {
  const float* hidden  = (const float*)d_in[0];
  const float* Win     = (const float*)d_in[1];
  const float* Wx      = (const float*)d_in[2];
  const float* Wdt     = (const float*)d_in[3];
  const float* dt_bias = (const float*)d_in[4];
  const float* Wout    = (const float*)d_in[5];
  const float* dwk     = (const float*)d_in[6];
  const float* dwb     = (const float*)d_in[7];
  const float* A_log   = (const float*)d_in[8];
  const float* Dskip   = (const float*)d_in[9];

  // ws (64 MB): xz 32MB | shared16 (WinT -> xdbl partials -> delta -> WoutT) 16MB | xc 16MB
  // xz per-row float layout: [0,1024) y-bf16 | [1024,2048) scan stash | [2048,4096) z
  char* ws = (char*)d_ws;
  float* xz       = (float*)ws;
  float* shared16 = (float*)(ws + (32u << 20));
  float* xc       = (float*)(ws + (48u << 20));
  // d_out (8 MB) scratch: hidb [0,4M) (dead after GEMM1); xdbl128 [4M,5M); WxT [5M,5.5M)
  char* dob = (char*)d_out;
  ushortT* hidb = (ushortT*)dob;
  float* xdbl   = (float*)(dob + (4u << 20));
  ushortT* WxT  = (ushortT*)(dob + (5u << 20));

  // 1. hidden -> bf16
  cvt_bf16<<<dim3(B_SZ * L_SZ * DM / 1024), 256, 0, stream>>>(hidden, hidb);
  // 2. Win (1024x4096) -> WinT bf16 (4096x1024) in shared16
  transpose_bf16<<<dim3(4096 / 32, 1024 / 32), dim3(32, 8), 0, stream>>>(
      Win, (ushortT*)shared16, DM, 2 * DI);
  // 3. Wx -> WxT bf16 padded (128 x 2048)
  wx_pad_t<<<dim3(DI / 256, 128), 256, 0, stream>>>(Wx, WxT);
  // 4. GEMM1: xz = hidden @ Win  (M=2048, N=4096, K=1024)
  gemm_bf16<128, 128><<<dim3(4096 / 128, 2048 / 128), 256, 0, stream>>>(
      hidb, DM, (ushortT*)shared16, DM, xz, 2 * DI, DM);
  // 5. depthwise conv + silu -> xc f32
  conv_silu<<<dim3(B_SZ * L_SZ, DI / 256), 256, 0, stream>>>(xz, dwk, dwb, xc);
  // 6. x_dbl partials (K-split 8) -> shared16 [0,8M) (WinT dead), then reduce
  gemm_xdbl_mfma<<<dim3(B_SZ * L_SZ / 64, KSPLIT), 256, 0, stream>>>(
      xc, WxT, shared16);
  xdbl_reduce<<<dim3(B_SZ * L_SZ * XDLD / 1024), 256, 0, stream>>>(shared16, xdbl);
  // 7. delta = softplus(dt @ Wdt + bias) -> shared16 (partials dead)
  gemm_delta<<<dim3(DI / 256, B_SZ * L_SZ / 16), 256, 0, stream>>>(
      xdbl, Wdt, dt_bias, shared16);
  // 8-10. chunked selective scan (states in xz stash); y (gated, bf16) -> xz
  scan_phase1<<<dim3(B_SZ * NCHUNK * (DI / 64)), 256, 0, stream>>>(
      shared16, xc, xdbl, A_log, xz);
  scan_phase2<<<dim3(B_SZ * DI * NS / 256), 256, 0, stream>>>(xz);
  scan_phase3<<<dim3(B_SZ * NCHUNK * (DI / 64)), 256, 0, stream>>>(
      shared16, xc, xdbl, A_log, Dskip, xz);
  // 11. Wout (2048x1024) -> WoutT bf16 (1024x2048) in shared16 (delta dead)
  transpose_bf16<<<dim3(1024 / 32, 2048 / 32), dim3(32, 8), 0, stream>>>(
      Wout, (ushortT*)shared16, DI, DM);
  // 12. GEMM4: out = y @ Wout  (M=2048, N=1024, K=2048); 64x64 tiles, 512 blocks
  gemm_out64<<<dim3(1024 / 64, 2048 / 64), 128, 0, stream>>>(
      (ushortT*)xz, 4 * DI, (ushortT*)shared16, DI, (float*)d_out, DM, DI);
}

// Round 10
// 280.900 us; speedup vs baseline: 1.6845x; 1.0394x over previous
//
#include <hip/hip_runtime.h>
#include <hip/hip_bf16.h>
#include <math.h>

#define B_SZ 2
#define L_SZ 1024
#define DM 1024
#define DI 2048
#define NS 16
#define DTR 64
#define NCHUNK 16
#define CLEN 64
#define XDLD 128  // padded x_dbl leading dim
#define KSPLIT 8

typedef unsigned short ushortT;
typedef __attribute__((ext_vector_type(8))) short short8;
typedef __attribute__((ext_vector_type(4))) float floatx4;

__device__ __forceinline__ ushortT f2bf(float f) {
  unsigned u = __float_as_uint(f);
  unsigned r = (u + 0x7fff + ((u >> 16) & 1)) >> 16;
  return (ushortT)r;
}

__device__ __forceinline__ void gl2lds16(const void* g, void* l) {
  __builtin_amdgcn_global_load_lds(
      (const __attribute__((address_space(1))) unsigned int*)g,
      (__attribute__((address_space(3))) unsigned int*)l, 16, 0, 0);
}

// Scan-state stash lives in the dead strided region of xz: floats [1024,2048)
// of each 4096-float row. i in [0, 2M): aprod at i, sfin at i + 1M.
__device__ __forceinline__ unsigned stash_addr(unsigned i) {
  return (i >> 10) * 4096 + 1024 + (i & 1023);
}

// ---------------- f32 -> bf16 convert (4 elems/thread) ----------------
__global__ __launch_bounds__(256) void cvt_bf16(const float* __restrict__ src,
                                                ushortT* __restrict__ dst) {
  const int i = blockIdx.x * 256 + threadIdx.x;
  float4 v = ((const float4*)src)[i];
  unsigned lo = (unsigned)f2bf(v.x) | ((unsigned)f2bf(v.y) << 16);
  unsigned hi = (unsigned)f2bf(v.z) | ((unsigned)f2bf(v.w) << 16);
  ((uint2*)dst)[i] = make_uint2(lo, hi);
}

// ---------------- f32 [R][C] -> bf16 [C][R] transpose ----------------
__global__ __launch_bounds__(256) void transpose_bf16(
    const float* __restrict__ src, ushortT* __restrict__ dst, int R, int C) {
  __shared__ float t[32][33];
  const int bx = blockIdx.x * 32;  // col base
  const int by = blockIdx.y * 32;  // row base
  const int tx = threadIdx.x, ty = threadIdx.y;  // (32,8)
#pragma unroll
  for (int j = 0; j < 4; ++j)
    t[ty + j * 8][tx] = src[(size_t)(by + ty + j * 8) * C + bx + tx];
  __syncthreads();
#pragma unroll
  for (int j = 0; j < 4; ++j)
    dst[(size_t)(bx + ty + j * 8) * R + by + tx] = f2bf(t[tx][ty + j * 8]);
}

// ---------------- Wx (2048x96) -> WxT bf16 (128x2048), rows 96..127 zero ----------------
__global__ __launch_bounds__(256) void wx_pad_t(const float* __restrict__ Wx,
                                                ushortT* __restrict__ WxT) {
  const int k = blockIdx.x * 256 + threadIdx.x;  // 0..2047
  const int n = blockIdx.y;                      // 0..127
  WxT[(size_t)n * DI + k] = (n < 96) ? f2bf(Wx[(size_t)k * 96 + n]) : (ushortT)0;
}

// ---------------- bf16 MFMA GEMM: C[M][N] f32 = A[M][K] @ BT[N][K]^T ----------------
// m97-style: BK=32, global_load_lds width=16, XOR chunk swizzle, 16x16x32 MFMA.
template <int BM, int BN>
__global__ __launch_bounds__((BM / 64) * (BN / 64) * 64) void gemm_bf16(
    const ushortT* __restrict__ A, int lda,
    const ushortT* __restrict__ BT, int ldb,
    float* __restrict__ C, int ldc, int K) {
  constexpr int NW = (BM / 64) * (BN / 64);
  constexpr int NT = NW * 64;
  __shared__ __align__(16) char smem[(BM + BN) * 64];
  char* As = smem;
  char* Bs = smem + BM * 64;
  const int tid = threadIdx.x;
  const int lane = tid & 63;
  const int quad = lane >> 4;
  const int l16 = lane & 15;
  const int wid = tid >> 6;
  const int wm = wid % (BM / 64);
  const int wn = wid / (BM / 64);
  const int m0 = blockIdx.y * BM;
  const int n0 = blockIdx.x * BN;

  floatx4 acc[4][4] = {};

  for (int k0 = 0; k0 < K; k0 += 32) {
    for (int i = tid; i < BM * 4; i += NT) {
      const int r = i >> 2, c = i & 3;
      const int cg = c ^ (r & 3);
      const char* g = (const char*)(A + (size_t)(m0 + r) * lda + k0) + cg * 16;
      gl2lds16(g, As + (size_t)(i - lane) * 16);
    }
    for (int i = tid; i < BN * 4; i += NT) {
      const int r = i >> 2, c = i & 3;
      const int cg = c ^ (r & 3);
      const char* g = (const char*)(BT + (size_t)(n0 + r) * ldb + k0) + cg * 16;
      gl2lds16(g, Bs + (size_t)(i - lane) * 16);
    }
    __syncthreads();

    short8 afr[4], bfr[4];
#pragma unroll
    for (int i = 0; i < 4; ++i) {
      const int r = wm * 64 + i * 16 + l16;
      afr[i] = *(const short8*)(As + r * 64 + ((quad ^ (r & 3)) * 16));
    }
#pragma unroll
    for (int j = 0; j < 4; ++j) {
      const int r = wn * 64 + j * 16 + l16;
      bfr[j] = *(const short8*)(Bs + r * 64 + ((quad ^ (r & 3)) * 16));
    }
#pragma unroll
    for (int i = 0; i < 4; ++i)
#pragma unroll
      for (int j = 0; j < 4; ++j)
        acc[i][j] = __builtin_amdgcn_mfma_f32_16x16x32_bf16(afr[i], bfr[j],
                                                            acc[i][j], 0, 0, 0);
    __syncthreads();
  }
#pragma unroll
  for (int i = 0; i < 4; ++i)
#pragma unroll
    for (int j = 0; j < 4; ++j)
#pragma unroll
      for (int r = 0; r < 4; ++r) {
        const int m = m0 + wm * 64 + i * 16 + quad * 4 + r;
        const int n = n0 + wn * 64 + j * 16 + l16;
        C[(size_t)m * ldc + n] = acc[i][j][r];
      }
}

// ---------------- GEMM4 kernel: 64x64 tile, 2 waves, 512 blocks (2/CU) ----------------
__global__ __launch_bounds__(128) void gemm_out64(
    const ushortT* __restrict__ A, int lda,
    const ushortT* __restrict__ BT, int ldb,
    float* __restrict__ C, int ldc, int K) {
  __shared__ __align__(16) char smem[128 * 64];
  char* As = smem;             // 64 rows x 64 B
  char* Bs = smem + 64 * 64;   // 64 rows x 64 B
  const int tid = threadIdx.x;
  const int lane = tid & 63;
  const int quad = lane >> 4;
  const int l16 = lane & 15;
  const int wm = tid >> 6;  // 0/1: 32-row half
  const int m0 = blockIdx.y * 64;
  const int n0 = blockIdx.x * 64;

  floatx4 acc[2][4] = {};

  for (int k0 = 0; k0 < K; k0 += 32) {
    for (int i = tid; i < 256; i += 128) {
      const int r = i >> 2, c = i & 3;
      const int cg = c ^ (r & 3);
      gl2lds16(A + (size_t)(m0 + r) * lda + k0 + cg * 8, As + (i - lane) * 16);
    }
    for (int i = tid; i < 256; i += 128) {
      const int r = i >> 2, c = i & 3;
      const int cg = c ^ (r & 3);
      gl2lds16(BT + (size_t)(n0 + r) * ldb + k0 + cg * 8, Bs + (i - lane) * 16);
    }
    __syncthreads();

    short8 afr[2], bfr[4];
#pragma unroll
    for (int i = 0; i < 2; ++i) {
      const int m = wm * 32 + i * 16 + l16;
      afr[i] = *(const short8*)(As + m * 64 + ((quad ^ (m & 3)) * 16));
    }
#pragma unroll
    for (int j = 0; j < 4; ++j) {
      const int n = j * 16 + l16;
      bfr[j] = *(const short8*)(Bs + n * 64 + ((quad ^ (n & 3)) * 16));
    }
#pragma unroll
    for (int i = 0; i < 2; ++i)
#pragma unroll
      for (int j = 0; j < 4; ++j)
        acc[i][j] = __builtin_amdgcn_mfma_f32_16x16x32_bf16(afr[i], bfr[j],
                                                            acc[i][j], 0, 0, 0);
    __syncthreads();
  }
#pragma unroll
  for (int i = 0; i < 2; ++i)
#pragma unroll
    for (int j = 0; j < 4; ++j)
#pragma unroll
      for (int r = 0; r < 4; ++r) {
        const int m = m0 + wm * 32 + i * 16 + quad * 4 + r;
        const int n = n0 + j * 16 + l16;
        C[(size_t)m * ldc + n] = acc[i][j][r];
      }
}

// ------------- x_dbl partials: xc @ Wx (padded N=128), K-split via MFMA -------------
__global__ __launch_bounds__(256) void gemm_xdbl_mfma(
    const float* __restrict__ xc, const ushortT* __restrict__ WxT,
    float* __restrict__ part) {
  __shared__ __align__(16) char smem[64 * 128 + 128 * 64];
  char* As = smem;             // [64 r][128 B f32]
  char* Bs = smem + 64 * 128;  // [128 r][64 B bf16]
  const int tid = threadIdx.x;
  const int lane = tid & 63;
  const int quad = lane >> 4;
  const int l16 = lane & 15;
  const int wid = tid >> 6;
  const int wm = wid & 1;
  const int wn = wid >> 1;
  const int m0 = blockIdx.x * 64;
  const int kbase = blockIdx.y * (DI / KSPLIT);

  floatx4 acc[2][4] = {};

  for (int kk = 0; kk < DI / KSPLIT; kk += 32) {
    const int k0 = kbase + kk;
    for (int i = tid; i < 64 * 8; i += 256) {
      const int r = i >> 3, c = i & 7;
      const int cg = c ^ (r & 7);
      gl2lds16(xc + (size_t)(m0 + r) * DI + k0 + cg * 4, As + (i - lane) * 16);
    }
    for (int i = tid; i < 128 * 4; i += 256) {
      const int r = i >> 2, c = i & 3;
      const int cg = c ^ (r & 3);
      gl2lds16(WxT + (size_t)r * DI + k0 + cg * 8, Bs + (i - lane) * 16);
    }
    __syncthreads();

    short8 afr[2], bfr[4];
#pragma unroll
    for (int i = 0; i < 2; ++i) {
      const int m = wm * 32 + i * 16 + l16;
      const float4 x0 = *(const float4*)(As + m * 128 + (((quad * 2 + 0) ^ (m & 7)) * 16));
      const float4 x1 = *(const float4*)(As + m * 128 + (((quad * 2 + 1) ^ (m & 7)) * 16));
      short8 f;
      f[0] = (short)f2bf(x0.x); f[1] = (short)f2bf(x0.y);
      f[2] = (short)f2bf(x0.z); f[3] = (short)f2bf(x0.w);
      f[4] = (short)f2bf(x1.x); f[5] = (short)f2bf(x1.y);
      f[6] = (short)f2bf(x1.z); f[7] = (short)f2bf(x1.w);
      afr[i] = f;
    }
#pragma unroll
    for (int j = 0; j < 4; ++j) {
      const int n = wn * 64 + j * 16 + l16;
      bfr[j] = *(const short8*)(Bs + n * 64 + ((quad ^ (n & 3)) * 16));
    }
#pragma unroll
    for (int i = 0; i < 2; ++i)
#pragma unroll
      for (int j = 0; j < 4; ++j)
        acc[i][j] = __builtin_amdgcn_mfma_f32_16x16x32_bf16(afr[i], bfr[j],
                                                            acc[i][j], 0, 0, 0);
    __syncthreads();
  }
  float* out = part + (size_t)blockIdx.y * (B_SZ * L_SZ * XDLD);
#pragma unroll
  for (int i = 0; i < 2; ++i)
#pragma unroll
    for (int j = 0; j < 4; ++j)
#pragma unroll
      for (int r = 0; r < 4; ++r) {
        const int m = m0 + wm * 32 + i * 16 + quad * 4 + r;
        const int n = wn * 64 + j * 16 + l16;
        out[(size_t)m * XDLD + n] = acc[i][j][r];
      }
}

// ------------- xdbl = sum of KSPLIT partials (float4 per thread) -------------
__global__ __launch_bounds__(256) void xdbl_reduce(const float* __restrict__ part,
                                                   float* __restrict__ xdbl) {
  const int i = blockIdx.x * 256 + threadIdx.x;  // float4 index, [0, 65536)
  float4 a = ((const float4*)part)[i];
#pragma unroll
  for (int s = 1; s < KSPLIT; ++s) {
    const float4 b = ((const float4*)part)[(size_t)s * (B_SZ * L_SZ * XDLD / 4) + i];
    a.x += b.x; a.y += b.y; a.z += b.z; a.w += b.w;
  }
  ((float4*)xdbl)[i] = a;
}

// ------------- causal depthwise conv (k=4) + silu -> xc f32 -------------
// Row-tiled 8x: 11 batched halo loads per thread feed 8 outputs (2.9x fewer
// reads than per-row version; 11-deep MLP).
__global__ __launch_bounds__(256) void conv_silu(
    const float* __restrict__ xz, const float* __restrict__ kern,
    const float* __restrict__ bias, float* __restrict__ xc) {
  const int d = blockIdx.y * 256 + threadIdx.x;
  const int b = blockIdx.x >> 7;           // 128 8-row chunks per batch
  const int l0 = (blockIdx.x & 127) * 8;
  const int row0 = b * L_SZ + l0;
  const float k0v = kern[0 * DI + d], k1v = kern[1 * DI + d];
  const float k2v = kern[2 * DI + d], k3v = kern[3 * DI + d];
  float xv[11];
#pragma unroll
  for (int i = 0; i < 11; ++i) {
    const int l = l0 - 3 + i;
    xv[i] = (l >= 0) ? xz[((size_t)(b * L_SZ + l)) * 4096 + d] : 0.f;
  }
  const float bs = bias[d];
#pragma unroll
  for (int j = 0; j < 8; ++j) {
    float a = bs;
    a = fmaf(xv[j], k0v, a);
    a = fmaf(xv[j + 1], k1v, a);
    a = fmaf(xv[j + 2], k2v, a);
    a = fmaf(xv[j + 3], k3v, a);
    xc[(size_t)(row0 + j) * DI + d] = a / (1.f + __expf(-a));
  }
}

// ------------- delta = softplus(dt @ Wdt + dt_bias) -------------
__global__ __launch_bounds__(256) void gemm_delta(
    const float* __restrict__ xdbl, const float* __restrict__ Wdt,
    const float* __restrict__ dt_bias, float* __restrict__ delta) {
  __shared__ float dtL[16][64];
  const int col = blockIdx.x * 256 + threadIdx.x;
  const int row0 = blockIdx.y * 16;
  for (int i = threadIdx.x; i < 16 * 64; i += 256) {
    const int r = i >> 6, k = i & 63;
    dtL[r][k] = xdbl[(size_t)(row0 + r) * XDLD + k];
  }
  __syncthreads();
  const float bias = dt_bias[col];
  float acc[16];
#pragma unroll
  for (int r = 0; r < 16; ++r) acc[r] = bias;
  for (int k8 = 0; k8 < 64; k8 += 8) {
    float w[8];
#pragma unroll
    for (int j = 0; j < 8; ++j) w[j] = Wdt[(size_t)(k8 + j) * DI + col];
#pragma unroll
    for (int r = 0; r < 16; ++r) {
      float a = acc[r];
#pragma unroll
      for (int j = 0; j < 8; ++j) a = fmaf(dtL[r][k8 + j], w[j], a);
      acc[r] = a;
    }
  }
#pragma unroll
  for (int r = 0; r < 16; ++r) {
    const float a = acc[r];
    delta[(size_t)(row0 + r) * DI + col] = (a > 20.f) ? a : log1pf(__expf(a));
  }
}

// ------------- scan phase 1: per-chunk transition -------------
__global__ __launch_bounds__(256) void scan_phase1(
    const float* __restrict__ delta, const float* __restrict__ xc,
    const float* __restrict__ xdbl, const float* __restrict__ A_log,
    float* __restrict__ xz) {
  const int bx = blockIdx.x;
  const int b = bx >> 9;
  const int c = (bx >> 5) & 15;
  const int dt = bx & 31;
  const int tid = threadIdx.x;
  const int dl = tid >> 2, nq = tid & 3;
  const int d = dt * 64 + dl;
  const int row0 = b * L_SZ + c * CLEN;

  __shared__ float Bsh[CLEN][16];
  for (int i = tid; i < CLEN * 16; i += 256)
    Bsh[i >> 4][i & 15] = xdbl[(size_t)(row0 + (i >> 4)) * XDLD + 64 + (i & 15)];

  float Av[4];
#pragma unroll
  for (int j = 0; j < 4; ++j) Av[j] = -__expf(A_log[d * 16 + nq * 4 + j]);
  float x[4] = {}, P[4] = {1.f, 1.f, 1.f, 1.f};
  __syncthreads();

  const float* dp = delta + (size_t)row0 * DI + d;
  const float* up = xc + (size_t)row0 * DI + d;
  float dB[4], uB[4];
#pragma unroll
  for (int j = 0; j < 4; ++j) { dB[j] = dp[(size_t)j * DI]; uB[j] = up[(size_t)j * DI]; }
  for (int l0 = 0; l0 < CLEN; l0 += 4) {
    float dN[4] = {}, uN[4] = {};
    if (l0 + 4 < CLEN) {
#pragma unroll
      for (int j = 0; j < 4; ++j) {
        dN[j] = dp[(size_t)(l0 + 4 + j) * DI];
        uN[j] = up[(size_t)(l0 + 4 + j) * DI];
      }
    }
#pragma unroll
    for (int jj = 0; jj < 4; ++jj) {
      const float dlt = dB[jj];
      const float t = dlt * uB[jj];
      const float* bb = &Bsh[l0 + jj][nq * 4];
#pragma unroll
      for (int n = 0; n < 4; ++n) {
        const float dA = __expf(dlt * Av[n]);
        P[n] *= dA;
        x[n] = fmaf(dA, x[n], t * bb[n]);
      }
    }
#pragma unroll
    for (int j = 0; j < 4; ++j) { dB[j] = dN[j]; uB[j] = uN[j]; }
  }
  const unsigned sb = ((unsigned)((b * NCHUNK + c) * DI + d)) * 16 + nq * 4;
  *(float4*)&xz[stash_addr(sb)] = make_float4(P[0], P[1], P[2], P[3]);
  *(float4*)&xz[stash_addr((1u << 20) + sb)] = make_float4(x[0], x[1], x[2], x[3]);
}

// ------------- scan phase 2: sequential chunk combine -------------
__global__ __launch_bounds__(256) void scan_phase2(float* __restrict__ xz) {
  const int t = blockIdx.x * 256 + threadIdx.x;
  const int b = t >> 15;
  const int rem = t & 32767;
  float x = 0.f;
#pragma unroll
  for (int c = 0; c < NCHUNK; ++c) {
    const unsigned i = ((unsigned)(b * NCHUNK + c) << 15) + rem;
    float* Pr = &xz[stash_addr(i)];
    float* Sr = &xz[stash_addr((1u << 20) + i)];
    const float P = *Pr, S = *Sr;
    *Sr = x;
    x = fmaf(P, x, S);
  }
}

// ------------- scan phase 3: rescan w/ init + y + skip + gate -> bf16 y -------------
__global__ __launch_bounds__(256) void scan_phase3(
    const float* __restrict__ delta, const float* __restrict__ xc,
    const float* __restrict__ xdbl, const float* __restrict__ A_log,
    const float* __restrict__ Dskip, float* __restrict__ xz) {
  const int bx = blockIdx.x;
  const int b = bx >> 9;
  const int c = (bx >> 5) & 15;
  const int dt = bx & 31;
  const int tid = threadIdx.x;
  const int dl = tid >> 2, nq = tid & 3;
  const int d = dt * 64 + dl;
  const int row0 = b * L_SZ + c * CLEN;

  __shared__ float Bsh[CLEN][16], Csh[CLEN][16];
  for (int i = tid; i < CLEN * 32; i += 256) {
    const int r = i >> 5, q = i & 31;
    const float v = xdbl[(size_t)(row0 + r) * XDLD + 64 + q];
    if (q < 16) Bsh[r][q] = v; else Csh[r][q - 16] = v;
  }

  float Av[4];
#pragma unroll
  for (int j = 0; j < 4; ++j) Av[j] = -__expf(A_log[d * 16 + nq * 4 + j]);
  const float Dsk = Dskip[d];
  const unsigned sb = ((unsigned)((b * NCHUNK + c) * DI + d)) * 16 + nq * 4;
  const float4 xi = *(const float4*)&xz[stash_addr((1u << 20) + sb)];
  float x[4] = {xi.x, xi.y, xi.z, xi.w};
  __syncthreads();

  const float* dp = delta + (size_t)row0 * DI + d;
  const float* up = xc + (size_t)row0 * DI + d;
  const float* zp = xz + (size_t)row0 * 4096 + DI + d;
  ushortT* yb = (ushortT*)xz;

  float dB[4], uB[4], zB[4];
#pragma unroll
  for (int j = 0; j < 4; ++j) {
    dB[j] = dp[(size_t)j * DI];
    uB[j] = up[(size_t)j * DI];
    zB[j] = zp[(size_t)j * 4096];
  }
  for (int l0 = 0; l0 < CLEN; l0 += 4) {
    float dN[4] = {}, uN[4] = {}, zN[4] = {};
    if (l0 + 4 < CLEN) {
#pragma unroll
      for (int j = 0; j < 4; ++j) {
        dN[j] = dp[(size_t)(l0 + 4 + j) * DI];
        uN[j] = up[(size_t)(l0 + 4 + j) * DI];
        zN[j] = zp[(size_t)(l0 + 4 + j) * 4096];
      }
    }
#pragma unroll
    for (int jj = 0; jj < 4; ++jj) {
      const float dlt = dB[jj];
      const float u = uB[jj];
      const float t = dlt * u;
      const float* bb = &Bsh[l0 + jj][nq * 4];
      const float* cc = &Csh[l0 + jj][nq * 4];
      float y = 0.f;
#pragma unroll
      for (int n = 0; n < 4; ++n) {
        const float dA = __expf(dlt * Av[n]);
        x[n] = fmaf(dA, x[n], t * bb[n]);
        y = fmaf(x[n], cc[n], y);
      }
      y += __shfl_xor(y, 1);
      y += __shfl_xor(y, 2);
      if (nq == 0) {
        const float z = zB[jj];
        const float g = (y + u * Dsk) * (z / (1.f + __expf(-z)));
        yb[(size_t)(row0 + l0 + jj) * 8192 + d] = f2bf(g);
      }
    }
#pragma unroll
    for (int j = 0; j < 4; ++j) { dB[j] = dN[j]; uB[j] = uN[j]; zB[j] = zN[j]; }
  }
}

extern "C" void kernel_launch(void* const* d_in, const int* in_sizes, int n_in,
                              void* d_out, int out_size, void* d_ws, size_t ws_size,
                              hipStream_t stream) {
  const float* hidden  = (const float*)d_in[0];
  const float* Win     = (const float*)d_in[1];
  const float* Wx      = (const float*)d_in[2];
  const float* Wdt     = (const float*)d_in[3];
  const float* dt_bias = (const float*)d_in[4];
  const float* Wout    = (const float*)d_in[5];
  const float* dwk     = (const float*)d_in[6];
  const float* dwb     = (const float*)d_in[7];
  const float* A_log   = (const float*)d_in[8];
  const float* Dskip   = (const float*)d_in[9];

  // ws (64 MB): xz 32MB | shared16 (WinT -> xdbl partials -> delta -> WoutT) 16MB | xc 16MB
  // xz per-row float layout: [0,1024) y-bf16 | [1024,2048) scan stash | [2048,4096) z
  char* ws = (char*)d_ws;
  float* xz       = (float*)ws;
  float* shared16 = (float*)(ws + (32u << 20));
  float* xc       = (float*)(ws + (48u << 20));
  // d_out (8 MB) scratch: hidb [0,4M) (dead after GEMM1); xdbl128 [4M,5M); WxT [5M,5.5M)
  char* dob = (char*)d_out;
  ushortT* hidb = (ushortT*)dob;
  float* xdbl   = (float*)(dob + (4u << 20));
  ushortT* WxT  = (ushortT*)(dob + (5u << 20));

  // 1. hidden -> bf16
  cvt_bf16<<<dim3(B_SZ * L_SZ * DM / 1024), 256, 0, stream>>>(hidden, hidb);
  // 2. Win (1024x4096) -> WinT bf16 (4096x1024) in shared16
  transpose_bf16<<<dim3(4096 / 32, 1024 / 32), dim3(32, 8), 0, stream>>>(
      Win, (ushortT*)shared16, DM, 2 * DI);
  // 3. Wx -> WxT bf16 padded (128 x 2048)
  wx_pad_t<<<dim3(DI / 256, 128), 256, 0, stream>>>(Wx, WxT);
  // 4. GEMM1: xz = hidden @ Win  (M=2048, N=4096, K=1024); 128x64 tiles, 1024 blocks
  gemm_bf16<128, 64><<<dim3(4096 / 64, 2048 / 128), 128, 0, stream>>>(
      hidb, DM, (ushortT*)shared16, DM, xz, 2 * DI, DM);
  // 5. depthwise conv + silu -> xc f32 (8-row tiles)
  conv_silu<<<dim3(B_SZ * L_SZ / 8, DI / 256), 256, 0, stream>>>(xz, dwk, dwb, xc);
  // 6. x_dbl partials (K-split 8) -> shared16 [0,8M) (WinT dead), then reduce
  gemm_xdbl_mfma<<<dim3(B_SZ * L_SZ / 64, KSPLIT), 256, 0, stream>>>(
      xc, WxT, shared16);
  xdbl_reduce<<<dim3(B_SZ * L_SZ * XDLD / 1024), 256, 0, stream>>>(shared16, xdbl);
  // 7. delta = softplus(dt @ Wdt + bias) -> shared16 (partials dead)
  gemm_delta<<<dim3(DI / 256, B_SZ * L_SZ / 16), 256, 0, stream>>>(
      xdbl, Wdt, dt_bias, shared16);
  // 8-10. chunked selective scan (states in xz stash); y (gated, bf16) -> xz
  scan_phase1<<<dim3(B_SZ * NCHUNK * (DI / 64)), 256, 0, stream>>>(
      shared16, xc, xdbl, A_log, xz);
  scan_phase2<<<dim3(B_SZ * DI * NS / 256), 256, 0, stream>>>(xz);
  scan_phase3<<<dim3(B_SZ * NCHUNK * (DI / 64)), 256, 0, stream>>>(
      shared16, xc, xdbl, A_log, Dskip, xz);
  // 11. Wout (2048x1024) -> WoutT bf16 (1024x2048) in shared16 (delta dead)
  transpose_bf16<<<dim3(1024 / 32, 2048 / 32), dim3(32, 8), 0, stream>>>(
      Wout, (ushortT*)shared16, DI, DM);
  // 12. GEMM4: out = y @ Wout  (M=2048, N=1024, K=2048); 64x64 tiles, 512 blocks
  gemm_out64<<<dim3(1024 / 64, 2048 / 64), 128, 0, stream>>>(
      (ushortT*)xz, 4 * DI, (ushortT*)shared16, DI, (float*)d_out, DM, DI);
}

// Round 12
// 262.578 us; speedup vs baseline: 1.8021x; 1.0698x over previous
//
#include <hip/hip_runtime.h>
#include <hip/hip_bf16.h>
#include <math.h>

#define B_SZ 2
#define L_SZ 1024
#define DM 1024
#define DI 2048
#define NS 16
#define DTR 64
#define NCHUNK 16
#define CLEN 64
#define XDLD 128  // padded x_dbl leading dim
#define KSPLIT 8

typedef unsigned short ushortT;
typedef __attribute__((ext_vector_type(8))) short short8;
typedef __attribute__((ext_vector_type(4))) float floatx4;

__device__ __forceinline__ ushortT f2bf(float f) {
  unsigned u = __float_as_uint(f);
  unsigned r = (u + 0x7fff + ((u >> 16) & 1)) >> 16;
  return (ushortT)r;
}

__device__ __forceinline__ void gl2lds16(const void* g, void* l) {
  __builtin_amdgcn_global_load_lds(
      (const __attribute__((address_space(1))) unsigned int*)g,
      (__attribute__((address_space(3))) unsigned int*)l, 16, 0, 0);
}

// Scan-state stash lives in the dead strided region of xz: floats [1024,2048)
// of each 4096-float row. i in [0, 2M): aprod at i, sfin at i + 1M.
__device__ __forceinline__ unsigned stash_addr(unsigned i) {
  return (i >> 10) * 4096 + 1024 + (i & 1023);
}

// ---------------- f32 -> bf16 convert (4 elems/thread) ----------------
__global__ __launch_bounds__(256) void cvt_bf16(const float* __restrict__ src,
                                                ushortT* __restrict__ dst) {
  const int i = blockIdx.x * 256 + threadIdx.x;
  float4 v = ((const float4*)src)[i];
  unsigned lo = (unsigned)f2bf(v.x) | ((unsigned)f2bf(v.y) << 16);
  unsigned hi = (unsigned)f2bf(v.z) | ((unsigned)f2bf(v.w) << 16);
  ((uint2*)dst)[i] = make_uint2(lo, hi);
}

// ---------------- f32 [R][C] -> bf16 [C][R] transpose ----------------
__global__ __launch_bounds__(256) void transpose_bf16(
    const float* __restrict__ src, ushortT* __restrict__ dst, int R, int C) {
  __shared__ float t[32][33];
  const int bx = blockIdx.x * 32;  // col base
  const int by = blockIdx.y * 32;  // row base
  const int tx = threadIdx.x, ty = threadIdx.y;  // (32,8)
#pragma unroll
  for (int j = 0; j < 4; ++j)
    t[ty + j * 8][tx] = src[(size_t)(by + ty + j * 8) * C + bx + tx];
  __syncthreads();
#pragma unroll
  for (int j = 0; j < 4; ++j)
    dst[(size_t)(bx + ty + j * 8) * R + by + tx] = f2bf(t[tx][ty + j * 8]);
}

// ---------------- Wx (2048x96) -> WxT bf16 (128x2048), rows 96..127 zero ----------------
__global__ __launch_bounds__(256) void wx_pad_t(const float* __restrict__ Wx,
                                                ushortT* __restrict__ WxT) {
  const int k = blockIdx.x * 256 + threadIdx.x;  // 0..2047
  const int n = blockIdx.y;                      // 0..127
  WxT[(size_t)n * DI + k] = (n < 96) ? f2bf(Wx[(size_t)k * 96 + n]) : (ushortT)0;
}

// ---------------- GEMM1: 128x64 tile, BK=64, 2 waves, 1024 blocks ----------------
// BK=64 halves the barrier count vs BK=32 (the per-iter vmcnt(0) drain is the cost).
__global__ __launch_bounds__(128) void gemm1_bk64(
    const ushortT* __restrict__ A, int lda,
    const ushortT* __restrict__ BT, int ldb,
    float* __restrict__ C, int ldc, int K) {
  __shared__ __align__(16) char smem[128 * 128 + 64 * 128];  // A 16KB | B 8KB
  char* As = smem;
  char* Bs = smem + 128 * 128;
  const int tid = threadIdx.x;
  const int lane = tid & 63;
  const int quad = lane >> 4;
  const int l16 = lane & 15;
  const int wm = tid >> 6;  // 0/1 -> 64-row half
  const int m0 = blockIdx.y * 128;
  const int n0 = blockIdx.x * 64;

  floatx4 acc[4][4] = {};

  for (int k0 = 0; k0 < K; k0 += 64) {
    for (int i = tid; i < 128 * 8; i += 128) {
      const int r = i >> 3, c = i & 7;
      const int cg = c ^ (r & 7);
      gl2lds16(A + (size_t)(m0 + r) * lda + k0 + cg * 8, As + (i - lane) * 16);
    }
    for (int i = tid; i < 64 * 8; i += 128) {
      const int r = i >> 3, c = i & 7;
      const int cg = c ^ (r & 7);
      gl2lds16(BT + (size_t)(n0 + r) * ldb + k0 + cg * 8, Bs + (i - lane) * 16);
    }
    __syncthreads();

    short8 afr[4][2], bfr[4][2];
#pragma unroll
    for (int i = 0; i < 4; ++i) {
      const int r = wm * 64 + i * 16 + l16;
#pragma unroll
      for (int s = 0; s < 2; ++s)
        afr[i][s] = *(const short8*)(As + r * 128 + (((s * 4 + quad) ^ (r & 7)) * 16));
    }
#pragma unroll
    for (int j = 0; j < 4; ++j) {
      const int r = j * 16 + l16;
#pragma unroll
      for (int s = 0; s < 2; ++s)
        bfr[j][s] = *(const short8*)(Bs + r * 128 + (((s * 4 + quad) ^ (r & 7)) * 16));
    }
#pragma unroll
    for (int s = 0; s < 2; ++s)
#pragma unroll
      for (int i = 0; i < 4; ++i)
#pragma unroll
        for (int j = 0; j < 4; ++j)
          acc[i][j] = __builtin_amdgcn_mfma_f32_16x16x32_bf16(afr[i][s], bfr[j][s],
                                                              acc[i][j], 0, 0, 0);
    __syncthreads();
  }
#pragma unroll
  for (int i = 0; i < 4; ++i)
#pragma unroll
    for (int j = 0; j < 4; ++j)
#pragma unroll
      for (int r = 0; r < 4; ++r) {
        const int m = m0 + wm * 64 + i * 16 + quad * 4 + r;
        const int n = n0 + j * 16 + l16;
        C[(size_t)m * ldc + n] = acc[i][j][r];
      }
}

// ---------------- GEMM4: 64x64 tile, BK=64, split-K=2, 1024 blocks ----------------
// Partials (f32) -> part[ks]; combined by reduce_out.
__global__ __launch_bounds__(128) void gemm_out_split(
    const ushortT* __restrict__ A, int lda,
    const ushortT* __restrict__ BT, int ldb,
    float* __restrict__ part) {
  __shared__ __align__(16) char smem[64 * 128 + 64 * 128];  // 8KB + 8KB
  char* As = smem;
  char* Bs = smem + 64 * 128;
  const int tid = threadIdx.x;
  const int lane = tid & 63;
  const int quad = lane >> 4;
  const int l16 = lane & 15;
  const int wm = tid >> 6;  // 0/1: 32-row half
  const int m0 = blockIdx.y * 64;
  const int n0 = blockIdx.x * 64;
  const int kb = blockIdx.z * (DI / 2);

  floatx4 acc[2][4] = {};

  for (int k0 = kb; k0 < kb + DI / 2; k0 += 64) {
    for (int i = tid; i < 64 * 8; i += 128) {
      const int r = i >> 3, c = i & 7;
      const int cg = c ^ (r & 7);
      gl2lds16(A + (size_t)(m0 + r) * lda + k0 + cg * 8, As + (i - lane) * 16);
    }
    for (int i = tid; i < 64 * 8; i += 128) {
      const int r = i >> 3, c = i & 7;
      const int cg = c ^ (r & 7);
      gl2lds16(BT + (size_t)(n0 + r) * ldb + k0 + cg * 8, Bs + (i - lane) * 16);
    }
    __syncthreads();

    short8 afr[2][2], bfr[4][2];
#pragma unroll
    for (int i = 0; i < 2; ++i) {
      const int m = wm * 32 + i * 16 + l16;
#pragma unroll
      for (int s = 0; s < 2; ++s)
        afr[i][s] = *(const short8*)(As + m * 128 + (((s * 4 + quad) ^ (m & 7)) * 16));
    }
#pragma unroll
    for (int j = 0; j < 4; ++j) {
      const int n = j * 16 + l16;
#pragma unroll
      for (int s = 0; s < 2; ++s)
        bfr[j][s] = *(const short8*)(Bs + n * 128 + (((s * 4 + quad) ^ (n & 7)) * 16));
    }
#pragma unroll
    for (int s = 0; s < 2; ++s)
#pragma unroll
      for (int i = 0; i < 2; ++i)
#pragma unroll
        for (int j = 0; j < 4; ++j)
          acc[i][j] = __builtin_amdgcn_mfma_f32_16x16x32_bf16(afr[i][s], bfr[j][s],
                                                              acc[i][j], 0, 0, 0);
    __syncthreads();
  }
  float* out = part + (size_t)blockIdx.z * (B_SZ * L_SZ * DM);
#pragma unroll
  for (int i = 0; i < 2; ++i)
#pragma unroll
    for (int j = 0; j < 4; ++j)
#pragma unroll
      for (int r = 0; r < 4; ++r) {
        const int m = m0 + wm * 32 + i * 16 + quad * 4 + r;
        const int n = n0 + j * 16 + l16;
        out[(size_t)m * DM + n] = acc[i][j][r];
      }
}

// ------------- out = part0 + part1 (float4 per thread) -------------
__global__ __launch_bounds__(256) void reduce_out(const float* __restrict__ part,
                                                  float* __restrict__ out) {
  const int i = blockIdx.x * 256 + threadIdx.x;
  const float4 a = ((const float4*)part)[i];
  const float4 b = ((const float4*)part)[(size_t)(B_SZ * L_SZ * DM / 4) + i];
  ((float4*)out)[i] = make_float4(a.x + b.x, a.y + b.y, a.z + b.z, a.w + b.w);
}

// ------------- x_dbl partials: xc @ Wx (padded N=128), K-split via MFMA -------------
__global__ __launch_bounds__(256) void gemm_xdbl_mfma(
    const float* __restrict__ xc, const ushortT* __restrict__ WxT,
    float* __restrict__ part) {
  __shared__ __align__(16) char smem[64 * 128 + 128 * 64];
  char* As = smem;             // [64 r][128 B f32]
  char* Bs = smem + 64 * 128;  // [128 r][64 B bf16]
  const int tid = threadIdx.x;
  const int lane = tid & 63;
  const int quad = lane >> 4;
  const int l16 = lane & 15;
  const int wid = tid >> 6;
  const int wm = wid & 1;
  const int wn = wid >> 1;
  const int m0 = blockIdx.x * 64;
  const int kbase = blockIdx.y * (DI / KSPLIT);

  floatx4 acc[2][4] = {};

  for (int kk = 0; kk < DI / KSPLIT; kk += 32) {
    const int k0 = kbase + kk;
    for (int i = tid; i < 64 * 8; i += 256) {
      const int r = i >> 3, c = i & 7;
      const int cg = c ^ (r & 7);
      gl2lds16(xc + (size_t)(m0 + r) * DI + k0 + cg * 4, As + (i - lane) * 16);
    }
    for (int i = tid; i < 128 * 4; i += 256) {
      const int r = i >> 2, c = i & 3;
      const int cg = c ^ (r & 3);
      gl2lds16(WxT + (size_t)r * DI + k0 + cg * 8, Bs + (i - lane) * 16);
    }
    __syncthreads();

    short8 afr[2], bfr[4];
#pragma unroll
    for (int i = 0; i < 2; ++i) {
      const int m = wm * 32 + i * 16 + l16;
      const float4 x0 = *(const float4*)(As + m * 128 + (((quad * 2 + 0) ^ (m & 7)) * 16));
      const float4 x1 = *(const float4*)(As + m * 128 + (((quad * 2 + 1) ^ (m & 7)) * 16));
      short8 f;
      f[0] = (short)f2bf(x0.x); f[1] = (short)f2bf(x0.y);
      f[2] = (short)f2bf(x0.z); f[3] = (short)f2bf(x0.w);
      f[4] = (short)f2bf(x1.x); f[5] = (short)f2bf(x1.y);
      f[6] = (short)f2bf(x1.z); f[7] = (short)f2bf(x1.w);
      afr[i] = f;
    }
#pragma unroll
    for (int j = 0; j < 4; ++j) {
      const int n = wn * 64 + j * 16 + l16;
      bfr[j] = *(const short8*)(Bs + n * 64 + ((quad ^ (n & 3)) * 16));
    }
#pragma unroll
    for (int i = 0; i < 2; ++i)
#pragma unroll
      for (int j = 0; j < 4; ++j)
        acc[i][j] = __builtin_amdgcn_mfma_f32_16x16x32_bf16(afr[i], bfr[j],
                                                            acc[i][j], 0, 0, 0);
    __syncthreads();
  }
  float* out = part + (size_t)blockIdx.y * (B_SZ * L_SZ * XDLD);
#pragma unroll
  for (int i = 0; i < 2; ++i)
#pragma unroll
    for (int j = 0; j < 4; ++j)
#pragma unroll
      for (int r = 0; r < 4; ++r) {
        const int m = m0 + wm * 32 + i * 16 + quad * 4 + r;
        const int n = wn * 64 + j * 16 + l16;
        out[(size_t)m * XDLD + n] = acc[i][j][r];
      }
}

// ------------- xdbl = sum of KSPLIT partials (float4 per thread) -------------
__global__ __launch_bounds__(256) void xdbl_reduce(const float* __restrict__ part,
                                                   float* __restrict__ xdbl) {
  const int i = blockIdx.x * 256 + threadIdx.x;  // float4 index, [0, 65536)
  float4 a = ((const float4*)part)[i];
#pragma unroll
  for (int s = 1; s < KSPLIT; ++s) {
    const float4 b = ((const float4*)part)[(size_t)s * (B_SZ * L_SZ * XDLD / 4) + i];
    a.x += b.x; a.y += b.y; a.z += b.z; a.w += b.w;
  }
  ((float4*)xdbl)[i] = a;
}

// ------------- causal depthwise conv (k=4) + silu -> xc f32 (8-row tiles) -------------
__global__ __launch_bounds__(256) void conv_silu(
    const float* __restrict__ xz, const float* __restrict__ kern,
    const float* __restrict__ bias, float* __restrict__ xc) {
  const int d = blockIdx.y * 256 + threadIdx.x;
  const int b = blockIdx.x >> 7;           // 128 8-row chunks per batch
  const int l0 = (blockIdx.x & 127) * 8;
  const int row0 = b * L_SZ + l0;
  const float k0v = kern[0 * DI + d], k1v = kern[1 * DI + d];
  const float k2v = kern[2 * DI + d], k3v = kern[3 * DI + d];
  float xv[11];
#pragma unroll
  for (int i = 0; i < 11; ++i) {
    const int l = l0 - 3 + i;
    xv[i] = (l >= 0) ? xz[((size_t)(b * L_SZ + l)) * 4096 + d] : 0.f;
  }
  const float bs = bias[d];
#pragma unroll
  for (int j = 0; j < 8; ++j) {
    float a = bs;
    a = fmaf(xv[j], k0v, a);
    a = fmaf(xv[j + 1], k1v, a);
    a = fmaf(xv[j + 2], k2v, a);
    a = fmaf(xv[j + 3], k3v, a);
    xc[(size_t)(row0 + j) * DI + d] = a / (1.f + __expf(-a));
  }
}

// ------------- delta = softplus(dt @ Wdt + dt_bias) -------------
__global__ __launch_bounds__(256) void gemm_delta(
    const float* __restrict__ xdbl, const float* __restrict__ Wdt,
    const float* __restrict__ dt_bias, float* __restrict__ delta) {
  __shared__ float dtL[16][64];
  const int col = blockIdx.x * 256 + threadIdx.x;
  const int row0 = blockIdx.y * 16;
  for (int i = threadIdx.x; i < 16 * 64; i += 256) {
    const int r = i >> 6, k = i & 63;
    dtL[r][k] = xdbl[(size_t)(row0 + r) * XDLD + k];
  }
  __syncthreads();
  const float bias = dt_bias[col];
  float acc[16];
#pragma unroll
  for (int r = 0; r < 16; ++r) acc[r] = bias;
  for (int k8 = 0; k8 < 64; k8 += 8) {
    float w[8];
#pragma unroll
    for (int j = 0; j < 8; ++j) w[j] = Wdt[(size_t)(k8 + j) * DI + col];
#pragma unroll
    for (int r = 0; r < 16; ++r) {
      float a = acc[r];
#pragma unroll
      for (int j = 0; j < 8; ++j) a = fmaf(dtL[r][k8 + j], w[j], a);
      acc[r] = a;
    }
  }
#pragma unroll
  for (int r = 0; r < 16; ++r) {
    const float a = acc[r];
    delta[(size_t)(row0 + r) * DI + col] = (a > 20.f) ? a : log1pf(__expf(a));
  }
}

// ------------- scan phase 1: per-chunk transition -------------
__global__ __launch_bounds__(256) void scan_phase1(
    const float* __restrict__ delta, const float* __restrict__ xc,
    const float* __restrict__ xdbl, const float* __restrict__ A_log,
    float* __restrict__ xz) {
  const int bx = blockIdx.x;
  const int b = bx >> 9;
  const int c = (bx >> 5) & 15;
  const int dt = bx & 31;
  const int tid = threadIdx.x;
  const int dl = tid >> 2, nq = tid & 3;
  const int d = dt * 64 + dl;
  const int row0 = b * L_SZ + c * CLEN;

  __shared__ float Bsh[CLEN][16];
  for (int i = tid; i < CLEN * 16; i += 256)
    Bsh[i >> 4][i & 15] = xdbl[(size_t)(row0 + (i >> 4)) * XDLD + 64 + (i & 15)];

  float Av[4];
#pragma unroll
  for (int j = 0; j < 4; ++j) Av[j] = -__expf(A_log[d * 16 + nq * 4 + j]);
  float x[4] = {}, P[4] = {1.f, 1.f, 1.f, 1.f};
  __syncthreads();

  const float* dp = delta + (size_t)row0 * DI + d;
  const float* up = xc + (size_t)row0 * DI + d;
  float dB[4], uB[4];
#pragma unroll
  for (int j = 0; j < 4; ++j) { dB[j] = dp[(size_t)j * DI]; uB[j] = up[(size_t)j * DI]; }
  for (int l0 = 0; l0 < CLEN; l0 += 4) {
    float dN[4] = {}, uN[4] = {};
    if (l0 + 4 < CLEN) {
#pragma unroll
      for (int j = 0; j < 4; ++j) {
        dN[j] = dp[(size_t)(l0 + 4 + j) * DI];
        uN[j] = up[(size_t)(l0 + 4 + j) * DI];
      }
    }
#pragma unroll
    for (int jj = 0; jj < 4; ++jj) {
      const float dlt = dB[jj];
      const float t = dlt * uB[jj];
      const float* bb = &Bsh[l0 + jj][nq * 4];
#pragma unroll
      for (int n = 0; n < 4; ++n) {
        const float dA = __expf(dlt * Av[n]);
        P[n] *= dA;
        x[n] = fmaf(dA, x[n], t * bb[n]);
      }
    }
#pragma unroll
    for (int j = 0; j < 4; ++j) { dB[j] = dN[j]; uB[j] = uN[j]; }
  }
  const unsigned sb = ((unsigned)((b * NCHUNK + c) * DI + d)) * 16 + nq * 4;
  *(float4*)&xz[stash_addr(sb)] = make_float4(P[0], P[1], P[2], P[3]);
  *(float4*)&xz[stash_addr((1u << 20) + sb)] = make_float4(x[0], x[1], x[2], x[3]);
}

// ------------- scan phase 2: sequential chunk combine -------------
__global__ __launch_bounds__(256) void scan_phase2(float* __restrict__ xz) {
  const int t = blockIdx.x * 256 + threadIdx.x;
  const int b = t >> 15;
  const int rem = t & 32767;
  float x = 0.f;
#pragma unroll
  for (int c = 0; c < NCHUNK; ++c) {
    const unsigned i = ((unsigned)(b * NCHUNK + c) << 15) + rem;
    float* Pr = &xz[stash_addr(i)];
    float* Sr = &xz[stash_addr((1u << 20) + i)];
    const float P = *Pr, S = *Sr;
    *Sr = x;
    x = fmaf(P, x, S);
  }
}

// ------------- scan phase 3: rescan w/ init + y + skip + gate -> bf16 y -------------
__global__ __launch_bounds__(256) void scan_phase3(
    const float* __restrict__ delta, const float* __restrict__ xc,
    const float* __restrict__ xdbl, const float* __restrict__ A_log,
    const float* __restrict__ Dskip, float* __restrict__ xz) {
  const int bx = blockIdx.x;
  const int b = bx >> 9;
  const int c = (bx >> 5) & 15;
  const int dt = bx & 31;
  const int tid = threadIdx.x;
  const int dl = tid >> 2, nq = tid & 3;
  const int d = dt * 64 + dl;
  const int row0 = b * L_SZ + c * CLEN;

  __shared__ float Bsh[CLEN][16], Csh[CLEN][16];
  for (int i = tid; i < CLEN * 32; i += 256) {
    const int r = i >> 5, q = i & 31;
    const float v = xdbl[(size_t)(row0 + r) * XDLD + 64 + q];
    if (q < 16) Bsh[r][q] = v; else Csh[r][q - 16] = v;
  }

  float Av[4];
#pragma unroll
  for (int j = 0; j < 4; ++j) Av[j] = -__expf(A_log[d * 16 + nq * 4 + j]);
  const float Dsk = Dskip[d];
  const unsigned sb = ((unsigned)((b * NCHUNK + c) * DI + d)) * 16 + nq * 4;
  const float4 xi = *(const float4*)&xz[stash_addr((1u << 20) + sb)];
  float x[4] = {xi.x, xi.y, xi.z, xi.w};
  __syncthreads();

  const float* dp = delta + (size_t)row0 * DI + d;
  const float* up = xc + (size_t)row0 * DI + d;
  const float* zp = xz + (size_t)row0 * 4096 + DI + d;
  ushortT* yb = (ushortT*)xz;

  float dB[4], uB[4], zB[4];
#pragma unroll
  for (int j = 0; j < 4; ++j) {
    dB[j] = dp[(size_t)j * DI];
    uB[j] = up[(size_t)j * DI];
    zB[j] = zp[(size_t)j * 4096];
  }
  for (int l0 = 0; l0 < CLEN; l0 += 4) {
    float dN[4] = {}, uN[4] = {}, zN[4] = {};
    if (l0 + 4 < CLEN) {
#pragma unroll
      for (int j = 0; j < 4; ++j) {
        dN[j] = dp[(size_t)(l0 + 4 + j) * DI];
        uN[j] = up[(size_t)(l0 + 4 + j) * DI];
        zN[j] = zp[(size_t)(l0 + 4 + j) * 4096];
      }
    }
#pragma unroll
    for (int jj = 0; jj < 4; ++jj) {
      const float dlt = dB[jj];
      const float u = uB[jj];
      const float t = dlt * u;
      const float* bb = &Bsh[l0 + jj][nq * 4];
      const float* cc = &Csh[l0 + jj][nq * 4];
      float y = 0.f;
#pragma unroll
      for (int n = 0; n < 4; ++n) {
        const float dA = __expf(dlt * Av[n]);
        x[n] = fmaf(dA, x[n], t * bb[n]);
        y = fmaf(x[n], cc[n], y);
      }
      y += __shfl_xor(y, 1);
      y += __shfl_xor(y, 2);
      if (nq == 0) {
        const float z = zB[jj];
        const float g = (y + u * Dsk) * (z / (1.f + __expf(-z)));
        yb[(size_t)(row0 + l0 + jj) * 8192 + d] = f2bf(g);
      }
    }
#pragma unroll
    for (int j = 0; j < 4; ++j) { dB[j] = dN[j]; uB[j] = uN[j]; zB[j] = zN[j]; }
  }
}

extern "C" void kernel_launch(void* const* d_in, const int* in_sizes, int n_in,
                              void* d_out, int out_size, void* d_ws, size_t ws_size,
                              hipStream_t stream) {
  const float* hidden  = (const float*)d_in[0];
  const float* Win     = (const float*)d_in[1];
  const float* Wx      = (const float*)d_in[2];
  const float* Wdt     = (const float*)d_in[3];
  const float* dt_bias = (const float*)d_in[4];
  const float* Wout    = (const float*)d_in[5];
  const float* dwk     = (const float*)d_in[6];
  const float* dwb     = (const float*)d_in[7];
  const float* A_log   = (const float*)d_in[8];
  const float* Dskip   = (const float*)d_in[9];

  // ws (64 MB): xz 32MB | shared16 (WinT -> xdbl partials -> delta -> WoutT) 16MB
  //             | xc 16MB (conv out; reused as GEMM4 split-K partials after scan)
  // xz per-row float layout: [0,1024) y-bf16 | [1024,2048) scan stash | [2048,4096) z
  char* ws = (char*)d_ws;
  float* xz       = (float*)ws;
  float* shared16 = (float*)(ws + (32u << 20));
  float* xc       = (float*)(ws + (48u << 20));
  // d_out (8 MB) scratch: hidb [0,4M) (dead after GEMM1); xdbl128 [4M,5M); WxT [5M,5.5M)
  char* dob = (char*)d_out;
  ushortT* hidb = (ushortT*)dob;
  float* xdbl   = (float*)(dob + (4u << 20));
  ushortT* WxT  = (ushortT*)(dob + (5u << 20));

  // 1. hidden -> bf16
  cvt_bf16<<<dim3(B_SZ * L_SZ * DM / 1024), 256, 0, stream>>>(hidden, hidb);
  // 2. Win (1024x4096) -> WinT bf16 (4096x1024) in shared16
  transpose_bf16<<<dim3(4096 / 32, 1024 / 32), dim3(32, 8), 0, stream>>>(
      Win, (ushortT*)shared16, DM, 2 * DI);
  // 3. Wx -> WxT bf16 padded (128 x 2048)
  wx_pad_t<<<dim3(DI / 256, 128), 256, 0, stream>>>(Wx, WxT);
  // 4. GEMM1: xz = hidden @ Win  (M=2048, N=4096, K=1024); BK=64, 1024 blocks
  gemm1_bk64<<<dim3(4096 / 64, 2048 / 128), 128, 0, stream>>>(
      hidb, DM, (ushortT*)shared16, DM, xz, 2 * DI, DM);
  // 5. depthwise conv + silu -> xc f32 (8-row tiles)
  conv_silu<<<dim3(B_SZ * L_SZ / 8, DI / 256), 256, 0, stream>>>(xz, dwk, dwb, xc);
  // 6. x_dbl partials (K-split 8) -> shared16 [0,8M) (WinT dead), then reduce
  gemm_xdbl_mfma<<<dim3(B_SZ * L_SZ / 64, KSPLIT), 256, 0, stream>>>(
      xc, WxT, shared16);
  xdbl_reduce<<<dim3(B_SZ * L_SZ * XDLD / 1024), 256, 0, stream>>>(shared16, xdbl);
  // 7. delta = softplus(dt @ Wdt + bias) -> shared16 (partials dead)
  gemm_delta<<<dim3(DI / 256, B_SZ * L_SZ / 16), 256, 0, stream>>>(
      xdbl, Wdt, dt_bias, shared16);
  // 8-10. chunked selective scan (states in xz stash); y (gated, bf16) -> xz
  scan_phase1<<<dim3(B_SZ * NCHUNK * (DI / 64)), 256, 0, stream>>>(
      shared16, xc, xdbl, A_log, xz);
  scan_phase2<<<dim3(B_SZ * DI * NS / 256), 256, 0, stream>>>(xz);
  scan_phase3<<<dim3(B_SZ * NCHUNK * (DI / 64)), 256, 0, stream>>>(
      shared16, xc, xdbl, A_log, Dskip, xz);
  // 11. Wout (2048x1024) -> WoutT bf16 (1024x2048) in shared16 (delta dead)
  transpose_bf16<<<dim3(1024 / 32, 2048 / 32), dim3(32, 8), 0, stream>>>(
      Wout, (ushortT*)shared16, DI, DM);
  // 12. GEMM4 split-K=2: partials -> xc region (dead after scan), then reduce -> d_out
  gemm_out_split<<<dim3(1024 / 64, 2048 / 64, 2), 128, 0, stream>>>(
      (ushortT*)xz, 4 * DI, (ushortT*)shared16, DI, xc);
  reduce_out<<<dim3(B_SZ * L_SZ * DM / 1024), 256, 0, stream>>>(xc, (float*)d_out);
}

// Round 13
// 256.177 us; speedup vs baseline: 1.8471x; 1.0250x over previous
//
#include <hip/hip_runtime.h>
#include <hip/hip_bf16.h>
#include <math.h>

#define B_SZ 2
#define L_SZ 1024
#define DM 1024
#define DI 2048
#define NS 16
#define DTR 64
#define NCHUNK 16
#define CLEN 64
#define XDLD 128  // padded x_dbl leading dim
#define KSPLIT 8

typedef unsigned short ushortT;
typedef __attribute__((ext_vector_type(8))) short short8;
typedef __attribute__((ext_vector_type(4))) float floatx4;

__device__ __forceinline__ ushortT f2bf(float f) {
  unsigned u = __float_as_uint(f);
  unsigned r = (u + 0x7fff + ((u >> 16) & 1)) >> 16;
  return (ushortT)r;
}

__device__ __forceinline__ void gl2lds16(const void* g, void* l) {
  __builtin_amdgcn_global_load_lds(
      (const __attribute__((address_space(1))) unsigned int*)g,
      (__attribute__((address_space(3))) unsigned int*)l, 16, 0, 0);
}

// Scan-state stash lives in the dead strided region of xz: floats [1024,2048)
// of each 4096-float row. i in [0, 2M): aprod at i, sfin at i + 1M.
__device__ __forceinline__ unsigned stash_addr(unsigned i) {
  return (i >> 10) * 4096 + 1024 + (i & 1023);
}

// ---------------- f32 -> bf16 convert (4 elems/thread) ----------------
__global__ __launch_bounds__(256) void cvt_bf16(const float* __restrict__ src,
                                                ushortT* __restrict__ dst) {
  const int i = blockIdx.x * 256 + threadIdx.x;
  float4 v = ((const float4*)src)[i];
  unsigned lo = (unsigned)f2bf(v.x) | ((unsigned)f2bf(v.y) << 16);
  unsigned hi = (unsigned)f2bf(v.z) | ((unsigned)f2bf(v.w) << 16);
  ((uint2*)dst)[i] = make_uint2(lo, hi);
}

// ---------------- f32 [R][C] -> bf16 [C][R] transpose ----------------
__global__ __launch_bounds__(256) void transpose_bf16(
    const float* __restrict__ src, ushortT* __restrict__ dst, int R, int C) {
  __shared__ float t[32][33];
  const int bx = blockIdx.x * 32;  // col base
  const int by = blockIdx.y * 32;  // row base
  const int tx = threadIdx.x, ty = threadIdx.y;  // (32,8)
#pragma unroll
  for (int j = 0; j < 4; ++j)
    t[ty + j * 8][tx] = src[(size_t)(by + ty + j * 8) * C + bx + tx];
  __syncthreads();
#pragma unroll
  for (int j = 0; j < 4; ++j)
    dst[(size_t)(bx + ty + j * 8) * R + by + tx] = f2bf(t[tx][ty + j * 8]);
}

// ---------------- Wx (2048x96) -> WxT bf16 (128x2048), rows 96..127 zero ----------------
__global__ __launch_bounds__(256) void wx_pad_t(const float* __restrict__ Wx,
                                                ushortT* __restrict__ WxT) {
  const int k = blockIdx.x * 256 + threadIdx.x;  // 0..2047
  const int n = blockIdx.y;                      // 0..127
  WxT[(size_t)n * DI + k] = (n < 96) ? f2bf(Wx[(size_t)k * 96 + n]) : (ushortT)0;
}

// ---------------- GEMM1: 128x64 tile, BK=64, 2 waves, 1024 blocks ----------------
__global__ __launch_bounds__(128) void gemm1_bk64(
    const ushortT* __restrict__ A, int lda,
    const ushortT* __restrict__ BT, int ldb,
    float* __restrict__ C, int ldc, int K) {
  __shared__ __align__(16) char smem[128 * 128 + 64 * 128];  // A 16KB | B 8KB
  char* As = smem;
  char* Bs = smem + 128 * 128;
  const int tid = threadIdx.x;
  const int lane = tid & 63;
  const int quad = lane >> 4;
  const int l16 = lane & 15;
  const int wm = tid >> 6;  // 0/1 -> 64-row half
  const int m0 = blockIdx.y * 128;
  const int n0 = blockIdx.x * 64;

  floatx4 acc[4][4] = {};

  for (int k0 = 0; k0 < K; k0 += 64) {
    for (int i = tid; i < 128 * 8; i += 128) {
      const int r = i >> 3, c = i & 7;
      const int cg = c ^ (r & 7);
      gl2lds16(A + (size_t)(m0 + r) * lda + k0 + cg * 8, As + (i - lane) * 16);
    }
    for (int i = tid; i < 64 * 8; i += 128) {
      const int r = i >> 3, c = i & 7;
      const int cg = c ^ (r & 7);
      gl2lds16(BT + (size_t)(n0 + r) * ldb + k0 + cg * 8, Bs + (i - lane) * 16);
    }
    __syncthreads();

    short8 afr[4][2], bfr[4][2];
#pragma unroll
    for (int i = 0; i < 4; ++i) {
      const int r = wm * 64 + i * 16 + l16;
#pragma unroll
      for (int s = 0; s < 2; ++s)
        afr[i][s] = *(const short8*)(As + r * 128 + (((s * 4 + quad) ^ (r & 7)) * 16));
    }
#pragma unroll
    for (int j = 0; j < 4; ++j) {
      const int r = j * 16 + l16;
#pragma unroll
      for (int s = 0; s < 2; ++s)
        bfr[j][s] = *(const short8*)(Bs + r * 128 + (((s * 4 + quad) ^ (r & 7)) * 16));
    }
#pragma unroll
    for (int s = 0; s < 2; ++s)
#pragma unroll
      for (int i = 0; i < 4; ++i)
#pragma unroll
        for (int j = 0; j < 4; ++j)
          acc[i][j] = __builtin_amdgcn_mfma_f32_16x16x32_bf16(afr[i][s], bfr[j][s],
                                                              acc[i][j], 0, 0, 0);
    __syncthreads();
  }
#pragma unroll
  for (int i = 0; i < 4; ++i)
#pragma unroll
    for (int j = 0; j < 4; ++j)
#pragma unroll
      for (int r = 0; r < 4; ++r) {
        const int m = m0 + wm * 64 + i * 16 + quad * 4 + r;
        const int n = n0 + j * 16 + l16;
        C[(size_t)m * ldc + n] = acc[i][j][r];
      }
}

// ---------------- GEMM4: 64x64 tile, BK=64, split-K=2, 1024 blocks ----------------
__global__ __launch_bounds__(128) void gemm_out_split(
    const ushortT* __restrict__ A, int lda,
    const ushortT* __restrict__ BT, int ldb,
    float* __restrict__ part) {
  __shared__ __align__(16) char smem[64 * 128 + 64 * 128];  // 8KB + 8KB
  char* As = smem;
  char* Bs = smem + 64 * 128;
  const int tid = threadIdx.x;
  const int lane = tid & 63;
  const int quad = lane >> 4;
  const int l16 = lane & 15;
  const int wm = tid >> 6;  // 0/1: 32-row half
  const int m0 = blockIdx.y * 64;
  const int n0 = blockIdx.x * 64;
  const int kb = blockIdx.z * (DI / 2);

  floatx4 acc[2][4] = {};

  for (int k0 = kb; k0 < kb + DI / 2; k0 += 64) {
    for (int i = tid; i < 64 * 8; i += 128) {
      const int r = i >> 3, c = i & 7;
      const int cg = c ^ (r & 7);
      gl2lds16(A + (size_t)(m0 + r) * lda + k0 + cg * 8, As + (i - lane) * 16);
    }
    for (int i = tid; i < 64 * 8; i += 128) {
      const int r = i >> 3, c = i & 7;
      const int cg = c ^ (r & 7);
      gl2lds16(BT + (size_t)(n0 + r) * ldb + k0 + cg * 8, Bs + (i - lane) * 16);
    }
    __syncthreads();

    short8 afr[2][2], bfr[4][2];
#pragma unroll
    for (int i = 0; i < 2; ++i) {
      const int m = wm * 32 + i * 16 + l16;
#pragma unroll
      for (int s = 0; s < 2; ++s)
        afr[i][s] = *(const short8*)(As + m * 128 + (((s * 4 + quad) ^ (m & 7)) * 16));
    }
#pragma unroll
    for (int j = 0; j < 4; ++j) {
      const int n = j * 16 + l16;
#pragma unroll
      for (int s = 0; s < 2; ++s)
        bfr[j][s] = *(const short8*)(Bs + n * 128 + (((s * 4 + quad) ^ (n & 7)) * 16));
    }
#pragma unroll
    for (int s = 0; s < 2; ++s)
#pragma unroll
      for (int i = 0; i < 2; ++i)
#pragma unroll
        for (int j = 0; j < 4; ++j)
          acc[i][j] = __builtin_amdgcn_mfma_f32_16x16x32_bf16(afr[i][s], bfr[j][s],
                                                              acc[i][j], 0, 0, 0);
    __syncthreads();
  }
  float* out = part + (size_t)blockIdx.z * (B_SZ * L_SZ * DM);
#pragma unroll
  for (int i = 0; i < 2; ++i)
#pragma unroll
    for (int j = 0; j < 4; ++j)
#pragma unroll
      for (int r = 0; r < 4; ++r) {
        const int m = m0 + wm * 32 + i * 16 + quad * 4 + r;
        const int n = n0 + j * 16 + l16;
        out[(size_t)m * DM + n] = acc[i][j][r];
      }
}

// ------------- out = part0 + part1 (float4 per thread) -------------
__global__ __launch_bounds__(256) void reduce_out(const float* __restrict__ part,
                                                  float* __restrict__ out) {
  const int i = blockIdx.x * 256 + threadIdx.x;
  const float4 a = ((const float4*)part)[i];
  const float4 b = ((const float4*)part)[(size_t)(B_SZ * L_SZ * DM / 4) + i];
  ((float4*)out)[i] = make_float4(a.x + b.x, a.y + b.y, a.z + b.z, a.w + b.w);
}

// ------------- x_dbl partials: xc @ Wx (padded N=128), K-split via MFMA -------------
__global__ __launch_bounds__(256) void gemm_xdbl_mfma(
    const float* __restrict__ xc, const ushortT* __restrict__ WxT,
    float* __restrict__ part) {
  __shared__ __align__(16) char smem[64 * 128 + 128 * 64];
  char* As = smem;             // [64 r][128 B f32]
  char* Bs = smem + 64 * 128;  // [128 r][64 B bf16]
  const int tid = threadIdx.x;
  const int lane = tid & 63;
  const int quad = lane >> 4;
  const int l16 = lane & 15;
  const int wid = tid >> 6;
  const int wm = wid & 1;
  const int wn = wid >> 1;
  const int m0 = blockIdx.x * 64;
  const int kbase = blockIdx.y * (DI / KSPLIT);

  floatx4 acc[2][4] = {};

  for (int kk = 0; kk < DI / KSPLIT; kk += 32) {
    const int k0 = kbase + kk;
    for (int i = tid; i < 64 * 8; i += 256) {
      const int r = i >> 3, c = i & 7;
      const int cg = c ^ (r & 7);
      gl2lds16(xc + (size_t)(m0 + r) * DI + k0 + cg * 4, As + (i - lane) * 16);
    }
    for (int i = tid; i < 128 * 4; i += 256) {
      const int r = i >> 2, c = i & 3;
      const int cg = c ^ (r & 3);
      gl2lds16(WxT + (size_t)r * DI + k0 + cg * 8, Bs + (i - lane) * 16);
    }
    __syncthreads();

    short8 afr[2], bfr[4];
#pragma unroll
    for (int i = 0; i < 2; ++i) {
      const int m = wm * 32 + i * 16 + l16;
      const float4 x0 = *(const float4*)(As + m * 128 + (((quad * 2 + 0) ^ (m & 7)) * 16));
      const float4 x1 = *(const float4*)(As + m * 128 + (((quad * 2 + 1) ^ (m & 7)) * 16));
      short8 f;
      f[0] = (short)f2bf(x0.x); f[1] = (short)f2bf(x0.y);
      f[2] = (short)f2bf(x0.z); f[3] = (short)f2bf(x0.w);
      f[4] = (short)f2bf(x1.x); f[5] = (short)f2bf(x1.y);
      f[6] = (short)f2bf(x1.z); f[7] = (short)f2bf(x1.w);
      afr[i] = f;
    }
#pragma unroll
    for (int j = 0; j < 4; ++j) {
      const int n = wn * 64 + j * 16 + l16;
      bfr[j] = *(const short8*)(Bs + n * 64 + ((quad ^ (n & 3)) * 16));
    }
#pragma unroll
    for (int i = 0; i < 2; ++i)
#pragma unroll
      for (int j = 0; j < 4; ++j)
        acc[i][j] = __builtin_amdgcn_mfma_f32_16x16x32_bf16(afr[i], bfr[j],
                                                            acc[i][j], 0, 0, 0);
    __syncthreads();
  }
  float* out = part + (size_t)blockIdx.y * (B_SZ * L_SZ * XDLD);
#pragma unroll
  for (int i = 0; i < 2; ++i)
#pragma unroll
    for (int j = 0; j < 4; ++j)
#pragma unroll
      for (int r = 0; r < 4; ++r) {
        const int m = m0 + wm * 32 + i * 16 + quad * 4 + r;
        const int n = wn * 64 + j * 16 + l16;
        out[(size_t)m * XDLD + n] = acc[i][j][r];
      }
}

// ------------- xdbl = sum of KSPLIT partials (float4 per thread) -------------
__global__ __launch_bounds__(256) void xdbl_reduce(const float* __restrict__ part,
                                                   float* __restrict__ xdbl) {
  const int i = blockIdx.x * 256 + threadIdx.x;  // float4 index, [0, 65536)
  float4 a = ((const float4*)part)[i];
#pragma unroll
  for (int s = 1; s < KSPLIT; ++s) {
    const float4 b = ((const float4*)part)[(size_t)s * (B_SZ * L_SZ * XDLD / 4) + i];
    a.x += b.x; a.y += b.y; a.z += b.z; a.w += b.w;
  }
  ((float4*)xdbl)[i] = a;
}

// ------------- causal depthwise conv (k=4) + silu -> xc f32 (8-row tiles) -------------
__global__ __launch_bounds__(256) void conv_silu(
    const float* __restrict__ xz, const float* __restrict__ kern,
    const float* __restrict__ bias, float* __restrict__ xc) {
  const int d = blockIdx.y * 256 + threadIdx.x;
  const int b = blockIdx.x >> 7;           // 128 8-row chunks per batch
  const int l0 = (blockIdx.x & 127) * 8;
  const int row0 = b * L_SZ + l0;
  const float k0v = kern[0 * DI + d], k1v = kern[1 * DI + d];
  const float k2v = kern[2 * DI + d], k3v = kern[3 * DI + d];
  float xv[11];
#pragma unroll
  for (int i = 0; i < 11; ++i) {
    const int l = l0 - 3 + i;
    xv[i] = (l >= 0) ? xz[((size_t)(b * L_SZ + l)) * 4096 + d] : 0.f;
  }
  const float bs = bias[d];
#pragma unroll
  for (int j = 0; j < 8; ++j) {
    float a = bs;
    a = fmaf(xv[j], k0v, a);
    a = fmaf(xv[j + 1], k1v, a);
    a = fmaf(xv[j + 2], k2v, a);
    a = fmaf(xv[j + 3], k3v, a);
    xc[(size_t)(row0 + j) * DI + d] = a / (1.f + __expf(-a));
  }
}

// ------------- delta = softplus(dt @ Wdt + dt_bias) via MFMA -------------
// M=2048 rows, N=2048 d-cols, K=64. BM=64, BN=128, BK=32 (2 K-iters), 4 waves.
// A = xdbl[:, 0:64] staged f32 -> bf16 in-register; B = WdtT bf16 (2048 x 64).
__global__ __launch_bounds__(256) void gemm_delta_mfma(
    const float* __restrict__ xdbl, const ushortT* __restrict__ WdtT,
    const float* __restrict__ dt_bias, float* __restrict__ delta) {
  __shared__ __align__(16) char smem[64 * 128 + 128 * 64];
  char* As = smem;             // [64 r][128 B f32]
  char* Bs = smem + 64 * 128;  // [128 r][64 B bf16]
  const int tid = threadIdx.x;
  const int lane = tid & 63;
  const int quad = lane >> 4;
  const int l16 = lane & 15;
  const int wid = tid >> 6;
  const int wm = wid & 1;
  const int wn = wid >> 1;
  const int m0 = blockIdx.x * 64;
  const int nb0 = blockIdx.y * 128;

  floatx4 acc[2][4] = {};

#pragma unroll
  for (int k0 = 0; k0 < DTR; k0 += 32) {
    for (int i = tid; i < 64 * 8; i += 256) {
      const int r = i >> 3, c = i & 7;
      const int cg = c ^ (r & 7);
      gl2lds16(xdbl + (size_t)(m0 + r) * XDLD + k0 + cg * 4, As + (i - lane) * 16);
    }
    for (int i = tid; i < 128 * 4; i += 256) {
      const int r = i >> 2, c = i & 3;
      const int cg = c ^ (r & 3);
      gl2lds16(WdtT + (size_t)(nb0 + r) * DTR + k0 + cg * 8, Bs + (i - lane) * 16);
    }
    __syncthreads();

    short8 afr[2], bfr[4];
#pragma unroll
    for (int i = 0; i < 2; ++i) {
      const int m = wm * 32 + i * 16 + l16;
      const float4 x0 = *(const float4*)(As + m * 128 + (((quad * 2 + 0) ^ (m & 7)) * 16));
      const float4 x1 = *(const float4*)(As + m * 128 + (((quad * 2 + 1) ^ (m & 7)) * 16));
      short8 f;
      f[0] = (short)f2bf(x0.x); f[1] = (short)f2bf(x0.y);
      f[2] = (short)f2bf(x0.z); f[3] = (short)f2bf(x0.w);
      f[4] = (short)f2bf(x1.x); f[5] = (short)f2bf(x1.y);
      f[6] = (short)f2bf(x1.z); f[7] = (short)f2bf(x1.w);
      afr[i] = f;
    }
#pragma unroll
    for (int j = 0; j < 4; ++j) {
      const int n = wn * 64 + j * 16 + l16;
      bfr[j] = *(const short8*)(Bs + n * 64 + ((quad ^ (n & 3)) * 16));
    }
#pragma unroll
    for (int i = 0; i < 2; ++i)
#pragma unroll
      for (int j = 0; j < 4; ++j)
        acc[i][j] = __builtin_amdgcn_mfma_f32_16x16x32_bf16(afr[i], bfr[j],
                                                            acc[i][j], 0, 0, 0);
    __syncthreads();
  }
#pragma unroll
  for (int i = 0; i < 2; ++i)
#pragma unroll
    for (int j = 0; j < 4; ++j) {
      const int n = nb0 + wn * 64 + j * 16 + l16;
      const float bias = dt_bias[n];
#pragma unroll
      for (int r = 0; r < 4; ++r) {
        const int m = m0 + wm * 32 + i * 16 + quad * 4 + r;
        const float a = acc[i][j][r] + bias;
        delta[(size_t)m * DI + n] = (a > 20.f) ? a : log1pf(__expf(a));
      }
    }
}

// ------------- scan phase 1: per-chunk transition -------------
__global__ __launch_bounds__(256) void scan_phase1(
    const float* __restrict__ delta, const float* __restrict__ xc,
    const float* __restrict__ xdbl, const float* __restrict__ A_log,
    float* __restrict__ xz) {
  const int bx = blockIdx.x;
  const int b = bx >> 9;
  const int c = (bx >> 5) & 15;
  const int dt = bx & 31;
  const int tid = threadIdx.x;
  const int dl = tid >> 2, nq = tid & 3;
  const int d = dt * 64 + dl;
  const int row0 = b * L_SZ + c * CLEN;

  __shared__ float Bsh[CLEN][16];
  for (int i = tid; i < CLEN * 16; i += 256)
    Bsh[i >> 4][i & 15] = xdbl[(size_t)(row0 + (i >> 4)) * XDLD + 64 + (i & 15)];

  float Av[4];
#pragma unroll
  for (int j = 0; j < 4; ++j) Av[j] = -__expf(A_log[d * 16 + nq * 4 + j]);
  float x[4] = {}, P[4] = {1.f, 1.f, 1.f, 1.f};
  __syncthreads();

  const float* dp = delta + (size_t)row0 * DI + d;
  const float* up = xc + (size_t)row0 * DI + d;
  float dB[4], uB[4];
#pragma unroll
  for (int j = 0; j < 4; ++j) { dB[j] = dp[(size_t)j * DI]; uB[j] = up[(size_t)j * DI]; }
  for (int l0 = 0; l0 < CLEN; l0 += 4) {
    float dN[4] = {}, uN[4] = {};
    if (l0 + 4 < CLEN) {
#pragma unroll
      for (int j = 0; j < 4; ++j) {
        dN[j] = dp[(size_t)(l0 + 4 + j) * DI];
        uN[j] = up[(size_t)(l0 + 4 + j) * DI];
      }
    }
#pragma unroll
    for (int jj = 0; jj < 4; ++jj) {
      const float dlt = dB[jj];
      const float t = dlt * uB[jj];
      const float* bb = &Bsh[l0 + jj][nq * 4];
#pragma unroll
      for (int n = 0; n < 4; ++n) {
        const float dA = __expf(dlt * Av[n]);
        P[n] *= dA;
        x[n] = fmaf(dA, x[n], t * bb[n]);
      }
    }
#pragma unroll
    for (int j = 0; j < 4; ++j) { dB[j] = dN[j]; uB[j] = uN[j]; }
  }
  const unsigned sb = ((unsigned)((b * NCHUNK + c) * DI + d)) * 16 + nq * 4;
  *(float4*)&xz[stash_addr(sb)] = make_float4(P[0], P[1], P[2], P[3]);
  *(float4*)&xz[stash_addr((1u << 20) + sb)] = make_float4(x[0], x[1], x[2], x[3]);
}

// ------------- scan phase 2: sequential chunk combine -------------
__global__ __launch_bounds__(256) void scan_phase2(float* __restrict__ xz) {
  const int t = blockIdx.x * 256 + threadIdx.x;
  const int b = t >> 15;
  const int rem = t & 32767;
  float x = 0.f;
#pragma unroll
  for (int c = 0; c < NCHUNK; ++c) {
    const unsigned i = ((unsigned)(b * NCHUNK + c) << 15) + rem;
    float* Pr = &xz[stash_addr(i)];
    float* Sr = &xz[stash_addr((1u << 20) + i)];
    const float P = *Pr, S = *Sr;
    *Sr = x;
    x = fmaf(P, x, S);
  }
}

// ------------- scan phase 3: rescan w/ init + y + skip + gate -> bf16 y -------------
__global__ __launch_bounds__(256) void scan_phase3(
    const float* __restrict__ delta, const float* __restrict__ xc,
    const float* __restrict__ xdbl, const float* __restrict__ A_log,
    const float* __restrict__ Dskip, float* __restrict__ xz) {
  const int bx = blockIdx.x;
  const int b = bx >> 9;
  const int c = (bx >> 5) & 15;
  const int dt = bx & 31;
  const int tid = threadIdx.x;
  const int dl = tid >> 2, nq = tid & 3;
  const int d = dt * 64 + dl;
  const int row0 = b * L_SZ + c * CLEN;

  __shared__ float Bsh[CLEN][16], Csh[CLEN][16];
  for (int i = tid; i < CLEN * 32; i += 256) {
    const int r = i >> 5, q = i & 31;
    const float v = xdbl[(size_t)(row0 + r) * XDLD + 64 + q];
    if (q < 16) Bsh[r][q] = v; else Csh[r][q - 16] = v;
  }

  float Av[4];
#pragma unroll
  for (int j = 0; j < 4; ++j) Av[j] = -__expf(A_log[d * 16 + nq * 4 + j]);
  const float Dsk = Dskip[d];
  const unsigned sb = ((unsigned)((b * NCHUNK + c) * DI + d)) * 16 + nq * 4;
  const float4 xi = *(const float4*)&xz[stash_addr((1u << 20) + sb)];
  float x[4] = {xi.x, xi.y, xi.z, xi.w};
  __syncthreads();

  const float* dp = delta + (size_t)row0 * DI + d;
  const float* up = xc + (size_t)row0 * DI + d;
  const float* zp = xz + (size_t)row0 * 4096 + DI + d;
  ushortT* yb = (ushortT*)xz;

  float dB[4], uB[4], zB[4];
#pragma unroll
  for (int j = 0; j < 4; ++j) {
    dB[j] = dp[(size_t)j * DI];
    uB[j] = up[(size_t)j * DI];
    zB[j] = zp[(size_t)j * 4096];
  }
  for (int l0 = 0; l0 < CLEN; l0 += 4) {
    float dN[4] = {}, uN[4] = {}, zN[4] = {};
    if (l0 + 4 < CLEN) {
#pragma unroll
      for (int j = 0; j < 4; ++j) {
        dN[j] = dp[(size_t)(l0 + 4 + j) * DI];
        uN[j] = up[(size_t)(l0 + 4 + j) * DI];
        zN[j] = zp[(size_t)(l0 + 4 + j) * 4096];
      }
    }
#pragma unroll
    for (int jj = 0; jj < 4; ++jj) {
      const float dlt = dB[jj];
      const float u = uB[jj];
      const float t = dlt * u;
      const float* bb = &Bsh[l0 + jj][nq * 4];
      const float* cc = &Csh[l0 + jj][nq * 4];
      float y = 0.f;
#pragma unroll
      for (int n = 0; n < 4; ++n) {
        const float dA = __expf(dlt * Av[n]);
        x[n] = fmaf(dA, x[n], t * bb[n]);
        y = fmaf(x[n], cc[n], y);
      }
      y += __shfl_xor(y, 1);
      y += __shfl_xor(y, 2);
      if (nq == 0) {
        const float z = zB[jj];
        const float g = (y + u * Dsk) * (z / (1.f + __expf(-z)));
        yb[(size_t)(row0 + l0 + jj) * 8192 + d] = f2bf(g);
      }
    }
#pragma unroll
    for (int j = 0; j < 4; ++j) { dB[j] = dN[j]; uB[j] = uN[j]; zB[j] = zN[j]; }
  }
}

extern "C" void kernel_launch(void* const* d_in, const int* in_sizes, int n_in,
                              void* d_out, int out_size, void* d_ws, size_t ws_size,
                              hipStream_t stream) {
  const float* hidden  = (const float*)d_in[0];
  const float* Win     = (const float*)d_in[1];
  const float* Wx      = (const float*)d_in[2];
  const float* Wdt     = (const float*)d_in[3];
  const float* dt_bias = (const float*)d_in[4];
  const float* Wout    = (const float*)d_in[5];
  const float* dwk     = (const float*)d_in[6];
  const float* dwb     = (const float*)d_in[7];
  const float* A_log   = (const float*)d_in[8];
  const float* Dskip   = (const float*)d_in[9];

  // ws (64 MB): xz 32MB | shared16 (WinT -> xdbl partials -> delta -> WoutT) 16MB
  //             | xc 16MB (conv out; reused as GEMM4 split-K partials after scan)
  // xz per-row float layout: [0,1024) y-bf16 | [1024,2048) scan stash | [2048,4096) z
  char* ws = (char*)d_ws;
  float* xz       = (float*)ws;
  float* shared16 = (float*)(ws + (32u << 20));
  float* xc       = (float*)(ws + (48u << 20));
  // d_out (8 MB) scratch: hidb [0,4M) (dead after GEMM1); xdbl128 [4M,5M);
  //                       WxT [5M,5.5M); WdtT [5.5M,5.75M)
  char* dob = (char*)d_out;
  ushortT* hidb = (ushortT*)dob;
  float* xdbl   = (float*)(dob + (4u << 20));
  ushortT* WxT  = (ushortT*)(dob + (5u << 20));
  ushortT* WdtT = (ushortT*)(dob + (5u << 20) + (512u << 10));

  // 1. hidden -> bf16
  cvt_bf16<<<dim3(B_SZ * L_SZ * DM / 1024), 256, 0, stream>>>(hidden, hidb);
  // 2. Win (1024x4096) -> WinT bf16 (4096x1024) in shared16
  transpose_bf16<<<dim3(4096 / 32, 1024 / 32), dim3(32, 8), 0, stream>>>(
      Win, (ushortT*)shared16, DM, 2 * DI);
  // 3. Wx -> WxT bf16 padded (128 x 2048); Wdt (64x2048) -> WdtT bf16 (2048x64)
  wx_pad_t<<<dim3(DI / 256, 128), 256, 0, stream>>>(Wx, WxT);
  transpose_bf16<<<dim3(DI / 32, DTR / 32), dim3(32, 8), 0, stream>>>(
      Wdt, WdtT, DTR, DI);
  // 4. GEMM1: xz = hidden @ Win  (M=2048, N=4096, K=1024); BK=64, 1024 blocks
  gemm1_bk64<<<dim3(4096 / 64, 2048 / 128), 128, 0, stream>>>(
      hidb, DM, (ushortT*)shared16, DM, xz, 2 * DI, DM);
  // 5. depthwise conv + silu -> xc f32 (8-row tiles)
  conv_silu<<<dim3(B_SZ * L_SZ / 8, DI / 256), 256, 0, stream>>>(xz, dwk, dwb, xc);
  // 6. x_dbl partials (K-split 8) -> shared16 [0,8M) (WinT dead), then reduce
  gemm_xdbl_mfma<<<dim3(B_SZ * L_SZ / 64, KSPLIT), 256, 0, stream>>>(
      xc, WxT, shared16);
  xdbl_reduce<<<dim3(B_SZ * L_SZ * XDLD / 1024), 256, 0, stream>>>(shared16, xdbl);
  // 7. delta = softplus(dt @ Wdt + bias) via MFMA -> shared16 (partials dead)
  gemm_delta_mfma<<<dim3(B_SZ * L_SZ / 64, DI / 128), 256, 0, stream>>>(
      xdbl, WdtT, dt_bias, shared16);
  // 8-10. chunked selective scan (states in xz stash); y (gated, bf16) -> xz
  scan_phase1<<<dim3(B_SZ * NCHUNK * (DI / 64)), 256, 0, stream>>>(
      shared16, xc, xdbl, A_log, xz);
  scan_phase2<<<dim3(B_SZ * DI * NS / 256), 256, 0, stream>>>(xz);
  scan_phase3<<<dim3(B_SZ * NCHUNK * (DI / 64)), 256, 0, stream>>>(
      shared16, xc, xdbl, A_log, Dskip, xz);
  // 11. Wout (2048x1024) -> WoutT bf16 (1024x2048) in shared16 (delta dead)
  transpose_bf16<<<dim3(1024 / 32, 2048 / 32), dim3(32, 8), 0, stream>>>(
      Wout, (ushortT*)shared16, DI, DM);
  // 12. GEMM4 split-K=2: partials -> xc region (dead after scan), then reduce -> d_out
  gemm_out_split<<<dim3(1024 / 64, 2048 / 64, 2), 128, 0, stream>>>(
      (ushortT*)xz, 4 * DI, (ushortT*)shared16, DI, xc);
  reduce_out<<<dim3(B_SZ * L_SZ * DM / 1024), 256, 0, stream>>>(xc, (float*)d_out);
}

// Round 14
// 253.987 us; speedup vs baseline: 1.8630x; 1.0086x over previous
//
#include <hip/hip_runtime.h>
#include <hip/hip_bf16.h>
#include <math.h>

#define B_SZ 2
#define L_SZ 1024
#define DM 1024
#define DI 2048
#define NS 16
#define DTR 64
#define NCHUNK 16
#define CLEN 64
#define XDLD 128  // padded x_dbl leading dim
#define KSPLIT 8

typedef unsigned short ushortT;
typedef __attribute__((ext_vector_type(8))) short short8;
typedef __attribute__((ext_vector_type(4))) float floatx4;

__device__ __forceinline__ ushortT f2bf(float f) {
  unsigned u = __float_as_uint(f);
  unsigned r = (u + 0x7fff + ((u >> 16) & 1)) >> 16;
  return (ushortT)r;
}

__device__ __forceinline__ float bf2f(ushortT v) {
  return __uint_as_float((unsigned)v << 16);
}

__device__ __forceinline__ void gl2lds16(const void* g, void* l) {
  __builtin_amdgcn_global_load_lds(
      (const __attribute__((address_space(1))) unsigned int*)g,
      (__attribute__((address_space(3))) unsigned int*)l, 16, 0, 0);
}

// Scan-state stash lives in the dead strided region of xz: floats [1024,2048)
// of each 4096-float row. i in [0, 2M): aprod at i, sfin at i + 1M.
__device__ __forceinline__ unsigned stash_addr(unsigned i) {
  return (i >> 10) * 4096 + 1024 + (i & 1023);
}

// ---------------- f32 -> bf16 convert (4 elems/thread) ----------------
__global__ __launch_bounds__(256) void cvt_bf16(const float* __restrict__ src,
                                                ushortT* __restrict__ dst) {
  const int i = blockIdx.x * 256 + threadIdx.x;
  float4 v = ((const float4*)src)[i];
  unsigned lo = (unsigned)f2bf(v.x) | ((unsigned)f2bf(v.y) << 16);
  unsigned hi = (unsigned)f2bf(v.z) | ((unsigned)f2bf(v.w) << 16);
  ((uint2*)dst)[i] = make_uint2(lo, hi);
}

// ---------------- f32 [R][C] -> bf16 [C][R] transpose ----------------
__global__ __launch_bounds__(256) void transpose_bf16(
    const float* __restrict__ src, ushortT* __restrict__ dst, int R, int C) {
  __shared__ float t[32][33];
  const int bx = blockIdx.x * 32;  // col base
  const int by = blockIdx.y * 32;  // row base
  const int tx = threadIdx.x, ty = threadIdx.y;  // (32,8)
#pragma unroll
  for (int j = 0; j < 4; ++j)
    t[ty + j * 8][tx] = src[(size_t)(by + ty + j * 8) * C + bx + tx];
  __syncthreads();
#pragma unroll
  for (int j = 0; j < 4; ++j)
    dst[(size_t)(bx + ty + j * 8) * R + by + tx] = f2bf(t[tx][ty + j * 8]);
}

// ---------------- Wx (2048x96) -> WxT bf16 (128x2048), rows 96..127 zero ----------------
__global__ __launch_bounds__(256) void wx_pad_t(const float* __restrict__ Wx,
                                                ushortT* __restrict__ WxT) {
  const int k = blockIdx.x * 256 + threadIdx.x;  // 0..2047
  const int n = blockIdx.y;                      // 0..127
  WxT[(size_t)n * DI + k] = (n < 96) ? f2bf(Wx[(size_t)k * 96 + n]) : (ushortT)0;
}

// ---------------- GEMM1: 128x128 tile, BK=64, 4 waves, 512 blocks (2/CU) ----------------
// 32 MFMA/wave per barrier; 16 K-iters; LDS 32 KB.
__global__ __launch_bounds__(256) void gemm1_big(
    const ushortT* __restrict__ A, int lda,
    const ushortT* __restrict__ BT, int ldb,
    float* __restrict__ C, int ldc, int K) {
  __shared__ __align__(16) char smem[128 * 128 + 128 * 128];  // A 16KB | B 16KB
  char* As = smem;
  char* Bs = smem + 128 * 128;
  const int tid = threadIdx.x;
  const int lane = tid & 63;
  const int quad = lane >> 4;
  const int l16 = lane & 15;
  const int wid = tid >> 6;
  const int wm = wid & 1;
  const int wn = wid >> 1;
  const int m0 = blockIdx.y * 128;
  const int n0 = blockIdx.x * 128;

  floatx4 acc[4][4] = {};

  for (int k0 = 0; k0 < K; k0 += 64) {
    for (int i = tid; i < 128 * 8; i += 256) {
      const int r = i >> 3, c = i & 7;
      const int cg = c ^ (r & 7);
      gl2lds16(A + (size_t)(m0 + r) * lda + k0 + cg * 8, As + (i - lane) * 16);
    }
    for (int i = tid; i < 128 * 8; i += 256) {
      const int r = i >> 3, c = i & 7;
      const int cg = c ^ (r & 7);
      gl2lds16(BT + (size_t)(n0 + r) * ldb + k0 + cg * 8, Bs + (i - lane) * 16);
    }
    __syncthreads();

    short8 afr[4][2], bfr[4][2];
#pragma unroll
    for (int i = 0; i < 4; ++i) {
      const int r = wm * 64 + i * 16 + l16;
#pragma unroll
      for (int s = 0; s < 2; ++s)
        afr[i][s] = *(const short8*)(As + r * 128 + (((s * 4 + quad) ^ (r & 7)) * 16));
    }
#pragma unroll
    for (int j = 0; j < 4; ++j) {
      const int r = wn * 64 + j * 16 + l16;
#pragma unroll
      for (int s = 0; s < 2; ++s)
        bfr[j][s] = *(const short8*)(Bs + r * 128 + (((s * 4 + quad) ^ (r & 7)) * 16));
    }
#pragma unroll
    for (int s = 0; s < 2; ++s)
#pragma unroll
      for (int i = 0; i < 4; ++i)
#pragma unroll
        for (int j = 0; j < 4; ++j)
          acc[i][j] = __builtin_amdgcn_mfma_f32_16x16x32_bf16(afr[i][s], bfr[j][s],
                                                              acc[i][j], 0, 0, 0);
    __syncthreads();
  }
#pragma unroll
  for (int i = 0; i < 4; ++i)
#pragma unroll
    for (int j = 0; j < 4; ++j)
#pragma unroll
      for (int r = 0; r < 4; ++r) {
        const int m = m0 + wm * 64 + i * 16 + quad * 4 + r;
        const int n = n0 + wn * 64 + j * 16 + l16;
        C[(size_t)m * ldc + n] = acc[i][j][r];
      }
}

// ---------------- GEMM4: 64x64 tile, BK=64, split-K=2, 1024 blocks ----------------
__global__ __launch_bounds__(128) void gemm_out_split(
    const ushortT* __restrict__ A, int lda,
    const ushortT* __restrict__ BT, int ldb,
    float* __restrict__ part) {
  __shared__ __align__(16) char smem[64 * 128 + 64 * 128];  // 8KB + 8KB
  char* As = smem;
  char* Bs = smem + 64 * 128;
  const int tid = threadIdx.x;
  const int lane = tid & 63;
  const int quad = lane >> 4;
  const int l16 = lane & 15;
  const int wm = tid >> 6;  // 0/1: 32-row half
  const int m0 = blockIdx.y * 64;
  const int n0 = blockIdx.x * 64;
  const int kb = blockIdx.z * (DI / 2);

  floatx4 acc[2][4] = {};

  for (int k0 = kb; k0 < kb + DI / 2; k0 += 64) {
    for (int i = tid; i < 64 * 8; i += 128) {
      const int r = i >> 3, c = i & 7;
      const int cg = c ^ (r & 7);
      gl2lds16(A + (size_t)(m0 + r) * lda + k0 + cg * 8, As + (i - lane) * 16);
    }
    for (int i = tid; i < 64 * 8; i += 128) {
      const int r = i >> 3, c = i & 7;
      const int cg = c ^ (r & 7);
      gl2lds16(BT + (size_t)(n0 + r) * ldb + k0 + cg * 8, Bs + (i - lane) * 16);
    }
    __syncthreads();

    short8 afr[2][2], bfr[4][2];
#pragma unroll
    for (int i = 0; i < 2; ++i) {
      const int m = wm * 32 + i * 16 + l16;
#pragma unroll
      for (int s = 0; s < 2; ++s)
        afr[i][s] = *(const short8*)(As + m * 128 + (((s * 4 + quad) ^ (m & 7)) * 16));
    }
#pragma unroll
    for (int j = 0; j < 4; ++j) {
      const int n = j * 16 + l16;
#pragma unroll
      for (int s = 0; s < 2; ++s)
        bfr[j][s] = *(const short8*)(Bs + n * 128 + (((s * 4 + quad) ^ (n & 7)) * 16));
    }
#pragma unroll
    for (int s = 0; s < 2; ++s)
#pragma unroll
      for (int i = 0; i < 2; ++i)
#pragma unroll
        for (int j = 0; j < 4; ++j)
          acc[i][j] = __builtin_amdgcn_mfma_f32_16x16x32_bf16(afr[i][s], bfr[j][s],
                                                              acc[i][j], 0, 0, 0);
    __syncthreads();
  }
  float* out = part + (size_t)blockIdx.z * (B_SZ * L_SZ * DM);
#pragma unroll
  for (int i = 0; i < 2; ++i)
#pragma unroll
    for (int j = 0; j < 4; ++j)
#pragma unroll
      for (int r = 0; r < 4; ++r) {
        const int m = m0 + wm * 32 + i * 16 + quad * 4 + r;
        const int n = n0 + j * 16 + l16;
        out[(size_t)m * DM + n] = acc[i][j][r];
      }
}

// ------------- out = part0 + part1 (float4 per thread) -------------
__global__ __launch_bounds__(256) void reduce_out(const float* __restrict__ part,
                                                  float* __restrict__ out) {
  const int i = blockIdx.x * 256 + threadIdx.x;
  const float4 a = ((const float4*)part)[i];
  const float4 b = ((const float4*)part)[(size_t)(B_SZ * L_SZ * DM / 4) + i];
  ((float4*)out)[i] = make_float4(a.x + b.x, a.y + b.y, a.z + b.z, a.w + b.w);
}

// ------------- x_dbl partials: xc(bf16) @ Wx (padded N=128), K-split via MFMA -------------
__global__ __launch_bounds__(256) void gemm_xdbl_mfma(
    const ushortT* __restrict__ xcb, const ushortT* __restrict__ WxT,
    float* __restrict__ part) {
  __shared__ __align__(16) char smem[64 * 64 + 128 * 64];
  char* As = smem;             // [64 r][64 B bf16]
  char* Bs = smem + 64 * 64;   // [128 r][64 B bf16]
  const int tid = threadIdx.x;
  const int lane = tid & 63;
  const int quad = lane >> 4;
  const int l16 = lane & 15;
  const int wid = tid >> 6;
  const int wm = wid & 1;
  const int wn = wid >> 1;
  const int m0 = blockIdx.x * 64;
  const int kbase = blockIdx.y * (DI / KSPLIT);

  floatx4 acc[2][4] = {};

  for (int kk = 0; kk < DI / KSPLIT; kk += 32) {
    const int k0 = kbase + kk;
    for (int i = tid; i < 64 * 4; i += 256) {
      const int r = i >> 2, c = i & 3;
      const int cg = c ^ (r & 3);
      gl2lds16(xcb + (size_t)(m0 + r) * DI + k0 + cg * 8, As + (i - lane) * 16);
    }
    for (int i = tid; i < 128 * 4; i += 256) {
      const int r = i >> 2, c = i & 3;
      const int cg = c ^ (r & 3);
      gl2lds16(WxT + (size_t)r * DI + k0 + cg * 8, Bs + (i - lane) * 16);
    }
    __syncthreads();

    short8 afr[2], bfr[4];
#pragma unroll
    for (int i = 0; i < 2; ++i) {
      const int m = wm * 32 + i * 16 + l16;
      afr[i] = *(const short8*)(As + m * 64 + ((quad ^ (m & 3)) * 16));
    }
#pragma unroll
    for (int j = 0; j < 4; ++j) {
      const int n = wn * 64 + j * 16 + l16;
      bfr[j] = *(const short8*)(Bs + n * 64 + ((quad ^ (n & 3)) * 16));
    }
#pragma unroll
    for (int i = 0; i < 2; ++i)
#pragma unroll
      for (int j = 0; j < 4; ++j)
        acc[i][j] = __builtin_amdgcn_mfma_f32_16x16x32_bf16(afr[i], bfr[j],
                                                            acc[i][j], 0, 0, 0);
    __syncthreads();
  }
  float* out = part + (size_t)blockIdx.y * (B_SZ * L_SZ * XDLD);
#pragma unroll
  for (int i = 0; i < 2; ++i)
#pragma unroll
    for (int j = 0; j < 4; ++j)
#pragma unroll
      for (int r = 0; r < 4; ++r) {
        const int m = m0 + wm * 32 + i * 16 + quad * 4 + r;
        const int n = wn * 64 + j * 16 + l16;
        out[(size_t)m * XDLD + n] = acc[i][j][r];
      }
}

// ------------- xdbl = sum of KSPLIT partials (float4 per thread) -------------
__global__ __launch_bounds__(256) void xdbl_reduce(const float* __restrict__ part,
                                                   float* __restrict__ xdbl) {
  const int i = blockIdx.x * 256 + threadIdx.x;  // float4 index, [0, 65536)
  float4 a = ((const float4*)part)[i];
#pragma unroll
  for (int s = 1; s < KSPLIT; ++s) {
    const float4 b = ((const float4*)part)[(size_t)s * (B_SZ * L_SZ * XDLD / 4) + i];
    a.x += b.x; a.y += b.y; a.z += b.z; a.w += b.w;
  }
  ((float4*)xdbl)[i] = a;
}

// ------------- causal depthwise conv (k=4) + silu -> xc bf16 (8-row tiles) -------------
__global__ __launch_bounds__(256) void conv_silu(
    const float* __restrict__ xz, const float* __restrict__ kern,
    const float* __restrict__ bias, ushortT* __restrict__ xcb) {
  const int d = blockIdx.y * 256 + threadIdx.x;
  const int b = blockIdx.x >> 7;           // 128 8-row chunks per batch
  const int l0 = (blockIdx.x & 127) * 8;
  const int row0 = b * L_SZ + l0;
  const float k0v = kern[0 * DI + d], k1v = kern[1 * DI + d];
  const float k2v = kern[2 * DI + d], k3v = kern[3 * DI + d];
  float xv[11];
#pragma unroll
  for (int i = 0; i < 11; ++i) {
    const int l = l0 - 3 + i;
    xv[i] = (l >= 0) ? xz[((size_t)(b * L_SZ + l)) * 4096 + d] : 0.f;
  }
  const float bs = bias[d];
#pragma unroll
  for (int j = 0; j < 8; ++j) {
    float a = bs;
    a = fmaf(xv[j], k0v, a);
    a = fmaf(xv[j + 1], k1v, a);
    a = fmaf(xv[j + 2], k2v, a);
    a = fmaf(xv[j + 3], k3v, a);
    xcb[(size_t)(row0 + j) * DI + d] = f2bf(a / (1.f + __expf(-a)));
  }
}

// ------------- delta = softplus(dt @ Wdt + dt_bias) via MFMA -------------
__global__ __launch_bounds__(256) void gemm_delta_mfma(
    const float* __restrict__ xdbl, const ushortT* __restrict__ WdtT,
    const float* __restrict__ dt_bias, float* __restrict__ delta) {
  __shared__ __align__(16) char smem[64 * 128 + 128 * 64];
  char* As = smem;             // [64 r][128 B f32]
  char* Bs = smem + 64 * 128;  // [128 r][64 B bf16]
  const int tid = threadIdx.x;
  const int lane = tid & 63;
  const int quad = lane >> 4;
  const int l16 = lane & 15;
  const int wid = tid >> 6;
  const int wm = wid & 1;
  const int wn = wid >> 1;
  const int m0 = blockIdx.x * 64;
  const int nb0 = blockIdx.y * 128;

  floatx4 acc[2][4] = {};

#pragma unroll
  for (int k0 = 0; k0 < DTR; k0 += 32) {
    for (int i = tid; i < 64 * 8; i += 256) {
      const int r = i >> 3, c = i & 7;
      const int cg = c ^ (r & 7);
      gl2lds16(xdbl + (size_t)(m0 + r) * XDLD + k0 + cg * 4, As + (i - lane) * 16);
    }
    for (int i = tid; i < 128 * 4; i += 256) {
      const int r = i >> 2, c = i & 3;
      const int cg = c ^ (r & 3);
      gl2lds16(WdtT + (size_t)(nb0 + r) * DTR + k0 + cg * 8, Bs + (i - lane) * 16);
    }
    __syncthreads();

    short8 afr[2], bfr[4];
#pragma unroll
    for (int i = 0; i < 2; ++i) {
      const int m = wm * 32 + i * 16 + l16;
      const float4 x0 = *(const float4*)(As + m * 128 + (((quad * 2 + 0) ^ (m & 7)) * 16));
      const float4 x1 = *(const float4*)(As + m * 128 + (((quad * 2 + 1) ^ (m & 7)) * 16));
      short8 f;
      f[0] = (short)f2bf(x0.x); f[1] = (short)f2bf(x0.y);
      f[2] = (short)f2bf(x0.z); f[3] = (short)f2bf(x0.w);
      f[4] = (short)f2bf(x1.x); f[5] = (short)f2bf(x1.y);
      f[6] = (short)f2bf(x1.z); f[7] = (short)f2bf(x1.w);
      afr[i] = f;
    }
#pragma unroll
    for (int j = 0; j < 4; ++j) {
      const int n = wn * 64 + j * 16 + l16;
      bfr[j] = *(const short8*)(Bs + n * 64 + ((quad ^ (n & 3)) * 16));
    }
#pragma unroll
    for (int i = 0; i < 2; ++i)
#pragma unroll
      for (int j = 0; j < 4; ++j)
        acc[i][j] = __builtin_amdgcn_mfma_f32_16x16x32_bf16(afr[i], bfr[j],
                                                            acc[i][j], 0, 0, 0);
    __syncthreads();
  }
#pragma unroll
  for (int i = 0; i < 2; ++i)
#pragma unroll
    for (int j = 0; j < 4; ++j) {
      const int n = nb0 + wn * 64 + j * 16 + l16;
      const float bias = dt_bias[n];
#pragma unroll
      for (int r = 0; r < 4; ++r) {
        const int m = m0 + wm * 32 + i * 16 + quad * 4 + r;
        const float a = acc[i][j][r] + bias;
        delta[(size_t)m * DI + n] = (a > 20.f) ? a : log1pf(__expf(a));
      }
    }
}

// ------------- scan phase 1: per-chunk transition -------------
__global__ __launch_bounds__(256) void scan_phase1(
    const float* __restrict__ delta, const ushortT* __restrict__ xcb,
    const float* __restrict__ xdbl, const float* __restrict__ A_log,
    float* __restrict__ xz) {
  const int bx = blockIdx.x;
  const int b = bx >> 9;
  const int c = (bx >> 5) & 15;
  const int dt = bx & 31;
  const int tid = threadIdx.x;
  const int dl = tid >> 2, nq = tid & 3;
  const int d = dt * 64 + dl;
  const int row0 = b * L_SZ + c * CLEN;

  __shared__ float Bsh[CLEN][16];
  for (int i = tid; i < CLEN * 16; i += 256)
    Bsh[i >> 4][i & 15] = xdbl[(size_t)(row0 + (i >> 4)) * XDLD + 64 + (i & 15)];

  float Av[4];
#pragma unroll
  for (int j = 0; j < 4; ++j) Av[j] = -__expf(A_log[d * 16 + nq * 4 + j]);
  float x[4] = {}, P[4] = {1.f, 1.f, 1.f, 1.f};
  __syncthreads();

  const float* dp = delta + (size_t)row0 * DI + d;
  const ushortT* up = xcb + (size_t)row0 * DI + d;
  float dB[4], uB[4];
#pragma unroll
  for (int j = 0; j < 4; ++j) {
    dB[j] = dp[(size_t)j * DI];
    uB[j] = bf2f(up[(size_t)j * DI]);
  }
  for (int l0 = 0; l0 < CLEN; l0 += 4) {
    float dN[4] = {}, uN[4] = {};
    if (l0 + 4 < CLEN) {
#pragma unroll
      for (int j = 0; j < 4; ++j) {
        dN[j] = dp[(size_t)(l0 + 4 + j) * DI];
        uN[j] = bf2f(up[(size_t)(l0 + 4 + j) * DI]);
      }
    }
#pragma unroll
    for (int jj = 0; jj < 4; ++jj) {
      const float dlt = dB[jj];
      const float t = dlt * uB[jj];
      const float* bb = &Bsh[l0 + jj][nq * 4];
#pragma unroll
      for (int n = 0; n < 4; ++n) {
        const float dA = __expf(dlt * Av[n]);
        P[n] *= dA;
        x[n] = fmaf(dA, x[n], t * bb[n]);
      }
    }
#pragma unroll
    for (int j = 0; j < 4; ++j) { dB[j] = dN[j]; uB[j] = uN[j]; }
  }
  const unsigned sb = ((unsigned)((b * NCHUNK + c) * DI + d)) * 16 + nq * 4;
  *(float4*)&xz[stash_addr(sb)] = make_float4(P[0], P[1], P[2], P[3]);
  *(float4*)&xz[stash_addr((1u << 20) + sb)] = make_float4(x[0], x[1], x[2], x[3]);
}

// ------------- scan phase 2: sequential chunk combine -------------
__global__ __launch_bounds__(256) void scan_phase2(float* __restrict__ xz) {
  const int t = blockIdx.x * 256 + threadIdx.x;
  const int b = t >> 15;
  const int rem = t & 32767;
  float x = 0.f;
#pragma unroll
  for (int c = 0; c < NCHUNK; ++c) {
    const unsigned i = ((unsigned)(b * NCHUNK + c) << 15) + rem;
    float* Pr = &xz[stash_addr(i)];
    float* Sr = &xz[stash_addr((1u << 20) + i)];
    const float P = *Pr, S = *Sr;
    *Sr = x;
    x = fmaf(P, x, S);
  }
}

// ------------- scan phase 3: rescan w/ init + y + skip + gate -> bf16 y -------------
__global__ __launch_bounds__(256) void scan_phase3(
    const float* __restrict__ delta, const ushortT* __restrict__ xcb,
    const float* __restrict__ xdbl, const float* __restrict__ A_log,
    const float* __restrict__ Dskip, float* __restrict__ xz) {
  const int bx = blockIdx.x;
  const int b = bx >> 9;
  const int c = (bx >> 5) & 15;
  const int dt = bx & 31;
  const int tid = threadIdx.x;
  const int dl = tid >> 2, nq = tid & 3;
  const int d = dt * 64 + dl;
  const int row0 = b * L_SZ + c * CLEN;

  __shared__ float Bsh[CLEN][16], Csh[CLEN][16];
  for (int i = tid; i < CLEN * 32; i += 256) {
    const int r = i >> 5, q = i & 31;
    const float v = xdbl[(size_t)(row0 + r) * XDLD + 64 + q];
    if (q < 16) Bsh[r][q] = v; else Csh[r][q - 16] = v;
  }

  float Av[4];
#pragma unroll
  for (int j = 0; j < 4; ++j) Av[j] = -__expf(A_log[d * 16 + nq * 4 + j]);
  const float Dsk = Dskip[d];
  const unsigned sb = ((unsigned)((b * NCHUNK + c) * DI + d)) * 16 + nq * 4;
  const float4 xi = *(const float4*)&xz[stash_addr((1u << 20) + sb)];
  float x[4] = {xi.x, xi.y, xi.z, xi.w};
  __syncthreads();

  const float* dp = delta + (size_t)row0 * DI + d;
  const ushortT* up = xcb + (size_t)row0 * DI + d;
  const float* zp = xz + (size_t)row0 * 4096 + DI + d;
  ushortT* yb = (ushortT*)xz;

  float dB[4], uB[4], zB[4];
#pragma unroll
  for (int j = 0; j < 4; ++j) {
    dB[j] = dp[(size_t)j * DI];
    uB[j] = bf2f(up[(size_t)j * DI]);
    zB[j] = zp[(size_t)j * 4096];
  }
  for (int l0 = 0; l0 < CLEN; l0 += 4) {
    float dN[4] = {}, uN[4] = {}, zN[4] = {};
    if (l0 + 4 < CLEN) {
#pragma unroll
      for (int j = 0; j < 4; ++j) {
        dN[j] = dp[(size_t)(l0 + 4 + j) * DI];
        uN[j] = bf2f(up[(size_t)(l0 + 4 + j) * DI]);
        zN[j] = zp[(size_t)(l0 + 4 + j) * 4096];
      }
    }
#pragma unroll
    for (int jj = 0; jj < 4; ++jj) {
      const float dlt = dB[jj];
      const float u = uB[jj];
      const float t = dlt * u;
      const float* bb = &Bsh[l0 + jj][nq * 4];
      const float* cc = &Csh[l0 + jj][nq * 4];
      float y = 0.f;
#pragma unroll
      for (int n = 0; n < 4; ++n) {
        const float dA = __expf(dlt * Av[n]);
        x[n] = fmaf(dA, x[n], t * bb[n]);
        y = fmaf(x[n], cc[n], y);
      }
      y += __shfl_xor(y, 1);
      y += __shfl_xor(y, 2);
      if (nq == 0) {
        const float z = zB[jj];
        const float g = (y + u * Dsk) * (z / (1.f + __expf(-z)));
        yb[(size_t)(row0 + l0 + jj) * 8192 + d] = f2bf(g);
      }
    }
#pragma unroll
    for (int j = 0; j < 4; ++j) { dB[j] = dN[j]; uB[j] = uN[j]; zB[j] = zN[j]; }
  }
}

extern "C" void kernel_launch(void* const* d_in, const int* in_sizes, int n_in,
                              void* d_out, int out_size, void* d_ws, size_t ws_size,
                              hipStream_t stream) {
  const float* hidden  = (const float*)d_in[0];
  const float* Win     = (const float*)d_in[1];
  const float* Wx      = (const float*)d_in[2];
  const float* Wdt     = (const float*)d_in[3];
  const float* dt_bias = (const float*)d_in[4];
  const float* Wout    = (const float*)d_in[5];
  const float* dwk     = (const float*)d_in[6];
  const float* dwb     = (const float*)d_in[7];
  const float* A_log   = (const float*)d_in[8];
  const float* Dskip   = (const float*)d_in[9];

  // ws (64 MB): xz 32MB | shared16 (WinT -> xdbl partials -> delta -> WoutT) 16MB
  //             | xc region 16MB: bf16 xc [0,8M); GEMM4 split-K partials reuse all 16MB
  // xz per-row float layout: [0,1024) y-bf16 | [1024,2048) scan stash | [2048,4096) z
  char* ws = (char*)d_ws;
  float* xz       = (float*)ws;
  float* shared16 = (float*)(ws + (32u << 20));
  float* xcreg    = (float*)(ws + (48u << 20));
  ushortT* xcb    = (ushortT*)xcreg;
  // d_out (8 MB) scratch: hidb [0,4M) (dead after GEMM1); xdbl128 [4M,5M);
  //                       WxT [5M,5.5M); WdtT [5.5M,5.75M)
  char* dob = (char*)d_out;
  ushortT* hidb = (ushortT*)dob;
  float* xdbl   = (float*)(dob + (4u << 20));
  ushortT* WxT  = (ushortT*)(dob + (5u << 20));
  ushortT* WdtT = (ushortT*)(dob + (5u << 20) + (512u << 10));

  // 1. hidden -> bf16
  cvt_bf16<<<dim3(B_SZ * L_SZ * DM / 1024), 256, 0, stream>>>(hidden, hidb);
  // 2. Win (1024x4096) -> WinT bf16 (4096x1024) in shared16
  transpose_bf16<<<dim3(4096 / 32, 1024 / 32), dim3(32, 8), 0, stream>>>(
      Win, (ushortT*)shared16, DM, 2 * DI);
  // 3. Wx -> WxT bf16 padded (128 x 2048); Wdt (64x2048) -> WdtT bf16 (2048x64)
  wx_pad_t<<<dim3(DI / 256, 128), 256, 0, stream>>>(Wx, WxT);
  transpose_bf16<<<dim3(DI / 32, DTR / 32), dim3(32, 8), 0, stream>>>(
      Wdt, WdtT, DTR, DI);
  // 4. GEMM1: xz = hidden @ Win  (M=2048, N=4096, K=1024); 128x128, BK=64, 512 blocks
  gemm1_big<<<dim3(4096 / 128, 2048 / 128), 256, 0, stream>>>(
      hidb, DM, (ushortT*)shared16, DM, xz, 2 * DI, DM);
  // 5. depthwise conv + silu -> xc bf16 (8-row tiles)
  conv_silu<<<dim3(B_SZ * L_SZ / 8, DI / 256), 256, 0, stream>>>(xz, dwk, dwb, xcb);
  // 6. x_dbl partials (K-split 8) -> shared16 [0,8M) (WinT dead), then reduce
  gemm_xdbl_mfma<<<dim3(B_SZ * L_SZ / 64, KSPLIT), 256, 0, stream>>>(
      xcb, WxT, shared16);
  xdbl_reduce<<<dim3(B_SZ * L_SZ * XDLD / 1024), 256, 0, stream>>>(shared16, xdbl);
  // 7. delta = softplus(dt @ Wdt + bias) via MFMA -> shared16 (partials dead)
  gemm_delta_mfma<<<dim3(B_SZ * L_SZ / 64, DI / 128), 256, 0, stream>>>(
      xdbl, WdtT, dt_bias, shared16);
  // 8-10. chunked selective scan (states in xz stash); y (gated, bf16) -> xz
  scan_phase1<<<dim3(B_SZ * NCHUNK * (DI / 64)), 256, 0, stream>>>(
      shared16, xcb, xdbl, A_log, xz);
  scan_phase2<<<dim3(B_SZ * DI * NS / 256), 256, 0, stream>>>(xz);
  scan_phase3<<<dim3(B_SZ * NCHUNK * (DI / 64)), 256, 0, stream>>>(
      shared16, xcb, xdbl, A_log, Dskip, xz);
  // 11. Wout (2048x1024) -> WoutT bf16 (1024x2048) in shared16 (delta dead)
  transpose_bf16<<<dim3(1024 / 32, 2048 / 32), dim3(32, 8), 0, stream>>>(
      Wout, (ushortT*)shared16, DI, DM);
  // 12. GEMM4 split-K=2: partials -> xc region (dead after scan), then reduce -> d_out
  gemm_out_split<<<dim3(1024 / 64, 2048 / 64, 2), 128, 0, stream>>>(
      (ushortT*)xz, 4 * DI, (ushortT*)shared16, DI, xcreg);
  reduce_out<<<dim3(B_SZ * L_SZ * DM / 1024), 256, 0, stream>>>(xcreg, (float*)d_out);
}